// Round 1
// baseline (2456.255 us; speedup 1.0000x reference)
//
#include <hip/hip_runtime.h>
#include <math.h>

#define NN 50000
#define HH 128
#define EE 600000
#define EDD 32

// ---------------------------------------------------------------------------
// Kernel 0: detect whether edge_index buffer is int64 or int32.
// Reading int32 data as int64 fuses two indices -> value >= 2^32 almost surely.
// flag = 1 -> int64, flag = 0 -> int32.
// ---------------------------------------------------------------------------
__global__ void k_detect(const long long* __restrict__ ei, int n_check,
                         long long nmax, int* __restrict__ flag) {
  __shared__ int bad;
  if (threadIdx.x == 0) bad = 0;
  __syncthreads();
  for (int i = threadIdx.x; i < n_check; i += blockDim.x) {
    long long v = ei[i];
    if (v < 0 || v >= nmax) bad = 1;
  }
  __syncthreads();
  if (threadIdx.x == 0) *flag = (bad ? 0 : 1);
}

// ---------------------------------------------------------------------------
// Kernel 1: convert indices to int32 arrays + per-destination edge count.
// ---------------------------------------------------------------------------
__global__ void k_idx_count(const void* __restrict__ eiv, int E,
                            int* __restrict__ srcD, int* __restrict__ dstD,
                            float* __restrict__ cnt, const int* __restrict__ flag) {
  int e = blockIdx.x * blockDim.x + threadIdx.x;
  if (e >= E) return;
  int s, d;
  if (*flag) {
    const long long* p = (const long long*)eiv;
    s = (int)p[e];
    d = (int)p[E + e];
  } else {
    const int* p = (const int*)eiv;
    s = p[e];
    d = p[E + e];
  }
  srcD[e] = s;
  dstD[e] = d;
  atomicAdd(&cnt[d], 1.0f);
}

__device__ __forceinline__ float gelu_exact(float v) {
  return 0.5f * v * (1.0f + erff(v * 0.70710678118654752f));
}

// ---------------------------------------------------------------------------
// Kernel 2: edge MLP  msg = (gelu([x_src | x_dst | ea] @ W1 + b1)) @ W2 + b2
// then atomicAdd msg into agg[dst].
// Block: 256 threads, 64 edges/block. Thread computes 4 edges x 8 cols.
// ---------------------------------------------------------------------------
__global__ __launch_bounds__(256, 2) void k_edge(
    const float* __restrict__ x, const float* __restrict__ ea,
    const float* __restrict__ W1, const float* __restrict__ b1,
    const float* __restrict__ W2, const float* __restrict__ b2,
    const int* __restrict__ srcD, const int* __restrict__ dstD,
    float* __restrict__ agg) {
  __shared__ float sA[64][36];    // A tile (padded)
  __shared__ float sW[32][128];   // weight K-tile
  __shared__ float sH[64][132];   // hidden activations (padded)

  const int tid = threadIdx.x;
  const int e0 = blockIdx.x * 64;
  const int ty = tid >> 4;   // 0..15 : edge group (4 edges each)
  const int tx = tid & 15;   // 0..15 : col group (8 cols each)
  const int le = tid >> 2;   // 0..63 : edge for A-tile loading
  const int lq = tid & 3;    // 0..3  : quarter of the 32-float slice

  const int gsrc = srcD[e0 + le];
  const int gdst = dstD[e0 + le];

  float acc[4][8];
#pragma unroll
  for (int i = 0; i < 4; ++i)
#pragma unroll
    for (int j = 0; j < 8; ++j) acc[i][j] = 0.f;

  // ---- GEMM1: [64 x 288] @ [288 x 128], K tiled by 32 ----
  for (int kt = 0; kt < 9; ++kt) {
    const float* abase;
    if (kt < 4)
      abase = x + (size_t)gsrc * HH + kt * 32;
    else if (kt < 8)
      abase = x + (size_t)gdst * HH + (kt - 4) * 32;
    else
      abase = ea + (size_t)(e0 + le) * EDD;
    float4 v0 = ((const float4*)abase)[lq];
    float4 v1 = ((const float4*)abase)[lq + 4];
    *(float4*)&sA[le][lq * 4] = v0;
    *(float4*)&sA[le][lq * 4 + 16] = v1;

    const float* wbase = W1 + (size_t)kt * 32 * HH;
#pragma unroll
    for (int q = 0; q < 4; ++q) {
      int idx = tid + 256 * q;
      int r = idx >> 5, c4 = idx & 31;
      *(float4*)&sW[r][c4 * 4] = ((const float4*)(wbase + (size_t)r * HH))[c4];
    }
    __syncthreads();
#pragma unroll
    for (int k = 0; k < 32; ++k) {
      float av[4];
      av[0] = sA[ty * 4 + 0][k];
      av[1] = sA[ty * 4 + 1][k];
      av[2] = sA[ty * 4 + 2][k];
      av[3] = sA[ty * 4 + 3][k];
      const float4 w0 = *(const float4*)&sW[k][tx * 8];
      const float4 w1 = *(const float4*)&sW[k][tx * 8 + 4];
      const float wv[8] = {w0.x, w0.y, w0.z, w0.w, w1.x, w1.y, w1.z, w1.w};
#pragma unroll
      for (int i = 0; i < 4; ++i)
#pragma unroll
        for (int j = 0; j < 8; ++j) acc[i][j] = fmaf(av[i], wv[j], acc[i][j]);
    }
    __syncthreads();
  }

  // ---- bias + exact GELU -> sH ----
  {
    const float4 ba = ((const float4*)b1)[tx * 2];
    const float4 bb = ((const float4*)b1)[tx * 2 + 1];
    const float bv[8] = {ba.x, ba.y, ba.z, ba.w, bb.x, bb.y, bb.z, bb.w};
#pragma unroll
    for (int i = 0; i < 4; ++i)
#pragma unroll
      for (int j = 0; j < 8; ++j)
        sH[ty * 4 + i][tx * 8 + j] = gelu_exact(acc[i][j] + bv[j]);
  }
  __syncthreads();

  // ---- GEMM2: [64 x 128] @ [128 x 128] ----
  float acc2[4][8];
#pragma unroll
  for (int i = 0; i < 4; ++i)
#pragma unroll
    for (int j = 0; j < 8; ++j) acc2[i][j] = 0.f;

  for (int kt = 0; kt < 4; ++kt) {
    const float* wbase = W2 + (size_t)kt * 32 * HH;
#pragma unroll
    for (int q = 0; q < 4; ++q) {
      int idx = tid + 256 * q;
      int r = idx >> 5, c4 = idx & 31;
      *(float4*)&sW[r][c4 * 4] = ((const float4*)(wbase + (size_t)r * HH))[c4];
    }
    __syncthreads();
#pragma unroll
    for (int k = 0; k < 32; ++k) {
      float av[4];
      av[0] = sH[ty * 4 + 0][kt * 32 + k];
      av[1] = sH[ty * 4 + 1][kt * 32 + k];
      av[2] = sH[ty * 4 + 2][kt * 32 + k];
      av[3] = sH[ty * 4 + 3][kt * 32 + k];
      const float4 w0 = *(const float4*)&sW[k][tx * 8];
      const float4 w1 = *(const float4*)&sW[k][tx * 8 + 4];
      const float wv[8] = {w0.x, w0.y, w0.z, w0.w, w1.x, w1.y, w1.z, w1.w};
#pragma unroll
      for (int i = 0; i < 4; ++i)
#pragma unroll
        for (int j = 0; j < 8; ++j) acc2[i][j] = fmaf(av[i], wv[j], acc2[i][j]);
    }
    __syncthreads();
  }

  // ---- + b2, atomic scatter into agg[dst] ----
  {
    const float4 ba = ((const float4*)b2)[tx * 2];
    const float4 bb = ((const float4*)b2)[tx * 2 + 1];
    const float bv[8] = {ba.x, ba.y, ba.z, ba.w, bb.x, bb.y, bb.z, bb.w};
#pragma unroll
    for (int i = 0; i < 4; ++i) {
      int d = dstD[e0 + ty * 4 + i];
      float* ag = agg + (size_t)d * HH + tx * 8;
#pragma unroll
      for (int j = 0; j < 8; ++j) atomicAdd(&ag[j], acc2[i][j] + bv[j]);
    }
  }
}

// ---------------------------------------------------------------------------
// Kernel 3: node MLP on [x | agg/cnt], + residual + LayerNorm.
// Block: 256 threads, 64 rows/block. Thread computes 4 rows x 8 cols.
// ---------------------------------------------------------------------------
__global__ __launch_bounds__(256, 2) void k_node(
    const float* __restrict__ x, const float* __restrict__ agg,
    const float* __restrict__ cnt,
    const float* __restrict__ W1, const float* __restrict__ b1,
    const float* __restrict__ W2, const float* __restrict__ b2,
    const float* __restrict__ g, const float* __restrict__ be,
    float* __restrict__ out) {
  __shared__ float sA[64][36];
  __shared__ float sW[32][128];
  __shared__ float sH[64][132];
  __shared__ float sRinv[64];

  const int tid = threadIdx.x;
  const int r0 = blockIdx.x * 64;
  const int ty = tid >> 4;
  const int tx = tid & 15;
  const int le = tid >> 2;
  const int lq = tid & 3;

  if (tid < 64) {
    int r = r0 + tid;
    float c = (r < NN) ? cnt[r] : 0.f;
    sRinv[tid] = 1.0f / (c + 1e-8f);
  }
  __syncthreads();

  const int lr = r0 + le;
  const bool lrok = (lr < NN);

  float acc[4][8];
#pragma unroll
  for (int i = 0; i < 4; ++i)
#pragma unroll
    for (int j = 0; j < 8; ++j) acc[i][j] = 0.f;

  // ---- GEMM1: [64 x 256] @ [256 x 128] ----
  for (int kt = 0; kt < 8; ++kt) {
    float4 v0 = {0.f, 0.f, 0.f, 0.f}, v1 = {0.f, 0.f, 0.f, 0.f};
    if (lrok) {
      const float* abase = (kt < 4) ? (x + (size_t)lr * HH + kt * 32)
                                    : (agg + (size_t)lr * HH + (kt - 4) * 32);
      v0 = ((const float4*)abase)[lq];
      v1 = ((const float4*)abase)[lq + 4];
      if (kt >= 4) {
        float ri = sRinv[le];
        v0.x *= ri; v0.y *= ri; v0.z *= ri; v0.w *= ri;
        v1.x *= ri; v1.y *= ri; v1.z *= ri; v1.w *= ri;
      }
    }
    *(float4*)&sA[le][lq * 4] = v0;
    *(float4*)&sA[le][lq * 4 + 16] = v1;

    const float* wbase = W1 + (size_t)kt * 32 * HH;
#pragma unroll
    for (int q = 0; q < 4; ++q) {
      int idx = tid + 256 * q;
      int r = idx >> 5, c4 = idx & 31;
      *(float4*)&sW[r][c4 * 4] = ((const float4*)(wbase + (size_t)r * HH))[c4];
    }
    __syncthreads();
#pragma unroll
    for (int k = 0; k < 32; ++k) {
      float av[4];
      av[0] = sA[ty * 4 + 0][k];
      av[1] = sA[ty * 4 + 1][k];
      av[2] = sA[ty * 4 + 2][k];
      av[3] = sA[ty * 4 + 3][k];
      const float4 w0 = *(const float4*)&sW[k][tx * 8];
      const float4 w1 = *(const float4*)&sW[k][tx * 8 + 4];
      const float wv[8] = {w0.x, w0.y, w0.z, w0.w, w1.x, w1.y, w1.z, w1.w};
#pragma unroll
      for (int i = 0; i < 4; ++i)
#pragma unroll
        for (int j = 0; j < 8; ++j) acc[i][j] = fmaf(av[i], wv[j], acc[i][j]);
    }
    __syncthreads();
  }

  // ---- bias + GELU -> sH ----
  {
    const float4 ba = ((const float4*)b1)[tx * 2];
    const float4 bb = ((const float4*)b1)[tx * 2 + 1];
    const float bv[8] = {ba.x, ba.y, ba.z, ba.w, bb.x, bb.y, bb.z, bb.w};
#pragma unroll
    for (int i = 0; i < 4; ++i)
#pragma unroll
      for (int j = 0; j < 8; ++j)
        sH[ty * 4 + i][tx * 8 + j] = gelu_exact(acc[i][j] + bv[j]);
  }
  __syncthreads();

  // ---- GEMM2: [64 x 128] @ [128 x 128] ----
  float acc2[4][8];
#pragma unroll
  for (int i = 0; i < 4; ++i)
#pragma unroll
    for (int j = 0; j < 8; ++j) acc2[i][j] = 0.f;

  for (int kt = 0; kt < 4; ++kt) {
    const float* wbase = W2 + (size_t)kt * 32 * HH;
#pragma unroll
    for (int q = 0; q < 4; ++q) {
      int idx = tid + 256 * q;
      int r = idx >> 5, c4 = idx & 31;
      *(float4*)&sW[r][c4 * 4] = ((const float4*)(wbase + (size_t)r * HH))[c4];
    }
    __syncthreads();
#pragma unroll
    for (int k = 0; k < 32; ++k) {
      float av[4];
      av[0] = sH[ty * 4 + 0][kt * 32 + k];
      av[1] = sH[ty * 4 + 1][kt * 32 + k];
      av[2] = sH[ty * 4 + 2][kt * 32 + k];
      av[3] = sH[ty * 4 + 3][kt * 32 + k];
      const float4 w0 = *(const float4*)&sW[k][tx * 8];
      const float4 w1 = *(const float4*)&sW[k][tx * 8 + 4];
      const float wv[8] = {w0.x, w0.y, w0.z, w0.w, w1.x, w1.y, w1.z, w1.w};
#pragma unroll
      for (int i = 0; i < 4; ++i)
#pragma unroll
        for (int j = 0; j < 8; ++j) acc2[i][j] = fmaf(av[i], wv[j], acc2[i][j]);
    }
    __syncthreads();
  }

  // ---- + b2 + residual, LayerNorm, store ----
  {
    const float4 ba = ((const float4*)b2)[tx * 2];
    const float4 bb = ((const float4*)b2)[tx * 2 + 1];
    const float b2v[8] = {ba.x, ba.y, ba.z, ba.w, bb.x, bb.y, bb.z, bb.w};
    const float4 g0 = *(const float4*)&g[tx * 8];
    const float4 g1 = *(const float4*)&g[tx * 8 + 4];
    const float gv[8] = {g0.x, g0.y, g0.z, g0.w, g1.x, g1.y, g1.z, g1.w};
    const float4 e0v = *(const float4*)&be[tx * 8];
    const float4 e1v = *(const float4*)&be[tx * 8 + 4];
    const float ev[8] = {e0v.x, e0v.y, e0v.z, e0v.w, e1v.x, e1v.y, e1v.z, e1v.w};

#pragma unroll
    for (int i = 0; i < 4; ++i) {
      int r = r0 + ty * 4 + i;
      if (r < NN) {
        const float4 xa = *(const float4*)&x[(size_t)r * HH + tx * 8];
        const float4 xb = *(const float4*)&x[(size_t)r * HH + tx * 8 + 4];
        const float xv[8] = {xa.x, xa.y, xa.z, xa.w, xb.x, xb.y, xb.z, xb.w};
        float v[8];
        float s = 0.f, s2 = 0.f;
#pragma unroll
        for (int j = 0; j < 8; ++j) {
          v[j] = acc2[i][j] + b2v[j] + xv[j];
          s += v[j];
          s2 += v[j] * v[j];
        }
#pragma unroll
        for (int o = 1; o < 16; o <<= 1) {
          s += __shfl_xor(s, o);
          s2 += __shfl_xor(s2, o);
        }
        float mu = s * 0.0078125f;
        float var = s2 * 0.0078125f - mu * mu;
        float rs = rsqrtf(var + 1e-5f);
        float o0[8];
#pragma unroll
        for (int j = 0; j < 8; ++j) o0[j] = (v[j] - mu) * rs * gv[j] + ev[j];
        float4 w0 = {o0[0], o0[1], o0[2], o0[3]};
        float4 w1 = {o0[4], o0[5], o0[6], o0[7]};
        *(float4*)&out[(size_t)r * HH + tx * 8] = w0;
        *(float4*)&out[(size_t)r * HH + tx * 8 + 4] = w1;
      }
    }
  }
}

extern "C" void kernel_launch(void* const* d_in, const int* in_sizes, int n_in,
                              void* d_out, int out_size, void* d_ws, size_t ws_size,
                              hipStream_t stream) {
  const float* x = (const float*)d_in[0];
  const void* ei = d_in[1];
  const float* ea = (const float*)d_in[2];
  const float* eW1 = (const float*)d_in[3];
  const float* eb1 = (const float*)d_in[4];
  const float* eW2 = (const float*)d_in[5];
  const float* eb2 = (const float*)d_in[6];
  const float* nW1 = (const float*)d_in[7];
  const float* nb1 = (const float*)d_in[8];
  const float* nW2 = (const float*)d_in[9];
  const float* nb2 = (const float*)d_in[10];
  const float* lng = (const float*)d_in[11];
  const float* lnb = (const float*)d_in[12];
  float* out = (float*)d_out;

  // workspace layout: agg [N*H f32] | cnt [N f32] | src [E i32] | dst [E i32] | flag
  char* w = (char*)d_ws;
  float* agg = (float*)w;
  float* cnt = (float*)(w + (size_t)NN * HH * 4);
  int* srcD = (int*)(w + (size_t)NN * HH * 4 + (size_t)NN * 4);
  int* dstD = srcD + EE;
  int* flag = dstD + EE;

  hipMemsetAsync(agg, 0, (size_t)NN * HH * 4 + (size_t)NN * 4, stream);
  k_detect<<<1, 256, 0, stream>>>((const long long*)ei, 2048, (long long)NN, flag);
  k_idx_count<<<(EE + 255) / 256, 256, 0, stream>>>(ei, EE, srcD, dstD, cnt, flag);
  k_edge<<<EE / 64, 256, 0, stream>>>(x, ea, eW1, eb1, eW2, eb2, srcD, dstD, agg);
  k_node<<<(NN + 63) / 64, 256, 0, stream>>>(x, agg, cnt, nW1, nb1, nW2, nb2, lng, lnb, out);
}

// Round 2
// 523.615 us; speedup vs baseline: 4.6910x; 4.6910x over previous
//
#include <hip/hip_runtime.h>
#include <hip/hip_bf16.h>
#include <math.h>

#define NN 50000
#define HH 128
#define EE 600000
#define EDD 32

typedef __attribute__((ext_vector_type(8))) short short8;
typedef __attribute__((ext_vector_type(4))) float f32x4;

// ---------------------------------------------------------------------------
// Kernel 0: detect whether edge_index buffer is int64 or int32.
// ---------------------------------------------------------------------------
__global__ void k_detect(const long long* __restrict__ ei, int n_check,
                         long long nmax, int* __restrict__ flag) {
  __shared__ int bad;
  if (threadIdx.x == 0) bad = 0;
  __syncthreads();
  for (int i = threadIdx.x; i < n_check; i += blockDim.x) {
    long long v = ei[i];
    if (v < 0 || v >= nmax) bad = 1;
  }
  __syncthreads();
  if (threadIdx.x == 0) *flag = (bad ? 0 : 1);
}

// ---------------------------------------------------------------------------
// Kernel 1: indices -> int32 + per-destination edge count.
// ---------------------------------------------------------------------------
__global__ void k_idx_count(const void* __restrict__ eiv, int E,
                            int* __restrict__ srcD, int* __restrict__ dstD,
                            float* __restrict__ cnt, const int* __restrict__ flag) {
  int e = blockIdx.x * blockDim.x + threadIdx.x;
  if (e >= E) return;
  int s, d;
  if (*flag) {
    const long long* p = (const long long*)eiv;
    s = (int)p[e];
    d = (int)p[E + e];
  } else {
    const int* p = (const int*)eiv;
    s = p[e];
    d = p[E + e];
  }
  srcD[e] = s;
  dstD[e] = d;
  atomicAdd(&cnt[d], 1.0f);
}

// ---------------------------------------------------------------------------
// Kernel 2: pack a [Kt*32 x 128] fp32 weight matrix into bf16 MFMA B-fragment
// order for v_mfma_f32_16x16x32_bf16:
//   P[((kt*8+ct)*64 + lane)*8 + j] = W[kt*32 + (lane>>4)*8 + j][ct*16 + (lane&15)]
// grid.x = Ktiles*8, block = 64.
// ---------------------------------------------------------------------------
__global__ void k_pack(const float* __restrict__ W, short* __restrict__ P) {
  const int blk = blockIdx.x;          // kt*8 + ct
  const int kt = blk >> 3, ct = blk & 7;
  const int l = threadIdx.x;           // 0..63
  short8 v;
#pragma unroll
  for (int j = 0; j < 8; ++j) {
    float f = W[(size_t)(kt * 32 + ((l >> 4) * 8 + j)) * HH + ct * 16 + (l & 15)];
    __hip_bfloat16 h = __float2bfloat16(f);
    v[j] = *reinterpret_cast<short*>(&h);
  }
  *(short8*)(P + ((size_t)blk * 64 + l) * 8) = v;
}

__device__ __forceinline__ short f2b(float f) {
  __hip_bfloat16 h = __float2bfloat16(f);
  return *reinterpret_cast<short*>(&h);
}

__device__ __forceinline__ void cvt_store8(short* d, const float4 a, const float4 b) {
  short8 v = {f2b(a.x), f2b(a.y), f2b(a.z), f2b(a.w),
              f2b(b.x), f2b(b.y), f2b(b.z), f2b(b.w)};
  *(short8*)d = v;
}

// overflow-safe tanh-form GELU: 0.5*v*(1+tanh(c*(v+0.044715 v^3)))
__device__ __forceinline__ float gelu_f(float v) {
  float u = 0.7978845608028654f * v * fmaf(0.044715f, v * v, 1.0f);
  float e = __expf(2.0f * u);          // e -> inf for large u is fine below
  float th = 1.0f - 2.0f / (e + 1.0f); // -> +/-1 at extremes, no NaN
  return 0.5f * v * (1.0f + th);
}

// ---------------------------------------------------------------------------
// Kernel 3: edge MLP via bf16 MFMA.
// 256 threads = 4 waves; 64 edges/block; wave w owns rows 16w..16w+15.
// A (64 x 288 bf16) staged in LDS, row stride 296 (592B -> 2-way bank alias, free).
// Hidden GELU output reuses the same LDS rows (cols 0..127).
// ---------------------------------------------------------------------------
#define AS 296
__global__ __launch_bounds__(256, 2) void k_edge(
    const float* __restrict__ x, const float* __restrict__ ea,
    const short* __restrict__ pW1, const float* __restrict__ b1,
    const short* __restrict__ pW2, const float* __restrict__ b2,
    const int* __restrict__ srcD, const int* __restrict__ dstD,
    float* __restrict__ agg) {
  __shared__ short sA[64 * AS];

  const int tid = threadIdx.x;
  const int e0 = blockIdx.x * 64;
  // staging ids: 4 threads per row
  const int le = tid >> 2;
  const int lq = tid & 3;
  // compute ids
  const int wv = tid >> 6;       // wave 0..3
  const int l = tid & 63;        // lane
  const int lr = l & 15;
  const int kq = l >> 4;         // 0..3

  // ---- stage A = [x[src] | x[dst] | ea] as bf16 (wave w stages its own rows)
  {
    const int gsrc = srcD[e0 + le];
    const int gdst = dstD[e0 + le];
    const float4* xs = (const float4*)(x + (size_t)gsrc * HH);
    const float4* xd = (const float4*)(x + (size_t)gdst * HH);
    short* row = &sA[le * AS];
#pragma unroll
    for (int i = 0; i < 4; ++i)
      cvt_store8(row + lq * 32 + i * 8, xs[lq * 8 + i * 2], xs[lq * 8 + i * 2 + 1]);
#pragma unroll
    for (int i = 0; i < 4; ++i)
      cvt_store8(row + 128 + lq * 32 + i * 8, xd[lq * 8 + i * 2], xd[lq * 8 + i * 2 + 1]);
    const float4* es = (const float4*)(ea + (size_t)(e0 + le) * EDD);
    cvt_store8(row + 256 + lq * 8, es[lq * 2], es[lq * 2 + 1]);
  }
  __syncthreads();

  // ---- GEMM1: [64 x 288] @ [288 x 128] ----
  f32x4 acc[8];
  const f32x4 zero = {0.f, 0.f, 0.f, 0.f};
#pragma unroll
  for (int ct = 0; ct < 8; ++ct) acc[ct] = zero;

  const short* abase = &sA[(wv * 16 + lr) * AS + kq * 8];
  const short8* bp1 = (const short8*)pW1;
  for (int kt = 0; kt < 9; ++kt) {
    short8 af = *(const short8*)(abase + kt * 32);
#pragma unroll
    for (int ct = 0; ct < 8; ++ct) {
      short8 bf_ = bp1[(kt * 8 + ct) * 64 + l];
      acc[ct] = __builtin_amdgcn_mfma_f32_16x16x32_bf16(af, bf_, acc[ct], 0, 0, 0);
    }
  }

  // ---- bias + GELU -> LDS (cols 0..127 of this wave's rows) ----
  // C/D layout: col = ct*16 + (l&15), row = wv*16 + (l>>4)*4 + reg
#pragma unroll
  for (int ct = 0; ct < 8; ++ct) {
    float b1v = b1[ct * 16 + lr];
#pragma unroll
    for (int r = 0; r < 4; ++r) {
      float v = acc[ct][r] + b1v;
      sA[(wv * 16 + kq * 4 + r) * AS + ct * 16 + lr] = f2b(gelu_f(v));
    }
  }
  // wave-local producer/consumer: compiler-inserted lgkmcnt orders write->read

  // ---- GEMM2: [64 x 128] @ [128 x 128] ----
  f32x4 acc2[8];
#pragma unroll
  for (int ct = 0; ct < 8; ++ct) acc2[ct] = zero;
  const short8* bp2 = (const short8*)pW2;
  for (int kt = 0; kt < 4; ++kt) {
    short8 af = *(const short8*)(abase + kt * 32);
#pragma unroll
    for (int ct = 0; ct < 8; ++ct) {
      short8 bf_ = bp2[(kt * 8 + ct) * 64 + l];
      acc2[ct] = __builtin_amdgcn_mfma_f32_16x16x32_bf16(af, bf_, acc2[ct], 0, 0, 0);
    }
  }

  // ---- + b2, atomic scatter ----
  int drow[4];
#pragma unroll
  for (int r = 0; r < 4; ++r) drow[r] = dstD[e0 + wv * 16 + kq * 4 + r];
#pragma unroll
  for (int ct = 0; ct < 8; ++ct) {
    float b2v = b2[ct * 16 + lr];
#pragma unroll
    for (int r = 0; r < 4; ++r)
      atomicAdd(&agg[(size_t)drow[r] * HH + ct * 16 + lr], acc2[ct][r] + b2v);
  }
}

// ---------------------------------------------------------------------------
// Kernel 4: node MLP + residual + LayerNorm via bf16 MFMA.
// A = [x | agg/cnt], 64 nodes/block, row stride 264 (528B -> 2-way alias).
// ---------------------------------------------------------------------------
#define NS 264
__global__ __launch_bounds__(256, 2) void k_node(
    const float* __restrict__ x, const float* __restrict__ agg,
    const float* __restrict__ cnt,
    const short* __restrict__ pW1, const float* __restrict__ b1,
    const short* __restrict__ pW2, const float* __restrict__ b2,
    const float* __restrict__ g, const float* __restrict__ be,
    float* __restrict__ out) {
  __shared__ short sA[64 * NS];

  const int tid = threadIdx.x;
  const int r0 = blockIdx.x * 64;
  const int le = tid >> 2;
  const int lq = tid & 3;
  const int wv = tid >> 6;
  const int l = tid & 63;
  const int lr = l & 15;
  const int kq = l >> 4;

  // ---- stage A = [x | agg*rinv] as bf16 ----
  {
    const int gr = r0 + le;
    short* row = &sA[le * NS];
    if (gr < NN) {
      float rinv = 1.0f / (cnt[gr] + 1e-8f);
      const float4* xs = (const float4*)(x + (size_t)gr * HH);
      const float4* as_ = (const float4*)(agg + (size_t)gr * HH);
#pragma unroll
      for (int i = 0; i < 4; ++i)
        cvt_store8(row + lq * 32 + i * 8, xs[lq * 8 + i * 2], xs[lq * 8 + i * 2 + 1]);
#pragma unroll
      for (int i = 0; i < 4; ++i) {
        float4 a = as_[lq * 8 + i * 2], b = as_[lq * 8 + i * 2 + 1];
        a.x *= rinv; a.y *= rinv; a.z *= rinv; a.w *= rinv;
        b.x *= rinv; b.y *= rinv; b.z *= rinv; b.w *= rinv;
        cvt_store8(row + 128 + lq * 32 + i * 8, a, b);
      }
    } else {
      short8 z = {0, 0, 0, 0, 0, 0, 0, 0};
#pragma unroll
      for (int i = 0; i < 8; ++i) *(short8*)(row + lq * 64 + i * 8) = z;
    }
  }
  __syncthreads();

  // ---- GEMM1: [64 x 256] @ [256 x 128] ----
  f32x4 acc[8];
  const f32x4 zero = {0.f, 0.f, 0.f, 0.f};
#pragma unroll
  for (int ct = 0; ct < 8; ++ct) acc[ct] = zero;

  const short* abase = &sA[(wv * 16 + lr) * NS + kq * 8];
  const short8* bp1 = (const short8*)pW1;
  for (int kt = 0; kt < 8; ++kt) {
    short8 af = *(const short8*)(abase + kt * 32);
#pragma unroll
    for (int ct = 0; ct < 8; ++ct) {
      short8 bf_ = bp1[(kt * 8 + ct) * 64 + l];
      acc[ct] = __builtin_amdgcn_mfma_f32_16x16x32_bf16(af, bf_, acc[ct], 0, 0, 0);
    }
  }

  // ---- bias + GELU -> LDS ----
#pragma unroll
  for (int ct = 0; ct < 8; ++ct) {
    float b1v = b1[ct * 16 + lr];
#pragma unroll
    for (int r = 0; r < 4; ++r) {
      float v = acc[ct][r] + b1v;
      sA[(wv * 16 + kq * 4 + r) * NS + ct * 16 + lr] = f2b(gelu_f(v));
    }
  }

  // ---- GEMM2: [64 x 128] @ [128 x 128] ----
  f32x4 acc2[8];
#pragma unroll
  for (int ct = 0; ct < 8; ++ct) acc2[ct] = zero;
  const short8* bp2 = (const short8*)pW2;
  for (int kt = 0; kt < 4; ++kt) {
    short8 af = *(const short8*)(abase + kt * 32);
#pragma unroll
    for (int ct = 0; ct < 8; ++ct) {
      short8 bf_ = bp2[(kt * 8 + ct) * 64 + l];
      acc2[ct] = __builtin_amdgcn_mfma_f32_16x16x32_bf16(af, bf_, acc2[ct], 0, 0, 0);
    }
  }

  // ---- + b2 + residual, LayerNorm, store ----
  float b2v[8], gv[8], bv[8];
#pragma unroll
  for (int ct = 0; ct < 8; ++ct) {
    int c = ct * 16 + lr;
    b2v[ct] = b2[c];
    gv[ct] = g[c];
    bv[ct] = be[c];
  }
#pragma unroll
  for (int r = 0; r < 4; ++r) {
    int grow = r0 + wv * 16 + kq * 4 + r;
    if (grow >= NN) continue;
    float v[8];
    float s = 0.f, s2 = 0.f;
#pragma unroll
    for (int ct = 0; ct < 8; ++ct) {
      v[ct] = acc2[ct][r] + b2v[ct] + x[(size_t)grow * HH + ct * 16 + lr];
      s += v[ct];
      s2 += v[ct] * v[ct];
    }
#pragma unroll
    for (int o = 1; o < 16; o <<= 1) {
      s += __shfl_xor(s, o);
      s2 += __shfl_xor(s2, o);
    }
    float mu = s * 0.0078125f;
    float var = s2 * 0.0078125f - mu * mu;
    float rs = rsqrtf(var + 1e-5f);
#pragma unroll
    for (int ct = 0; ct < 8; ++ct)
      out[(size_t)grow * HH + ct * 16 + lr] = (v[ct] - mu) * rs * gv[ct] + bv[ct];
  }
}

extern "C" void kernel_launch(void* const* d_in, const int* in_sizes, int n_in,
                              void* d_out, int out_size, void* d_ws, size_t ws_size,
                              hipStream_t stream) {
  const float* x = (const float*)d_in[0];
  const void* ei = d_in[1];
  const float* ea = (const float*)d_in[2];
  const float* eW1 = (const float*)d_in[3];
  const float* eb1 = (const float*)d_in[4];
  const float* eW2 = (const float*)d_in[5];
  const float* eb2 = (const float*)d_in[6];
  const float* nW1 = (const float*)d_in[7];
  const float* nb1 = (const float*)d_in[8];
  const float* nW2 = (const float*)d_in[9];
  const float* nb2 = (const float*)d_in[10];
  const float* lng = (const float*)d_in[11];
  const float* lnb = (const float*)d_in[12];
  float* out = (float*)d_out;

  // ws layout
  char* w = (char*)d_ws;
  size_t off = 0;
  float* agg = (float*)(w + off); off += (size_t)NN * HH * 4;   // 25.6MB
  float* cnt = (float*)(w + off); off += (size_t)NN * 4;        // 200KB
  short* pe1 = (short*)(w + off); off += (size_t)9 * 512 * 8 * 2;
  short* pe2 = (short*)(w + off); off += (size_t)4 * 512 * 8 * 2;
  short* pn1 = (short*)(w + off); off += (size_t)8 * 512 * 8 * 2;
  short* pn2 = (short*)(w + off); off += (size_t)4 * 512 * 8 * 2;
  int* srcD = (int*)(w + off); off += (size_t)EE * 4;
  int* dstD = (int*)(w + off); off += (size_t)EE * 4;
  int* flag = (int*)(w + off);

  hipMemsetAsync(agg, 0, (size_t)NN * HH * 4 + (size_t)NN * 4, stream);
  k_detect<<<1, 256, 0, stream>>>((const long long*)ei, 2048, (long long)NN, flag);
  k_idx_count<<<(EE + 255) / 256, 256, 0, stream>>>(ei, EE, srcD, dstD, cnt, flag);
  k_pack<<<9 * 8, 64, 0, stream>>>(eW1, pe1);
  k_pack<<<4 * 8, 64, 0, stream>>>(eW2, pe2);
  k_pack<<<8 * 8, 64, 0, stream>>>(nW1, pn1);
  k_pack<<<4 * 8, 64, 0, stream>>>(nW2, pn2);
  k_edge<<<EE / 64, 256, 0, stream>>>(x, ea, pe1, eb1, pe2, eb2, srcD, dstD, agg);
  k_node<<<(NN + 63) / 64, 256, 0, stream>>>(x, agg, cnt, pn1, nb1, pn2, nb2, lng, lnb, out);
}

// Round 3
// 407.152 us; speedup vs baseline: 6.0328x; 1.2860x over previous
//
#include <hip/hip_runtime.h>
#include <hip/hip_bf16.h>
#include <math.h>

#define NN 50000
#define HH 128
#define EE 600000
#define EDD 32

typedef __attribute__((ext_vector_type(8))) short short8;
typedef __attribute__((ext_vector_type(4))) float f32x4;

// ---------------------------------------------------------------------------
// Kernel 0: detect whether edge_index buffer is int64 or int32.
// ---------------------------------------------------------------------------
__global__ void k_detect(const long long* __restrict__ ei, int n_check,
                         long long nmax, int* __restrict__ flag) {
  __shared__ int bad;
  if (threadIdx.x == 0) bad = 0;
  __syncthreads();
  for (int i = threadIdx.x; i < n_check; i += blockDim.x) {
    long long v = ei[i];
    if (v < 0 || v >= nmax) bad = 1;
  }
  __syncthreads();
  if (threadIdx.x == 0) *flag = (bad ? 0 : 1);
}

// ---------------------------------------------------------------------------
// Kernel 1: indices -> int32 + per-destination edge count.
// ---------------------------------------------------------------------------
__global__ void k_idx_count(const void* __restrict__ eiv, int E,
                            int* __restrict__ srcD, int* __restrict__ dstD,
                            float* __restrict__ cnt, const int* __restrict__ flag) {
  int e = blockIdx.x * blockDim.x + threadIdx.x;
  if (e >= E) return;
  int s, d;
  if (*flag) {
    const long long* p = (const long long*)eiv;
    s = (int)p[e];
    d = (int)p[E + e];
  } else {
    const int* p = (const int*)eiv;
    s = p[e];
    d = p[E + e];
  }
  srcD[e] = s;
  dstD[e] = d;
  atomicAdd(&cnt[d], 1.0f);
}

// ---------------------------------------------------------------------------
// Kernel 2: pack all 4 fp32 weight matrices into bf16 MFMA B-fragment order:
//   P[((kt*8+ct)*64 + lane)*8 + j] = W[kt*32 + (lane>>4)*8 + j][ct*16 + (lane&15)]
// grid = 200 blocks x 64 (eW1:72, eW2:32, nW1:64, nW2:32).
// ---------------------------------------------------------------------------
__global__ void k_pack_all(const float* __restrict__ eW1, const float* __restrict__ eW2,
                           const float* __restrict__ nW1, const float* __restrict__ nW2,
                           short* __restrict__ pe1, short* __restrict__ pe2,
                           short* __restrict__ pn1, short* __restrict__ pn2) {
  int blk = blockIdx.x;
  const float* W;
  short* P;
  int b;
  if (blk < 72)       { W = eW1; P = pe1; b = blk; }
  else if (blk < 104) { W = eW2; P = pe2; b = blk - 72; }
  else if (blk < 168) { W = nW1; P = pn1; b = blk - 104; }
  else                { W = nW2; P = pn2; b = blk - 168; }
  const int kt = b >> 3, ct = b & 7;
  const int l = threadIdx.x;
  short8 v;
#pragma unroll
  for (int j = 0; j < 8; ++j) {
    float f = W[(size_t)(kt * 32 + ((l >> 4) * 8 + j)) * HH + ct * 16 + (l & 15)];
    __hip_bfloat16 h = __float2bfloat16(f);
    v[j] = *reinterpret_cast<short*>(&h);
  }
  *(short8*)(P + ((size_t)b * 64 + l) * 8) = v;
}

__device__ __forceinline__ short f2b(float f) {
  __hip_bfloat16 h = __float2bfloat16(f);
  return *reinterpret_cast<short*>(&h);
}

__device__ __forceinline__ void cvt_store8(short* d, const float4 a, const float4 b) {
  short8 v = {f2b(a.x), f2b(a.y), f2b(a.z), f2b(a.w),
              f2b(b.x), f2b(b.y), f2b(b.z), f2b(b.w)};
  *(short8*)d = v;
}

// overflow-safe tanh-form GELU
__device__ __forceinline__ float gelu_f(float v) {
  float u = 0.7978845608028654f * v * fmaf(0.044715f, v * v, 1.0f);
  float e = __expf(2.0f * u);
  float th = 1.0f - 2.0f / (e + 1.0f);
  return 0.5f * v * (1.0f + th);
}

// ---------------------------------------------------------------------------
// Kernel 3: edge MLP via bf16 MFMA, column-split waves, B in registers.
// 256 threads = 4 waves; 64 edges/block; wave w owns cols [32w, 32w+32).
// ---------------------------------------------------------------------------
#define AS 296   // A row stride (shorts): 592B -> 2-way bank alias (free)
#define HS 136   // hidden row stride (shorts): 272B
__global__ __launch_bounds__(256, 2) void k_edge(
    const float* __restrict__ x, const float* __restrict__ ea,
    const short* __restrict__ pW1, const float* __restrict__ b1,
    const short* __restrict__ pW2, const float* __restrict__ b2,
    const int* __restrict__ srcD, const int* __restrict__ dstD,
    float* __restrict__ agg) {
  __shared__ short sA[64 * AS];
  __shared__ short sH[64 * HS];
  __shared__ int sDst[64];

  const int tid = threadIdx.x;
  const int e0 = blockIdx.x * 64;
  const int le = tid >> 2;
  const int lq = tid & 3;
  const int wv = tid >> 6;
  const int l = tid & 63;
  const int lr = l & 15;
  const int kq = l >> 4;

  // ---- B1 fragments -> registers (18 independent L2 loads, issued first) ----
  const short8* bp1 = (const short8*)pW1;
  short8 b1f[18];
#pragma unroll
  for (int kt = 0; kt < 9; ++kt)
#pragma unroll
    for (int c = 0; c < 2; ++c)
      b1f[kt * 2 + c] = bp1[(kt * 8 + wv * 2 + c) * 64 + l];

  // ---- stage A = [x[src] | x[dst] | ea] as bf16 (latency hides B1 loads) ----
  {
    const int gsrc = srcD[e0 + le];
    const int gdst = dstD[e0 + le];
    if (lq == 0) sDst[le] = gdst;
    const float4* xs = (const float4*)(x + (size_t)gsrc * HH);
    const float4* xd = (const float4*)(x + (size_t)gdst * HH);
    short* row = &sA[le * AS];
#pragma unroll
    for (int i = 0; i < 4; ++i)
      cvt_store8(row + lq * 32 + i * 8, xs[lq * 8 + i * 2], xs[lq * 8 + i * 2 + 1]);
#pragma unroll
    for (int i = 0; i < 4; ++i)
      cvt_store8(row + 128 + lq * 32 + i * 8, xd[lq * 8 + i * 2], xd[lq * 8 + i * 2 + 1]);
    const float4* es = (const float4*)(ea + (size_t)(e0 + le) * EDD);
    cvt_store8(row + 256 + lq * 8, es[lq * 2], es[lq * 2 + 1]);
  }
  __syncthreads();

  // ---- GEMM1: [64 x 288] @ [288 x 32(wave)] ----
  f32x4 acc[4][2];
  const f32x4 zero = {0.f, 0.f, 0.f, 0.f};
#pragma unroll
  for (int m = 0; m < 4; ++m) { acc[m][0] = zero; acc[m][1] = zero; }

  const short* ab = &sA[lr * AS + kq * 8];
#pragma unroll
  for (int kt = 0; kt < 9; ++kt) {
    short8 af[4];
#pragma unroll
    for (int m = 0; m < 4; ++m)
      af[m] = *(const short8*)(ab + m * 16 * AS + kt * 32);
#pragma unroll
    for (int m = 0; m < 4; ++m)
#pragma unroll
      for (int c = 0; c < 2; ++c)
        acc[m][c] = __builtin_amdgcn_mfma_f32_16x16x32_bf16(af[m], b1f[kt * 2 + c], acc[m][c], 0, 0, 0);
  }

  // ---- B2 fragments -> registers (latency hides under GELU + barrier) ----
  const short8* bp2 = (const short8*)pW2;
  short8 b2f[8];
#pragma unroll
  for (int kt = 0; kt < 4; ++kt)
#pragma unroll
    for (int c = 0; c < 2; ++c)
      b2f[kt * 2 + c] = bp2[(kt * 8 + wv * 2 + c) * 64 + l];

  // ---- bias + GELU -> sH ----
  // C/D layout: col = ct*16 + lr, row = kq*4 + reg (+16m)
#pragma unroll
  for (int c = 0; c < 2; ++c) {
    const int col = wv * 32 + c * 16 + lr;
    const float b1v = b1[col];
#pragma unroll
    for (int m = 0; m < 4; ++m)
#pragma unroll
      for (int r = 0; r < 4; ++r)
        sH[(m * 16 + kq * 4 + r) * HS + col] = f2b(gelu_f(acc[m][c][r] + b1v));
  }
  __syncthreads();

  // ---- GEMM2: [64 x 128] @ [128 x 32(wave)] ----
  f32x4 acc2[4][2];
#pragma unroll
  for (int m = 0; m < 4; ++m) { acc2[m][0] = zero; acc2[m][1] = zero; }
  const short* hb = &sH[lr * HS + kq * 8];
#pragma unroll
  for (int kt = 0; kt < 4; ++kt) {
    short8 af[4];
#pragma unroll
    for (int m = 0; m < 4; ++m)
      af[m] = *(const short8*)(hb + m * 16 * HS + kt * 32);
#pragma unroll
    for (int m = 0; m < 4; ++m)
#pragma unroll
      for (int c = 0; c < 2; ++c)
        acc2[m][c] = __builtin_amdgcn_mfma_f32_16x16x32_bf16(af[m], b2f[kt * 2 + c], acc2[m][c], 0, 0, 0);
  }

  // ---- + b2, atomic scatter ----
#pragma unroll
  for (int c = 0; c < 2; ++c) {
    const int col = wv * 32 + c * 16 + lr;
    const float b2v = b2[col];
#pragma unroll
    for (int m = 0; m < 4; ++m)
#pragma unroll
      for (int r = 0; r < 4; ++r) {
        const int row = m * 16 + kq * 4 + r;
        atomicAdd(&agg[(size_t)sDst[row] * HH + col], acc2[m][c][r] + b2v);
      }
  }
}

// ---------------------------------------------------------------------------
// Kernel 4: node MLP + residual + LayerNorm, column-split waves, B in regs.
// ---------------------------------------------------------------------------
#define NS 264
__global__ __launch_bounds__(256, 2) void k_node(
    const float* __restrict__ x, const float* __restrict__ agg,
    const float* __restrict__ cnt,
    const short* __restrict__ pW1, const float* __restrict__ b1,
    const short* __restrict__ pW2, const float* __restrict__ b2,
    const float* __restrict__ g, const float* __restrict__ be,
    float* __restrict__ out) {
  __shared__ short sA[64 * NS];
  __shared__ short sH[64 * HS];
  __shared__ float sP[64 * 4];
  __shared__ float sP2[64 * 4];

  const int tid = threadIdx.x;
  const int r0 = blockIdx.x * 64;
  const int le = tid >> 2;
  const int lq = tid & 3;
  const int wv = tid >> 6;
  const int l = tid & 63;
  const int lr = l & 15;
  const int kq = l >> 4;

  // ---- B1 fragments -> registers ----
  const short8* bp1 = (const short8*)pW1;
  short8 b1f[16];
#pragma unroll
  for (int kt = 0; kt < 8; ++kt)
#pragma unroll
    for (int c = 0; c < 2; ++c)
      b1f[kt * 2 + c] = bp1[(kt * 8 + wv * 2 + c) * 64 + l];

  // ---- stage A = [x | agg*rinv] as bf16 ----
  {
    const int gr = r0 + le;
    short* row = &sA[le * NS];
    if (gr < NN) {
      float rinv = 1.0f / (cnt[gr] + 1e-8f);
      const float4* xs = (const float4*)(x + (size_t)gr * HH);
      const float4* as_ = (const float4*)(agg + (size_t)gr * HH);
#pragma unroll
      for (int i = 0; i < 4; ++i)
        cvt_store8(row + lq * 32 + i * 8, xs[lq * 8 + i * 2], xs[lq * 8 + i * 2 + 1]);
#pragma unroll
      for (int i = 0; i < 4; ++i) {
        float4 a = as_[lq * 8 + i * 2], b = as_[lq * 8 + i * 2 + 1];
        a.x *= rinv; a.y *= rinv; a.z *= rinv; a.w *= rinv;
        b.x *= rinv; b.y *= rinv; b.z *= rinv; b.w *= rinv;
        cvt_store8(row + 128 + lq * 32 + i * 8, a, b);
      }
    } else {
      short8 z = {0, 0, 0, 0, 0, 0, 0, 0};
#pragma unroll
      for (int i = 0; i < 8; ++i) *(short8*)(row + lq * 64 + i * 8) = z;
    }
  }
  __syncthreads();

  // ---- GEMM1: [64 x 256] @ [256 x 32(wave)] ----
  f32x4 acc[4][2];
  const f32x4 zero = {0.f, 0.f, 0.f, 0.f};
#pragma unroll
  for (int m = 0; m < 4; ++m) { acc[m][0] = zero; acc[m][1] = zero; }
  const short* ab = &sA[lr * NS + kq * 8];
#pragma unroll
  for (int kt = 0; kt < 8; ++kt) {
    short8 af[4];
#pragma unroll
    for (int m = 0; m < 4; ++m)
      af[m] = *(const short8*)(ab + m * 16 * NS + kt * 32);
#pragma unroll
    for (int m = 0; m < 4; ++m)
#pragma unroll
      for (int c = 0; c < 2; ++c)
        acc[m][c] = __builtin_amdgcn_mfma_f32_16x16x32_bf16(af[m], b1f[kt * 2 + c], acc[m][c], 0, 0, 0);
  }

  // ---- B2 fragments -> registers ----
  const short8* bp2 = (const short8*)pW2;
  short8 b2f[8];
#pragma unroll
  for (int kt = 0; kt < 4; ++kt)
#pragma unroll
    for (int c = 0; c < 2; ++c)
      b2f[kt * 2 + c] = bp2[(kt * 8 + wv * 2 + c) * 64 + l];

  // ---- bias + GELU -> sH ----
#pragma unroll
  for (int c = 0; c < 2; ++c) {
    const int col = wv * 32 + c * 16 + lr;
    const float b1v = b1[col];
#pragma unroll
    for (int m = 0; m < 4; ++m)
#pragma unroll
      for (int r = 0; r < 4; ++r)
        sH[(m * 16 + kq * 4 + r) * HS + col] = f2b(gelu_f(acc[m][c][r] + b1v));
  }
  __syncthreads();

  // ---- GEMM2: [64 x 128] @ [128 x 32(wave)] ----
  f32x4 acc2[4][2];
#pragma unroll
  for (int m = 0; m < 4; ++m) { acc2[m][0] = zero; acc2[m][1] = zero; }
  const short* hb = &sH[lr * HS + kq * 8];
#pragma unroll
  for (int kt = 0; kt < 4; ++kt) {
    short8 af[4];
#pragma unroll
    for (int m = 0; m < 4; ++m)
      af[m] = *(const short8*)(hb + m * 16 * HS + kt * 32);
#pragma unroll
    for (int m = 0; m < 4; ++m)
#pragma unroll
      for (int c = 0; c < 2; ++c)
        acc2[m][c] = __builtin_amdgcn_mfma_f32_16x16x32_bf16(af[m], b2f[kt * 2 + c], acc2[m][c], 0, 0, 0);
  }

  // ---- + b2 + residual; cross-wave LN partial sums ----
  float val[4][2][4];
#pragma unroll
  for (int c = 0; c < 2; ++c) {
    const int col = wv * 32 + c * 16 + lr;
    const float b2v = b2[col];
#pragma unroll
    for (int m = 0; m < 4; ++m)
#pragma unroll
      for (int r = 0; r < 4; ++r) {
        const int row = r0 + m * 16 + kq * 4 + r;
        float xr = (row < NN) ? x[(size_t)row * HH + col] : 0.f;
        val[m][c][r] = acc2[m][c][r] + b2v + xr;
      }
  }
#pragma unroll
  for (int m = 0; m < 4; ++m)
#pragma unroll
    for (int r = 0; r < 4; ++r) {
      float s = val[m][0][r] + val[m][1][r];
      float s2 = val[m][0][r] * val[m][0][r] + val[m][1][r] * val[m][1][r];
#pragma unroll
      for (int o = 1; o < 16; o <<= 1) {
        s += __shfl_xor(s, o);
        s2 += __shfl_xor(s2, o);
      }
      if (lr == 0) {
        const int row = m * 16 + kq * 4 + r;
        sP[row * 4 + wv] = s;
        sP2[row * 4 + wv] = s2;
      }
    }
  __syncthreads();

  // ---- LN finalize + store ----
#pragma unroll
  for (int c = 0; c < 2; ++c) {
    const int col = wv * 32 + c * 16 + lr;
    const float gv = g[col];
    const float bv = be[col];
#pragma unroll
    for (int m = 0; m < 4; ++m)
#pragma unroll
      for (int r = 0; r < 4; ++r) {
        const int lrow = m * 16 + kq * 4 + r;
        const int row = r0 + lrow;
        if (row < NN) {
          float4 ps = *(float4*)&sP[lrow * 4];
          float4 qs = *(float4*)&sP2[lrow * 4];
          float s = ps.x + ps.y + ps.z + ps.w;
          float s2 = qs.x + qs.y + qs.z + qs.w;
          float mu = s * 0.0078125f;
          float var = s2 * 0.0078125f - mu * mu;
          float rs = rsqrtf(var + 1e-5f);
          out[(size_t)row * HH + col] = (val[m][c][r] - mu) * rs * gv + bv;
        }
      }
  }
}

extern "C" void kernel_launch(void* const* d_in, const int* in_sizes, int n_in,
                              void* d_out, int out_size, void* d_ws, size_t ws_size,
                              hipStream_t stream) {
  const float* x = (const float*)d_in[0];
  const void* ei = d_in[1];
  const float* ea = (const float*)d_in[2];
  const float* eW1 = (const float*)d_in[3];
  const float* eb1 = (const float*)d_in[4];
  const float* eW2 = (const float*)d_in[5];
  const float* eb2 = (const float*)d_in[6];
  const float* nW1 = (const float*)d_in[7];
  const float* nb1 = (const float*)d_in[8];
  const float* nW2 = (const float*)d_in[9];
  const float* nb2 = (const float*)d_in[10];
  const float* lng = (const float*)d_in[11];
  const float* lnb = (const float*)d_in[12];
  float* out = (float*)d_out;

  // ws layout
  char* w = (char*)d_ws;
  size_t off = 0;
  float* agg = (float*)(w + off); off += (size_t)NN * HH * 4;
  float* cnt = (float*)(w + off); off += (size_t)NN * 4;
  short* pe1 = (short*)(w + off); off += (size_t)9 * 512 * 8 * 2;
  short* pe2 = (short*)(w + off); off += (size_t)4 * 512 * 8 * 2;
  short* pn1 = (short*)(w + off); off += (size_t)8 * 512 * 8 * 2;
  short* pn2 = (short*)(w + off); off += (size_t)4 * 512 * 8 * 2;
  int* srcD = (int*)(w + off); off += (size_t)EE * 4;
  int* dstD = (int*)(w + off); off += (size_t)EE * 4;
  int* flag = (int*)(w + off);

  hipMemsetAsync(agg, 0, (size_t)NN * HH * 4 + (size_t)NN * 4, stream);
  k_detect<<<1, 256, 0, stream>>>((const long long*)ei, 2048, (long long)NN, flag);
  k_idx_count<<<(EE + 255) / 256, 256, 0, stream>>>(ei, EE, srcD, dstD, cnt, flag);
  k_pack_all<<<200, 64, 0, stream>>>(eW1, eW2, nW1, nW2, pe1, pe2, pn1, pn2);
  k_edge<<<EE / 64, 256, 0, stream>>>(x, ea, pe1, eb1, pe2, eb2, srcD, dstD, agg);
  k_node<<<(NN + 63) / 64, 256, 0, stream>>>(x, agg, cnt, pn1, nb1, pn2, nb2, lng, lnb, out);
}

// Round 4
// 387.358 us; speedup vs baseline: 6.3411x; 1.0511x over previous
//
#include <hip/hip_runtime.h>
#include <hip/hip_bf16.h>
#include <math.h>

#define NN 50000
#define HH 128
#define EE 600000
#define EDD 32

typedef __attribute__((ext_vector_type(8))) short short8;
typedef __attribute__((ext_vector_type(4))) float f32x4;

// ---------------------------------------------------------------------------
// Kernel 0: detect whether edge_index buffer is int64 or int32.
// ---------------------------------------------------------------------------
__global__ void k_detect(const long long* __restrict__ ei, int n_check,
                         long long nmax, int* __restrict__ flag) {
  __shared__ int bad;
  if (threadIdx.x == 0) bad = 0;
  __syncthreads();
  for (int i = threadIdx.x; i < n_check; i += blockDim.x) {
    long long v = ei[i];
    if (v < 0 || v >= nmax) bad = 1;
  }
  __syncthreads();
  if (threadIdx.x == 0) *flag = (bad ? 0 : 1);
}

// ---------------------------------------------------------------------------
// Kernel 1: indices -> int32 + per-destination edge count.
// ---------------------------------------------------------------------------
__global__ void k_idx_count(const void* __restrict__ eiv, int E,
                            int* __restrict__ srcD, int* __restrict__ dstD,
                            float* __restrict__ cnt, const int* __restrict__ flag) {
  int e = blockIdx.x * blockDim.x + threadIdx.x;
  if (e >= E) return;
  int s, d;
  if (*flag) {
    const long long* p = (const long long*)eiv;
    s = (int)p[e];
    d = (int)p[E + e];
  } else {
    const int* p = (const int*)eiv;
    s = p[e];
    d = p[E + e];
  }
  srcD[e] = s;
  dstD[e] = d;
  atomicAdd(&cnt[d], 1.0f);
}

__device__ __forceinline__ short f2b(float f) {
  __hip_bfloat16 h = __float2bfloat16(f);
  return *reinterpret_cast<short*>(&h);
}

__device__ __forceinline__ void cvt_store8(short* d, const float4 a, const float4 b) {
  short8 v = {f2b(a.x), f2b(a.y), f2b(a.z), f2b(a.w),
              f2b(b.x), f2b(b.y), f2b(b.z), f2b(b.w)};
  *(short8*)d = v;
}

// ---------------------------------------------------------------------------
// Kernel 2: fp32 -> bf16 bulk convert (8 elems/thread).
// ---------------------------------------------------------------------------
__global__ void k_cvt(const float* __restrict__ in, short* __restrict__ o, int n8) {
  int i = blockIdx.x * blockDim.x + threadIdx.x;
  if (i >= n8) return;
  const float4* p = (const float4*)in + (size_t)i * 2;
  cvt_store8(o + (size_t)i * 8, p[0], p[1]);
}

// ---------------------------------------------------------------------------
// Kernel 3: pack all 4 fp32 weight matrices into bf16 MFMA B-fragment order:
//   P[((kt*8+ct)*64 + lane)*8 + j] = W[kt*32 + (lane>>4)*8 + j][ct*16 + (lane&15)]
// ---------------------------------------------------------------------------
__global__ void k_pack_all(const float* __restrict__ eW1, const float* __restrict__ eW2,
                           const float* __restrict__ nW1, const float* __restrict__ nW2,
                           short* __restrict__ pe1, short* __restrict__ pe2,
                           short* __restrict__ pn1, short* __restrict__ pn2) {
  int blk = blockIdx.x;
  const float* W;
  short* P;
  int b;
  if (blk < 72)       { W = eW1; P = pe1; b = blk; }
  else if (blk < 104) { W = eW2; P = pe2; b = blk - 72; }
  else if (blk < 168) { W = nW1; P = pn1; b = blk - 104; }
  else                { W = nW2; P = pn2; b = blk - 168; }
  const int kt = b >> 3, ct = b & 7;
  const int l = threadIdx.x;
  short8 v;
#pragma unroll
  for (int j = 0; j < 8; ++j) {
    float f = W[(size_t)(kt * 32 + ((l >> 4) * 8 + j)) * HH + ct * 16 + (l & 15)];
    v[j] = f2b(f);
  }
  *(short8*)(P + ((size_t)b * 64 + l) * 8) = v;
}

// overflow-safe tanh-form GELU
__device__ __forceinline__ float gelu_f(float v) {
  float u = 0.7978845608028654f * v * fmaf(0.044715f, v * v, 1.0f);
  float e = __expf(2.0f * u);
  float th = 1.0f - 2.0f / (e + 1.0f);
  return 0.5f * v * (1.0f + th);
}

// ---------------------------------------------------------------------------
// Kernel 4: edge MLP via bf16 MFMA, column-split waves, single LDS buffer.
// 256 threads = 4 waves; 64 edges/block; wave w owns cols [32w, 32w+32).
// sA holds A (64 x 288 bf16); after GEMM1, cols 0..127 are reused for GELU(h).
// ---------------------------------------------------------------------------
#define AS 296   // row stride (shorts): 592B -> benign aliasing
__global__ __launch_bounds__(256, 4) void k_edge(
    const short* __restrict__ xb, const short* __restrict__ eab,
    const short* __restrict__ pW1, const float* __restrict__ b1,
    const short* __restrict__ pW2, const float* __restrict__ b2,
    const int* __restrict__ srcD, const int* __restrict__ dstD,
    float* __restrict__ agg) {
  __shared__ short sA[64 * AS];
  __shared__ int sSrc[64];
  __shared__ int sDst[64];

  const int tid = threadIdx.x;
  const int e0 = blockIdx.x * 64;
  const int wv = tid >> 6;
  const int l = tid & 63;
  const int lr = l & 15;
  const int kq = l >> 4;

  // ---- B1 fragments -> registers (independent L2 loads, issued first) ----
  const short8* bp1 = (const short8*)pW1;
  short8 b1f[18];
#pragma unroll
  for (int kt = 0; kt < 9; ++kt)
#pragma unroll
    for (int c = 0; c < 2; ++c)
      b1f[kt * 2 + c] = bp1[(kt * 8 + wv * 2 + c) * 64 + l];

  if (tid < 64) {
    sSrc[tid] = srcD[e0 + tid];
    sDst[tid] = dstD[e0 + tid];
  }
  __syncthreads();

  // ---- stage A = [xb[src] | xb[dst] | eab] : 36 16B-chunks per row ----
#pragma unroll
  for (int k = 0; k < 9; ++k) {
    int idx = tid + 256 * k;
    int row = idx / 36;
    int c = idx - row * 36;
    const short8* gp;
    if (c < 16)
      gp = (const short8*)(xb + (size_t)sSrc[row] * HH) + c;
    else if (c < 32)
      gp = (const short8*)(xb + (size_t)sDst[row] * HH) + (c - 16);
    else
      gp = (const short8*)(eab + (size_t)(e0 + row) * EDD) + (c - 32);
    *(short8*)&sA[row * AS + c * 8] = *gp;
  }
  __syncthreads();

  // ---- GEMM1: [64 x 288] @ [288 x 32(wave)] ----
  f32x4 acc[4][2];
  const f32x4 zero = {0.f, 0.f, 0.f, 0.f};
#pragma unroll
  for (int m = 0; m < 4; ++m) { acc[m][0] = zero; acc[m][1] = zero; }

  const short* ab = &sA[lr * AS + kq * 8];
#pragma unroll
  for (int kt = 0; kt < 9; ++kt) {
    short8 af[4];
#pragma unroll
    for (int m = 0; m < 4; ++m)
      af[m] = *(const short8*)(ab + m * 16 * AS + kt * 32);
#pragma unroll
    for (int m = 0; m < 4; ++m)
#pragma unroll
      for (int c = 0; c < 2; ++c)
        acc[m][c] = __builtin_amdgcn_mfma_f32_16x16x32_bf16(af[m], b1f[kt * 2 + c], acc[m][c], 0, 0, 0);
  }

  // ---- B2 fragments -> registers ----
  const short8* bp2 = (const short8*)pW2;
  short8 b2f[8];
#pragma unroll
  for (int kt = 0; kt < 4; ++kt)
#pragma unroll
    for (int c = 0; c < 2; ++c)
      b2f[kt * 2 + c] = bp2[(kt * 8 + wv * 2 + c) * 64 + l];

  __syncthreads();   // all waves done reading sA before overwrite

  // ---- bias + GELU -> sA cols 0..127 ----
  // C/D layout: col = ct*16 + lr, row = kq*4 + reg (+16m)
#pragma unroll
  for (int c = 0; c < 2; ++c) {
    const int col = wv * 32 + c * 16 + lr;
    const float b1v = b1[col];
#pragma unroll
    for (int m = 0; m < 4; ++m)
#pragma unroll
      for (int r = 0; r < 4; ++r)
        sA[(m * 16 + kq * 4 + r) * AS + col] = f2b(gelu_f(acc[m][c][r] + b1v));
  }
  __syncthreads();

  // ---- GEMM2: [64 x 128] @ [128 x 32(wave)] ----
  f32x4 acc2[4][2];
#pragma unroll
  for (int m = 0; m < 4; ++m) { acc2[m][0] = zero; acc2[m][1] = zero; }
#pragma unroll
  for (int kt = 0; kt < 4; ++kt) {
    short8 af[4];
#pragma unroll
    for (int m = 0; m < 4; ++m)
      af[m] = *(const short8*)(ab + m * 16 * AS + kt * 32);
#pragma unroll
    for (int m = 0; m < 4; ++m)
#pragma unroll
      for (int c = 0; c < 2; ++c)
        acc2[m][c] = __builtin_amdgcn_mfma_f32_16x16x32_bf16(af[m], b2f[kt * 2 + c], acc2[m][c], 0, 0, 0);
  }

  // ---- + b2, atomic scatter ----
#pragma unroll
  for (int c = 0; c < 2; ++c) {
    const int col = wv * 32 + c * 16 + lr;
    const float b2v = b2[col];
#pragma unroll
    for (int m = 0; m < 4; ++m)
#pragma unroll
      for (int r = 0; r < 4; ++r) {
        const int row = m * 16 + kq * 4 + r;
        atomicAdd(&agg[(size_t)sDst[row] * HH + col], acc2[m][c][r] + b2v);
      }
  }
}

// ---------------------------------------------------------------------------
// Kernel 5: node MLP + residual + LayerNorm, column-split waves, single buffer.
// ---------------------------------------------------------------------------
#define NS 264
__global__ __launch_bounds__(256, 4) void k_node(
    const float* __restrict__ x, const short* __restrict__ xb,
    const float* __restrict__ agg, const float* __restrict__ cnt,
    const short* __restrict__ pW1, const float* __restrict__ b1,
    const short* __restrict__ pW2, const float* __restrict__ b2,
    const float* __restrict__ g, const float* __restrict__ be,
    float* __restrict__ out) {
  __shared__ short sA[64 * NS];
  __shared__ float sP[64 * 4];
  __shared__ float sP2[64 * 4];

  const int tid = threadIdx.x;
  const int r0 = blockIdx.x * 64;
  const int le = tid >> 2;
  const int lq = tid & 3;
  const int wv = tid >> 6;
  const int l = tid & 63;
  const int lr = l & 15;
  const int kq = l >> 4;

  // ---- B1 fragments -> registers ----
  const short8* bp1 = (const short8*)pW1;
  short8 b1f[16];
#pragma unroll
  for (int kt = 0; kt < 8; ++kt)
#pragma unroll
    for (int c = 0; c < 2; ++c)
      b1f[kt * 2 + c] = bp1[(kt * 8 + wv * 2 + c) * 64 + l];

  // ---- stage A = [xb | agg*rinv] as bf16 ----
  {
    const int gr = r0 + le;
    short* row = &sA[le * NS];
    if (gr < NN) {
      float rinv = 1.0f / (cnt[gr] + 1e-8f);
      const short8* xp = (const short8*)(xb + (size_t)gr * HH);
#pragma unroll
      for (int i = 0; i < 4; ++i)
        *(short8*)(row + lq * 32 + i * 8) = xp[lq * 4 + i];
      const float4* as_ = (const float4*)(agg + (size_t)gr * HH);
#pragma unroll
      for (int i = 0; i < 4; ++i) {
        float4 a = as_[lq * 8 + i * 2], b = as_[lq * 8 + i * 2 + 1];
        a.x *= rinv; a.y *= rinv; a.z *= rinv; a.w *= rinv;
        b.x *= rinv; b.y *= rinv; b.z *= rinv; b.w *= rinv;
        cvt_store8(row + 128 + lq * 32 + i * 8, a, b);
      }
    } else {
      short8 z = {0, 0, 0, 0, 0, 0, 0, 0};
#pragma unroll
      for (int i = 0; i < 8; ++i) *(short8*)(row + lq * 64 + i * 8) = z;
    }
  }
  __syncthreads();

  // ---- GEMM1: [64 x 256] @ [256 x 32(wave)] ----
  f32x4 acc[4][2];
  const f32x4 zero = {0.f, 0.f, 0.f, 0.f};
#pragma unroll
  for (int m = 0; m < 4; ++m) { acc[m][0] = zero; acc[m][1] = zero; }
  const short* ab = &sA[lr * NS + kq * 8];
#pragma unroll
  for (int kt = 0; kt < 8; ++kt) {
    short8 af[4];
#pragma unroll
    for (int m = 0; m < 4; ++m)
      af[m] = *(const short8*)(ab + m * 16 * NS + kt * 32);
#pragma unroll
    for (int m = 0; m < 4; ++m)
#pragma unroll
      for (int c = 0; c < 2; ++c)
        acc[m][c] = __builtin_amdgcn_mfma_f32_16x16x32_bf16(af[m], b1f[kt * 2 + c], acc[m][c], 0, 0, 0);
  }

  // ---- B2 fragments -> registers ----
  const short8* bp2 = (const short8*)pW2;
  short8 b2f[8];
#pragma unroll
  for (int kt = 0; kt < 4; ++kt)
#pragma unroll
    for (int c = 0; c < 2; ++c)
      b2f[kt * 2 + c] = bp2[(kt * 8 + wv * 2 + c) * 64 + l];

  __syncthreads();

  // ---- bias + GELU -> sA cols 0..127 ----
#pragma unroll
  for (int c = 0; c < 2; ++c) {
    const int col = wv * 32 + c * 16 + lr;
    const float b1v = b1[col];
#pragma unroll
    for (int m = 0; m < 4; ++m)
#pragma unroll
      for (int r = 0; r < 4; ++r)
        sA[(m * 16 + kq * 4 + r) * NS + col] = f2b(gelu_f(acc[m][c][r] + b1v));
  }
  __syncthreads();

  // ---- GEMM2: [64 x 128] @ [128 x 32(wave)] ----
  f32x4 acc2[4][2];
#pragma unroll
  for (int m = 0; m < 4; ++m) { acc2[m][0] = zero; acc2[m][1] = zero; }
#pragma unroll
  for (int kt = 0; kt < 4; ++kt) {
    short8 af[4];
#pragma unroll
    for (int m = 0; m < 4; ++m)
      af[m] = *(const short8*)(ab + m * 16 * NS + kt * 32);
#pragma unroll
    for (int m = 0; m < 4; ++m)
#pragma unroll
      for (int c = 0; c < 2; ++c)
        acc2[m][c] = __builtin_amdgcn_mfma_f32_16x16x32_bf16(af[m], b2f[kt * 2 + c], acc2[m][c], 0, 0, 0);
  }

  // ---- + b2 + residual; cross-wave LN partial sums ----
  float val[4][2][4];
#pragma unroll
  for (int c = 0; c < 2; ++c) {
    const int col = wv * 32 + c * 16 + lr;
    const float b2v = b2[col];
#pragma unroll
    for (int m = 0; m < 4; ++m)
#pragma unroll
      for (int r = 0; r < 4; ++r) {
        const int row = r0 + m * 16 + kq * 4 + r;
        float xr = (row < NN) ? x[(size_t)row * HH + col] : 0.f;
        val[m][c][r] = acc2[m][c][r] + b2v + xr;
      }
  }
#pragma unroll
  for (int m = 0; m < 4; ++m)
#pragma unroll
    for (int r = 0; r < 4; ++r) {
      float s = val[m][0][r] + val[m][1][r];
      float s2 = val[m][0][r] * val[m][0][r] + val[m][1][r] * val[m][1][r];
#pragma unroll
      for (int o = 1; o < 16; o <<= 1) {
        s += __shfl_xor(s, o);
        s2 += __shfl_xor(s2, o);
      }
      if (lr == 0) {
        const int row = m * 16 + kq * 4 + r;
        sP[row * 4 + wv] = s;
        sP2[row * 4 + wv] = s2;
      }
    }
  __syncthreads();

  // ---- LN finalize + store ----
#pragma unroll
  for (int c = 0; c < 2; ++c) {
    const int col = wv * 32 + c * 16 + lr;
    const float gv = g[col];
    const float bv = be[col];
#pragma unroll
    for (int m = 0; m < 4; ++m)
#pragma unroll
      for (int r = 0; r < 4; ++r) {
        const int lrow = m * 16 + kq * 4 + r;
        const int row = r0 + lrow;
        if (row < NN) {
          float4 ps = *(float4*)&sP[lrow * 4];
          float4 qs = *(float4*)&sP2[lrow * 4];
          float s = ps.x + ps.y + ps.z + ps.w;
          float s2 = qs.x + qs.y + qs.z + qs.w;
          float mu = s * 0.0078125f;
          float var = s2 * 0.0078125f - mu * mu;
          float rs = rsqrtf(var + 1e-5f);
          out[(size_t)row * HH + col] = (val[m][c][r] - mu) * rs * gv + bv;
        }
      }
  }
}

extern "C" void kernel_launch(void* const* d_in, const int* in_sizes, int n_in,
                              void* d_out, int out_size, void* d_ws, size_t ws_size,
                              hipStream_t stream) {
  const float* x = (const float*)d_in[0];
  const void* ei = d_in[1];
  const float* ea = (const float*)d_in[2];
  const float* eW1 = (const float*)d_in[3];
  const float* eb1 = (const float*)d_in[4];
  const float* eW2 = (const float*)d_in[5];
  const float* eb2 = (const float*)d_in[6];
  const float* nW1 = (const float*)d_in[7];
  const float* nb1 = (const float*)d_in[8];
  const float* nW2 = (const float*)d_in[9];
  const float* nb2 = (const float*)d_in[10];
  const float* lng = (const float*)d_in[11];
  const float* lnb = (const float*)d_in[12];
  float* out = (float*)d_out;

  // ws layout (all 256B-aligned)
  char* w = (char*)d_ws;
  size_t off = 0;
  auto alloc = [&](size_t bytes) { void* p = w + off; off = (off + bytes + 255) & ~(size_t)255; return p; };
  float* agg = (float*)alloc((size_t)NN * HH * 4);        // 25.6 MB
  float* cnt = (float*)alloc((size_t)NN * 4);             // 200 KB
  short* pe1 = (short*)alloc((size_t)72 * 512 * 2);
  short* pe2 = (short*)alloc((size_t)32 * 512 * 2);
  short* pn1 = (short*)alloc((size_t)64 * 512 * 2);
  short* pn2 = (short*)alloc((size_t)32 * 512 * 2);
  int* srcD = (int*)alloc((size_t)EE * 4);
  int* dstD = (int*)alloc((size_t)EE * 4);
  int* flag = (int*)alloc(256);
  short* xb = (short*)alloc((size_t)NN * HH * 2);         // 12.8 MB
  short* eab = (short*)alloc((size_t)EE * EDD * 2);       // 38.4 MB

  hipMemsetAsync(agg, 0, (size_t)NN * HH * 4 + (size_t)NN * 4, stream);
  k_detect<<<1, 256, 0, stream>>>((const long long*)ei, 2048, (long long)NN, flag);
  k_idx_count<<<(EE + 255) / 256, 256, 0, stream>>>(ei, EE, srcD, dstD, cnt, flag);
  k_cvt<<<(NN * HH / 8 + 255) / 256, 256, 0, stream>>>(x, xb, NN * HH / 8);
  k_cvt<<<(EE * EDD / 8 + 255) / 256, 256, 0, stream>>>(ea, eab, EE * EDD / 8);
  k_pack_all<<<200, 64, 0, stream>>>(eW1, eW2, nW1, nW2, pe1, pe2, pn1, pn2);
  k_edge<<<EE / 64, 256, 0, stream>>>(xb, eab, pe1, eb1, pe2, eb2, srcD, dstD, agg);
  k_node<<<(NN + 63) / 64, 256, 0, stream>>>(x, xb, agg, cnt, pn1, nb1, pn2, nb2, lng, lnb, out);
}

// Round 5
// 260.450 us; speedup vs baseline: 9.4308x; 1.4873x over previous
//
#include <hip/hip_runtime.h>
#include <hip/hip_bf16.h>
#include <math.h>

#define NN 50000
#define HH 128
#define EE 600000
#define EDD 32
#define NBINS 50176   // 196*256 >= NN

typedef __attribute__((ext_vector_type(8))) short short8;
typedef __attribute__((ext_vector_type(4))) float f32x4;

// ---------------------------------------------------------------------------
// Kernel 0: detect int64 vs int32 edge_index. flag=1 -> int64.
// ---------------------------------------------------------------------------
__global__ void k_detect(const long long* __restrict__ ei, int n_check,
                         long long nmax, int* __restrict__ flag) {
  __shared__ int bad;
  if (threadIdx.x == 0) bad = 0;
  __syncthreads();
  for (int i = threadIdx.x; i < n_check; i += blockDim.x) {
    long long v = ei[i];
    if (v < 0 || v >= nmax) bad = 1;
  }
  __syncthreads();
  if (threadIdx.x == 0) *flag = (bad ? 0 : 1);
}

// ---------------------------------------------------------------------------
// Kernel 1: indices -> int32 + int histogram of dst.
// ---------------------------------------------------------------------------
__global__ void k_idx_count(const void* __restrict__ eiv,
                            int* __restrict__ srcD, int* __restrict__ dstD,
                            int* __restrict__ chist, const int* __restrict__ flag) {
  int e = blockIdx.x * blockDim.x + threadIdx.x;
  if (e >= EE) return;
  int s, d;
  if (*flag) {
    const long long* p = (const long long*)eiv;
    s = (int)p[e];
    d = (int)p[EE + e];
  } else {
    const int* p = (const int*)eiv;
    s = p[e];
    d = p[EE + e];
  }
  srcD[e] = s;
  dstD[e] = d;
  atomicAdd(&chist[d], 1);
}

// ---------------------------------------------------------------------------
// Scan chain: exclusive prefix over NBINS bins.
// ---------------------------------------------------------------------------
__global__ void k_scan1(const int* __restrict__ chist, int* __restrict__ tmp,
                        int* __restrict__ bsum) {
  __shared__ int buf[2][256];
  int t = threadIdx.x;
  int i = blockIdx.x * 256 + t;
  buf[0][t] = chist[i];
  __syncthreads();
  int cur = 0;
  for (int o = 1; o < 256; o <<= 1) {
    int v = buf[cur][t];
    if (t >= o) v += buf[cur][t - o];
    buf[cur ^ 1][t] = v;
    __syncthreads();
    cur ^= 1;
  }
  tmp[i] = buf[cur][t];
  if (t == 255) bsum[blockIdx.x] = buf[cur][255];
}

__global__ void k_scan2(int* __restrict__ bsum) {
  __shared__ int buf[2][256];
  int t = threadIdx.x;
  int orig = (t < 196) ? bsum[t] : 0;
  buf[0][t] = orig;
  __syncthreads();
  int cur = 0;
  for (int o = 1; o < 256; o <<= 1) {
    int v = buf[cur][t];
    if (t >= o) v += buf[cur][t - o];
    buf[cur ^ 1][t] = v;
    __syncthreads();
    cur ^= 1;
  }
  if (t < 196) bsum[t] = buf[cur][t] - orig;   // exclusive
}

__global__ void k_scan3(const int* __restrict__ tmp, const int* __restrict__ chist,
                        const int* __restrict__ bsum, int* __restrict__ offs_work) {
  int i = blockIdx.x * 256 + threadIdx.x;
  offs_work[i] = tmp[i] - chist[i] + bsum[blockIdx.x];
}

// ---------------------------------------------------------------------------
// Kernel: scatter edges into dst-sorted order.
// ---------------------------------------------------------------------------
__global__ void k_scatter(const int* __restrict__ srcD, const int* __restrict__ dstD,
                          int* __restrict__ offs_work, int* __restrict__ srcS,
                          int* __restrict__ dstS, int* __restrict__ eidS) {
  int e = blockIdx.x * blockDim.x + threadIdx.x;
  if (e >= EE) return;
  int d = dstD[e];
  int pos = atomicAdd(&offs_work[d], 1);
  srcS[pos] = srcD[e];
  dstS[pos] = d;
  eidS[pos] = e;
}

__device__ __forceinline__ short f2b(float f) {
  __hip_bfloat16 h = __float2bfloat16(f);
  return *reinterpret_cast<short*>(&h);
}
__device__ __forceinline__ float b2f(short s) {
  unsigned u = ((unsigned)(unsigned short)s) << 16;
  return *reinterpret_cast<float*>(&u);
}

__device__ __forceinline__ void cvt_store8(short* d, const float4 a, const float4 b) {
  short8 v = {f2b(a.x), f2b(a.y), f2b(a.z), f2b(a.w),
              f2b(b.x), f2b(b.y), f2b(b.z), f2b(b.w)};
  *(short8*)d = v;
}

// ---------------------------------------------------------------------------
// Kernel: fp32 -> bf16 bulk convert (x only).
// ---------------------------------------------------------------------------
__global__ void k_cvt(const float* __restrict__ in, short* __restrict__ o, int n8) {
  int i = blockIdx.x * blockDim.x + threadIdx.x;
  if (i >= n8) return;
  const float4* p = (const float4*)in + (size_t)i * 2;
  cvt_store8(o + (size_t)i * 8, p[0], p[1]);
}

// ---------------------------------------------------------------------------
// Kernel: pack 4 fp32 weight matrices into bf16 MFMA B-fragment order.
// ---------------------------------------------------------------------------
__global__ void k_pack_all(const float* __restrict__ eW1, const float* __restrict__ eW2,
                           const float* __restrict__ nW1, const float* __restrict__ nW2,
                           short* __restrict__ pe1, short* __restrict__ pe2,
                           short* __restrict__ pn1, short* __restrict__ pn2) {
  int blk = blockIdx.x;
  const float* W;
  short* P;
  int b;
  if (blk < 72)       { W = eW1; P = pe1; b = blk; }
  else if (blk < 104) { W = eW2; P = pe2; b = blk - 72; }
  else if (blk < 168) { W = nW1; P = pn1; b = blk - 104; }
  else                { W = nW2; P = pn2; b = blk - 168; }
  const int kt = b >> 3, ct = b & 7;
  const int l = threadIdx.x;
  short8 v;
#pragma unroll
  for (int j = 0; j < 8; ++j) {
    float f = W[(size_t)(kt * 32 + ((l >> 4) * 8 + j)) * HH + ct * 16 + (l & 15)];
    v[j] = f2b(f);
  }
  *(short8*)(P + ((size_t)b * 64 + l) * 8) = v;
}

// overflow-safe tanh-form GELU
__device__ __forceinline__ float gelu_f(float v) {
  float u = 0.7978845608028654f * v * fmaf(0.044715f, v * v, 1.0f);
  float e = __expf(2.0f * u);
  float th = 1.0f - 2.0f / (e + 1.0f);
  return 0.5f * v * (1.0f + th);
}

// ---------------------------------------------------------------------------
// Kernel: node-level precompute Ps = x@W1a, Pd = x@W1b (bf16 outputs).
// pe1 kt 0..3 = W1a, kt 4..7 = W1b (k-tiles of the packed eW1).
// ---------------------------------------------------------------------------
__global__ __launch_bounds__(256, 2) void k_pre(
    const short* __restrict__ xb, const short* __restrict__ pW1,
    short* __restrict__ Ps, short* __restrict__ Pd) {
  __shared__ short sX[64 * 136];
  const int tid = threadIdx.x;
  const int r0 = blockIdx.x * 64;
  const int le = tid >> 2, lq = tid & 3;
  const int wv = tid >> 6, l = tid & 63, lr = l & 15, kq = l >> 4;

  const short8* bp = (const short8*)pW1;
  short8 fa[8], fb[8];
#pragma unroll
  for (int kt = 0; kt < 4; ++kt)
#pragma unroll
    for (int c = 0; c < 2; ++c) {
      fa[kt * 2 + c] = bp[(kt * 8 + wv * 2 + c) * 64 + l];
      fb[kt * 2 + c] = bp[((kt + 4) * 8 + wv * 2 + c) * 64 + l];
    }
  {
    int gr = r0 + le;
    short* row = &sX[le * 136];
    if (gr < NN) {
      const short8* xp = (const short8*)(xb + (size_t)gr * HH);
#pragma unroll
      for (int i = 0; i < 4; ++i) *(short8*)(row + lq * 32 + i * 8) = xp[lq * 4 + i];
    } else {
      short8 z = {0, 0, 0, 0, 0, 0, 0, 0};
#pragma unroll
      for (int i = 0; i < 4; ++i) *(short8*)(row + lq * 32 + i * 8) = z;
    }
  }
  __syncthreads();

  f32x4 as_[4][2], ad[4][2];
  const f32x4 zero = {0.f, 0.f, 0.f, 0.f};
#pragma unroll
  for (int m = 0; m < 4; ++m) { as_[m][0] = zero; as_[m][1] = zero; ad[m][0] = zero; ad[m][1] = zero; }
  const short* ab = &sX[lr * 136 + kq * 8];
#pragma unroll
  for (int kt = 0; kt < 4; ++kt) {
    short8 af[4];
#pragma unroll
    for (int m = 0; m < 4; ++m) af[m] = *(const short8*)(ab + m * 16 * 136 + kt * 32);
#pragma unroll
    for (int m = 0; m < 4; ++m)
#pragma unroll
      for (int c = 0; c < 2; ++c) {
        as_[m][c] = __builtin_amdgcn_mfma_f32_16x16x32_bf16(af[m], fa[kt * 2 + c], as_[m][c], 0, 0, 0);
        ad[m][c] = __builtin_amdgcn_mfma_f32_16x16x32_bf16(af[m], fb[kt * 2 + c], ad[m][c], 0, 0, 0);
      }
  }
#pragma unroll
  for (int c = 0; c < 2; ++c) {
    const int col = wv * 32 + c * 16 + lr;
#pragma unroll
    for (int m = 0; m < 4; ++m)
#pragma unroll
      for (int r = 0; r < 4; ++r) {
        int grow = r0 + m * 16 + kq * 4 + r;
        if (grow < NN) {
          Ps[(size_t)grow * HH + col] = f2b(as_[m][c][r]);
          Pd[(size_t)grow * HH + col] = f2b(ad[m][c][r]);
        }
      }
  }
}

// ---------------------------------------------------------------------------
// Kernel: edge MLP, dst-sorted, P-gather + K=32 MFMA + GEMM2 + segmented
// reduction. 256 threads = 4 waves col-split; 64 sorted edges/block.
// ---------------------------------------------------------------------------
#define FS 132   // f32 row stride
#define HS2 136  // bf16 row stride
__global__ __launch_bounds__(256, 3) void k_edge(
    const short* __restrict__ Ps, const short* __restrict__ Pd,
    const float* __restrict__ ea,
    const short* __restrict__ pW1, const float* __restrict__ b1,
    const short* __restrict__ pW2, const float* __restrict__ b2,
    const int* __restrict__ srcS, const int* __restrict__ dstS,
    const int* __restrict__ eidS, float* __restrict__ agg) {
  __shared__ float sF[64 * FS];   // P rows (then msg)
  __shared__ short sH[64 * HS2];  // ea tile (cols 0..31), then h
  __shared__ int sDst[64];

  const int tid = threadIdx.x;
  const int e0 = blockIdx.x * 64;
  const int le = tid >> 2, lq = tid & 3;
  const int wv = tid >> 6, l = tid & 63, lr = l & 15, kq = l >> 4;

  // W1c (kt=8) + W2 fragments -> registers
  const short8* bp1 = (const short8*)pW1;
  short8 w1c[2];
#pragma unroll
  for (int c = 0; c < 2; ++c) w1c[c] = bp1[(64 + wv * 2 + c) * 64 + l];
  const short8* bp2 = (const short8*)pW2;
  short8 w2f[8];
#pragma unroll
  for (int kt = 0; kt < 4; ++kt)
#pragma unroll
    for (int c = 0; c < 2; ++c) w2f[kt * 2 + c] = bp2[(kt * 8 + wv * 2 + c) * 64 + l];

  if (tid < 64) sDst[tid] = dstS[e0 + tid];

  // ---- stage: sF = Ps[src]+Pd[dst] (f32); sH cols0..31 = bf16(ea[eid]) ----
  {
    const int gs = srcS[e0 + le];
    const int gd = dstS[e0 + le];
    const int ge = eidS[e0 + le];
    const short8* ps = (const short8*)(Ps + (size_t)gs * HH) + lq * 4;
    const short8* pd = (const short8*)(Pd + (size_t)gd * HH) + lq * 4;
    float* frow = &sF[le * FS + lq * 32];
#pragma unroll
    for (int i = 0; i < 4; ++i) {
      short8 a = ps[i];
      short8 b = pd[i];
      float4 lo = {b2f(a[0]) + b2f(b[0]), b2f(a[1]) + b2f(b[1]),
                   b2f(a[2]) + b2f(b[2]), b2f(a[3]) + b2f(b[3])};
      float4 hi = {b2f(a[4]) + b2f(b[4]), b2f(a[5]) + b2f(b[5]),
                   b2f(a[6]) + b2f(b[6]), b2f(a[7]) + b2f(b[7])};
      *(float4*)(frow + i * 8) = lo;
      *(float4*)(frow + i * 8 + 4) = hi;
    }
    const float4* ep = (const float4*)(ea + (size_t)ge * EDD) + lq * 2;
    cvt_store8(&sH[le * HS2 + lq * 8], ep[0], ep[1]);
  }
  __syncthreads();

  // ---- GEMM1c: [64 x 32] @ [32 x 32(wave)] (single K-tile) ----
  f32x4 acc[4][2];
  const f32x4 zero = {0.f, 0.f, 0.f, 0.f};
#pragma unroll
  for (int m = 0; m < 4; ++m) { acc[m][0] = zero; acc[m][1] = zero; }
  const short* ab = &sH[lr * HS2 + kq * 8];
  {
    short8 af[4];
#pragma unroll
    for (int m = 0; m < 4; ++m) af[m] = *(const short8*)(ab + m * 16 * HS2);
#pragma unroll
    for (int m = 0; m < 4; ++m)
#pragma unroll
      for (int c = 0; c < 2; ++c)
        acc[m][c] = __builtin_amdgcn_mfma_f32_16x16x32_bf16(af[m], w1c[c], acc[m][c], 0, 0, 0);
  }

  // ---- + P + b1, GELU (in regs) ----
#pragma unroll
  for (int c = 0; c < 2; ++c) {
    const int col = wv * 32 + c * 16 + lr;
    const float b1v = b1[col];
#pragma unroll
    for (int m = 0; m < 4; ++m)
#pragma unroll
      for (int r = 0; r < 4; ++r) {
        float p = sF[(m * 16 + kq * 4 + r) * FS + col];
        acc[m][c][r] = gelu_f(acc[m][c][r] + p + b1v);
      }
  }
  __syncthreads();   // all reads of sH(ea) and sF(P) complete

  // ---- write h -> sH (all 128 cols) ----
#pragma unroll
  for (int c = 0; c < 2; ++c) {
    const int col = wv * 32 + c * 16 + lr;
#pragma unroll
    for (int m = 0; m < 4; ++m)
#pragma unroll
      for (int r = 0; r < 4; ++r)
        sH[(m * 16 + kq * 4 + r) * HS2 + col] = f2b(acc[m][c][r]);
  }
  __syncthreads();

  // ---- GEMM2: [64 x 128] @ [128 x 32(wave)] ----
  f32x4 acc2[4][2];
#pragma unroll
  for (int m = 0; m < 4; ++m) { acc2[m][0] = zero; acc2[m][1] = zero; }
#pragma unroll
  for (int kt = 0; kt < 4; ++kt) {
    short8 af[4];
#pragma unroll
    for (int m = 0; m < 4; ++m) af[m] = *(const short8*)(ab + m * 16 * HS2 + kt * 32);
#pragma unroll
    for (int m = 0; m < 4; ++m)
#pragma unroll
      for (int c = 0; c < 2; ++c)
        acc2[m][c] = __builtin_amdgcn_mfma_f32_16x16x32_bf16(af[m], w2f[kt * 2 + c], acc2[m][c], 0, 0, 0);
  }

  // ---- msg = acc2 + b2 -> sF ----
#pragma unroll
  for (int c = 0; c < 2; ++c) {
    const int col = wv * 32 + c * 16 + lr;
    const float b2v = b2[col];
#pragma unroll
    for (int m = 0; m < 4; ++m)
#pragma unroll
      for (int r = 0; r < 4; ++r)
        sF[(m * 16 + kq * 4 + r) * FS + col] = acc2[m][c][r] + b2v;
  }
  __syncthreads();

  // ---- segmented reduction over sorted dst runs, one atomic per segment ----
  {
    const int col = tid & 127;
    const int rs = (tid >> 7) * 32;
    float run = 0.f;
#pragma unroll 4
    for (int r = rs; r < rs + 32; ++r) {
      run += sF[r * FS + col];
      bool last = (r == rs + 31) || (sDst[r + 1] != sDst[r]);
      if (last) {
        atomicAdd(&agg[(size_t)sDst[r] * HH + col], run);
        run = 0.f;
      }
    }
  }
}

// ---------------------------------------------------------------------------
// Kernel: node MLP + residual + LayerNorm (round-4 structure, chist count).
// ---------------------------------------------------------------------------
#define NS 264
__global__ __launch_bounds__(256, 4) void k_node(
    const float* __restrict__ x, const short* __restrict__ xb,
    const float* __restrict__ agg, const int* __restrict__ chist,
    const short* __restrict__ pW1, const float* __restrict__ b1,
    const short* __restrict__ pW2, const float* __restrict__ b2,
    const float* __restrict__ g, const float* __restrict__ be,
    float* __restrict__ out) {
  __shared__ short sA[64 * NS];
  __shared__ float sP[64 * 4];
  __shared__ float sP2[64 * 4];

  const int tid = threadIdx.x;
  const int r0 = blockIdx.x * 64;
  const int le = tid >> 2;
  const int lq = tid & 3;
  const int wv = tid >> 6;
  const int l = tid & 63;
  const int lr = l & 15;
  const int kq = l >> 4;

  const short8* bp1 = (const short8*)pW1;
  short8 b1f[16];
#pragma unroll
  for (int kt = 0; kt < 8; ++kt)
#pragma unroll
    for (int c = 0; c < 2; ++c)
      b1f[kt * 2 + c] = bp1[(kt * 8 + wv * 2 + c) * 64 + l];

  {
    const int gr = r0 + le;
    short* row = &sA[le * NS];
    if (gr < NN) {
      float rinv = 1.0f / ((float)chist[gr] + 1e-8f);
      const short8* xp = (const short8*)(xb + (size_t)gr * HH);
#pragma unroll
      for (int i = 0; i < 4; ++i)
        *(short8*)(row + lq * 32 + i * 8) = xp[lq * 4 + i];
      const float4* as_ = (const float4*)(agg + (size_t)gr * HH);
#pragma unroll
      for (int i = 0; i < 4; ++i) {
        float4 a = as_[lq * 8 + i * 2], b = as_[lq * 8 + i * 2 + 1];
        a.x *= rinv; a.y *= rinv; a.z *= rinv; a.w *= rinv;
        b.x *= rinv; b.y *= rinv; b.z *= rinv; b.w *= rinv;
        cvt_store8(row + 128 + lq * 32 + i * 8, a, b);
      }
    } else {
      short8 z = {0, 0, 0, 0, 0, 0, 0, 0};
#pragma unroll
      for (int i = 0; i < 8; ++i) *(short8*)(row + lq * 64 + i * 8) = z;
    }
  }
  __syncthreads();

  f32x4 acc[4][2];
  const f32x4 zero = {0.f, 0.f, 0.f, 0.f};
#pragma unroll
  for (int m = 0; m < 4; ++m) { acc[m][0] = zero; acc[m][1] = zero; }
  const short* ab = &sA[lr * NS + kq * 8];
#pragma unroll
  for (int kt = 0; kt < 8; ++kt) {
    short8 af[4];
#pragma unroll
    for (int m = 0; m < 4; ++m)
      af[m] = *(const short8*)(ab + m * 16 * NS + kt * 32);
#pragma unroll
    for (int m = 0; m < 4; ++m)
#pragma unroll
      for (int c = 0; c < 2; ++c)
        acc[m][c] = __builtin_amdgcn_mfma_f32_16x16x32_bf16(af[m], b1f[kt * 2 + c], acc[m][c], 0, 0, 0);
  }

  const short8* bp2 = (const short8*)pW2;
  short8 b2f_[8];
#pragma unroll
  for (int kt = 0; kt < 4; ++kt)
#pragma unroll
    for (int c = 0; c < 2; ++c)
      b2f_[kt * 2 + c] = bp2[(kt * 8 + wv * 2 + c) * 64 + l];

  __syncthreads();

#pragma unroll
  for (int c = 0; c < 2; ++c) {
    const int col = wv * 32 + c * 16 + lr;
    const float b1v = b1[col];
#pragma unroll
    for (int m = 0; m < 4; ++m)
#pragma unroll
      for (int r = 0; r < 4; ++r)
        sA[(m * 16 + kq * 4 + r) * NS + col] = f2b(gelu_f(acc[m][c][r] + b1v));
  }
  __syncthreads();

  f32x4 acc2[4][2];
#pragma unroll
  for (int m = 0; m < 4; ++m) { acc2[m][0] = zero; acc2[m][1] = zero; }
#pragma unroll
  for (int kt = 0; kt < 4; ++kt) {
    short8 af[4];
#pragma unroll
    for (int m = 0; m < 4; ++m)
      af[m] = *(const short8*)(ab + m * 16 * NS + kt * 32);
#pragma unroll
    for (int m = 0; m < 4; ++m)
#pragma unroll
      for (int c = 0; c < 2; ++c)
        acc2[m][c] = __builtin_amdgcn_mfma_f32_16x16x32_bf16(af[m], b2f_[kt * 2 + c], acc2[m][c], 0, 0, 0);
  }

  float val[4][2][4];
#pragma unroll
  for (int c = 0; c < 2; ++c) {
    const int col = wv * 32 + c * 16 + lr;
    const float b2v = b2[col];
#pragma unroll
    for (int m = 0; m < 4; ++m)
#pragma unroll
      for (int r = 0; r < 4; ++r) {
        const int row = r0 + m * 16 + kq * 4 + r;
        float xr = (row < NN) ? x[(size_t)row * HH + col] : 0.f;
        val[m][c][r] = acc2[m][c][r] + b2v + xr;
      }
  }
#pragma unroll
  for (int m = 0; m < 4; ++m)
#pragma unroll
    for (int r = 0; r < 4; ++r) {
      float s = val[m][0][r] + val[m][1][r];
      float s2 = val[m][0][r] * val[m][0][r] + val[m][1][r] * val[m][1][r];
#pragma unroll
      for (int o = 1; o < 16; o <<= 1) {
        s += __shfl_xor(s, o);
        s2 += __shfl_xor(s2, o);
      }
      if (lr == 0) {
        const int row = m * 16 + kq * 4 + r;
        sP[row * 4 + wv] = s;
        sP2[row * 4 + wv] = s2;
      }
    }
  __syncthreads();

#pragma unroll
  for (int c = 0; c < 2; ++c) {
    const int col = wv * 32 + c * 16 + lr;
    const float gv = g[col];
    const float bv = be[col];
#pragma unroll
    for (int m = 0; m < 4; ++m)
#pragma unroll
      for (int r = 0; r < 4; ++r) {
        const int lrow = m * 16 + kq * 4 + r;
        const int row = r0 + lrow;
        if (row < NN) {
          float4 ps = *(float4*)&sP[lrow * 4];
          float4 qs = *(float4*)&sP2[lrow * 4];
          float s = ps.x + ps.y + ps.z + ps.w;
          float s2 = qs.x + qs.y + qs.z + qs.w;
          float mu = s * 0.0078125f;
          float var = s2 * 0.0078125f - mu * mu;
          float rs = rsqrtf(var + 1e-5f);
          out[(size_t)row * HH + col] = (val[m][c][r] - mu) * rs * gv + bv;
        }
      }
  }
}

extern "C" void kernel_launch(void* const* d_in, const int* in_sizes, int n_in,
                              void* d_out, int out_size, void* d_ws, size_t ws_size,
                              hipStream_t stream) {
  const float* x = (const float*)d_in[0];
  const void* ei = d_in[1];
  const float* ea = (const float*)d_in[2];
  const float* eW1 = (const float*)d_in[3];
  const float* eb1 = (const float*)d_in[4];
  const float* eW2 = (const float*)d_in[5];
  const float* eb2 = (const float*)d_in[6];
  const float* nW1 = (const float*)d_in[7];
  const float* nb1 = (const float*)d_in[8];
  const float* nW2 = (const float*)d_in[9];
  const float* nb2 = (const float*)d_in[10];
  const float* lng = (const float*)d_in[11];
  const float* lnb = (const float*)d_in[12];
  float* out = (float*)d_out;

  char* w = (char*)d_ws;
  size_t off = 0;
  auto alloc = [&](size_t bytes) { void* p = w + off; off = (off + bytes + 255) & ~(size_t)255; return p; };
  float* agg = (float*)alloc((size_t)NN * HH * 4);      // 25.6 MB (zeroed)
  int* chist = (int*)alloc((size_t)NBINS * 4);          // 200 KB (zeroed, contiguous)
  short* pe1 = (short*)alloc((size_t)72 * 512 * 2);
  short* pe2 = (short*)alloc((size_t)32 * 512 * 2);
  short* pn1 = (short*)alloc((size_t)64 * 512 * 2);
  short* pn2 = (short*)alloc((size_t)32 * 512 * 2);
  int* srcD = (int*)alloc((size_t)EE * 4);
  int* dstD = (int*)alloc((size_t)EE * 4);
  int* srcS = (int*)alloc((size_t)EE * 4);
  int* dstS = (int*)alloc((size_t)EE * 4);
  int* eidS = (int*)alloc((size_t)EE * 4);
  int* tmpS = (int*)alloc((size_t)NBINS * 4);
  int* bsum = (int*)alloc(256 * 4);
  int* offsW = (int*)alloc((size_t)NBINS * 4);
  int* flag = (int*)alloc(256);
  short* xb = (short*)alloc((size_t)NN * HH * 2);       // 12.8 MB
  short* Ps = (short*)alloc((size_t)NN * HH * 2);       // 12.8 MB
  short* Pd = (short*)alloc((size_t)NN * HH * 2);       // 12.8 MB

  hipMemsetAsync(agg, 0, (size_t)NN * HH * 4 + (size_t)NBINS * 4, stream);
  k_detect<<<1, 256, 0, stream>>>((const long long*)ei, 2048, (long long)NN, flag);
  k_idx_count<<<(EE + 255) / 256, 256, 0, stream>>>(ei, srcD, dstD, chist, flag);
  k_scan1<<<NBINS / 256, 256, 0, stream>>>(chist, tmpS, bsum);
  k_scan2<<<1, 256, 0, stream>>>(bsum);
  k_scan3<<<NBINS / 256, 256, 0, stream>>>(tmpS, chist, bsum, offsW);
  k_scatter<<<(EE + 255) / 256, 256, 0, stream>>>(srcD, dstD, offsW, srcS, dstS, eidS);
  k_cvt<<<(NN * HH / 8 + 255) / 256, 256, 0, stream>>>(x, xb, NN * HH / 8);
  k_pack_all<<<200, 64, 0, stream>>>(eW1, eW2, nW1, nW2, pe1, pe2, pn1, pn2);
  k_pre<<<(NN + 63) / 64, 256, 0, stream>>>(xb, pe1, Ps, Pd);
  k_edge<<<EE / 64, 256, 0, stream>>>(Ps, Pd, ea, pe1, eb1, pe2, eb2, srcS, dstS, eidS, agg);
  k_node<<<(NN + 63) / 64, 256, 0, stream>>>(x, xb, agg, chist, pn1, nb1, pn2, nb2, lng, lnb, out);
}

// Round 6
// 219.425 us; speedup vs baseline: 11.1941x; 1.1870x over previous
//
#include <hip/hip_runtime.h>
#include <hip/hip_bf16.h>
#include <math.h>

#define NN 50000
#define HH 128
#define EE 600000
#define EDD 32
#define NBINS 50176   // 196*256 >= NN

typedef __attribute__((ext_vector_type(8))) short short8;
typedef __attribute__((ext_vector_type(4))) float f32x4;

// ---------------------------------------------------------------------------
// detect int64 vs int32 edge_index. flag=1 -> int64.
// ---------------------------------------------------------------------------
__global__ void k_detect(const long long* __restrict__ ei, int n_check,
                         long long nmax, int* __restrict__ flag) {
  __shared__ int bad;
  if (threadIdx.x == 0) bad = 0;
  __syncthreads();
  for (int i = threadIdx.x; i < n_check; i += blockDim.x) {
    long long v = ei[i];
    if (v < 0 || v >= nmax) bad = 1;
  }
  __syncthreads();
  if (threadIdx.x == 0) *flag = (bad ? 0 : 1);
}

// ---------------------------------------------------------------------------
// histogram of dst.
// ---------------------------------------------------------------------------
__global__ void k_hist(const void* __restrict__ eiv, int* __restrict__ chist,
                       const int* __restrict__ flag) {
  int e = blockIdx.x * blockDim.x + threadIdx.x;
  if (e >= EE) return;
  int d;
  if (*flag) d = (int)((const long long*)eiv)[EE + e];
  else       d = ((const int*)eiv)[EE + e];
  atomicAdd(&chist[d], 1);
}

// ---------------------------------------------------------------------------
// exclusive prefix scan over NBINS bins (3 kernels).
// ---------------------------------------------------------------------------
__global__ void k_scan1(const int* __restrict__ chist, int* __restrict__ tmp,
                        int* __restrict__ bsum) {
  __shared__ int buf[2][256];
  int t = threadIdx.x;
  int i = blockIdx.x * 256 + t;
  buf[0][t] = chist[i];
  __syncthreads();
  int cur = 0;
  for (int o = 1; o < 256; o <<= 1) {
    int v = buf[cur][t];
    if (t >= o) v += buf[cur][t - o];
    buf[cur ^ 1][t] = v;
    __syncthreads();
    cur ^= 1;
  }
  tmp[i] = buf[cur][t];
  if (t == 255) bsum[blockIdx.x] = buf[cur][255];
}

__global__ void k_scan2(int* __restrict__ bsum) {
  __shared__ int buf[2][256];
  int t = threadIdx.x;
  int orig = (t < 196) ? bsum[t] : 0;
  buf[0][t] = orig;
  __syncthreads();
  int cur = 0;
  for (int o = 1; o < 256; o <<= 1) {
    int v = buf[cur][t];
    if (t >= o) v += buf[cur][t - o];
    buf[cur ^ 1][t] = v;
    __syncthreads();
    cur ^= 1;
  }
  if (t < 196) bsum[t] = buf[cur][t] - orig;   // exclusive
}

__global__ void k_scan3(const int* __restrict__ tmp, const int* __restrict__ chist,
                        const int* __restrict__ bsum, int* __restrict__ offs_work) {
  int i = blockIdx.x * 256 + threadIdx.x;
  offs_work[i] = tmp[i] - chist[i] + bsum[blockIdx.x];
}

// ---------------------------------------------------------------------------
// scatter edges into dst-sorted order (decodes edge_index directly).
// ---------------------------------------------------------------------------
__global__ void k_scatter(const void* __restrict__ eiv, const int* __restrict__ flag,
                          int* __restrict__ offs_work, int* __restrict__ srcS,
                          int* __restrict__ dstS, int* __restrict__ eidS) {
  int e = blockIdx.x * blockDim.x + threadIdx.x;
  if (e >= EE) return;
  int s, d;
  if (*flag) {
    const long long* p = (const long long*)eiv;
    s = (int)p[e];
    d = (int)p[EE + e];
  } else {
    const int* p = (const int*)eiv;
    s = p[e];
    d = p[EE + e];
  }
  int pos = atomicAdd(&offs_work[d], 1);
  srcS[pos] = s;
  dstS[pos] = d;
  eidS[pos] = e;
}

__device__ __forceinline__ short f2b(float f) {
  __hip_bfloat16 h = __float2bfloat16(f);
  return *reinterpret_cast<short*>(&h);
}
__device__ __forceinline__ float b2f(short s) {
  unsigned u = ((unsigned)(unsigned short)s) << 16;
  return *reinterpret_cast<float*>(&u);
}
__device__ __forceinline__ short8 cvt8(const float4 a, const float4 b) {
  short8 v = {f2b(a.x), f2b(a.y), f2b(a.z), f2b(a.w),
              f2b(b.x), f2b(b.y), f2b(b.z), f2b(b.w)};
  return v;
}

// overflow-safe tanh-form GELU
__device__ __forceinline__ float gelu_f(float v) {
  float u = 0.7978845608028654f * v * fmaf(0.044715f, v * v, 1.0f);
  float e = __expf(2.0f * u);
  float th = 1.0f - 2.0f / (e + 1.0f);
  return 0.5f * v * (1.0f + th);
}

// ---------------------------------------------------------------------------
// pack eW1 / nW1 / nW2 into bf16 MFMA B-fragment order:
//   P[((kt*8+ct)*64 + lane)*8 + j] = W[kt*32 + (lane>>4)*8 + j][ct*16 + (lane&15)]
// blocks: eW1 72 | nW1 64 | nW2 32  -> 168 blocks x 64.
// ---------------------------------------------------------------------------
__global__ void k_pack_all(const float* __restrict__ eW1, const float* __restrict__ nW1,
                           const float* __restrict__ nW2,
                           short* __restrict__ pe1, short* __restrict__ pn1,
                           short* __restrict__ pn2) {
  int blk = blockIdx.x;
  const float* W;
  short* P;
  int b;
  if (blk < 72)       { W = eW1; P = pe1; b = blk; }
  else if (blk < 136) { W = nW1; P = pn1; b = blk - 72; }
  else                { W = nW2; P = pn2; b = blk - 136; }
  const int kt = b >> 3, ct = b & 7;
  const int l = threadIdx.x;
  short8 v;
#pragma unroll
  for (int j = 0; j < 8; ++j) {
    float f = W[(size_t)(kt * 32 + ((l >> 4) * 8 + j)) * HH + ct * 16 + (l & 15)];
    v[j] = f2b(f);
  }
  *(short8*)(P + ((size_t)b * 64 + l) * 8) = v;
}

// ---------------------------------------------------------------------------
// W2' = eW2 @ nW1b  (128x128), emitted directly in B-fragment pack order.
// grid = 2 blocks (64 rows each). B-frags of nW1b come from pn1 kt4..7.
// ---------------------------------------------------------------------------
#define FS 132
__global__ __launch_bounds__(256, 2) void k_w2p(
    const float* __restrict__ eW2, const short* __restrict__ pn1,
    short* __restrict__ pnW2p) {
  __shared__ short sA[64 * 136];
  __shared__ float sR[64 * FS];
  const int b = blockIdx.x;
  const int tid = threadIdx.x;
  const int le = tid >> 2, lq = tid & 3;
  const int wv = tid >> 6, l = tid & 63, lr = l & 15, kq = l >> 4;

  const short8* bp = (const short8*)pn1;
  short8 bf[8];
#pragma unroll
  for (int kt = 0; kt < 4; ++kt)
#pragma unroll
    for (int c = 0; c < 2; ++c)
      bf[kt * 2 + c] = bp[((kt + 4) * 8 + wv * 2 + c) * 64 + l];

  {
    const float4* xs = (const float4*)(eW2 + (size_t)(64 * b + le) * HH);
#pragma unroll
    for (int i = 0; i < 4; ++i)
      *(short8*)&sA[le * 136 + lq * 8 + i * 32] = cvt8(xs[lq * 2 + i * 8], xs[lq * 2 + i * 8 + 1]);
  }
  __syncthreads();

  f32x4 acc[4][2];
  const f32x4 zero = {0.f, 0.f, 0.f, 0.f};
#pragma unroll
  for (int m = 0; m < 4; ++m) { acc[m][0] = zero; acc[m][1] = zero; }
  const short* ab = &sA[lr * 136 + kq * 8];
#pragma unroll
  for (int kt = 0; kt < 4; ++kt) {
    short8 af[4];
#pragma unroll
    for (int m = 0; m < 4; ++m) af[m] = *(const short8*)(ab + m * 16 * 136 + kt * 32);
#pragma unroll
    for (int m = 0; m < 4; ++m)
#pragma unroll
      for (int c = 0; c < 2; ++c)
        acc[m][c] = __builtin_amdgcn_mfma_f32_16x16x32_bf16(af[m], bf[kt * 2 + c], acc[m][c], 0, 0, 0);
  }
#pragma unroll
  for (int c = 0; c < 2; ++c)
#pragma unroll
    for (int m = 0; m < 4; ++m)
#pragma unroll
      for (int r = 0; r < 4; ++r)
        sR[(m * 16 + kq * 4 + r) * FS + wv * 32 + c * 16 + lr] = acc[m][c][r];
  __syncthreads();

  // emit pack: kt_local in {0,1} -> combined kt 2b+ktl (0..3 of pnW2p)
#pragma unroll
  for (int it = 0; it < 4; ++it) {
    int item = tid + 256 * it;
    int lane = item & 63;
    int pair = item >> 6;      // 0..15
    int ktl = pair >> 3, ct = pair & 7;
    short8 v;
#pragma unroll
    for (int j = 0; j < 8; ++j) {
      int rowl = ktl * 32 + ((lane >> 4) * 8 + j);
      int colp = ct * 16 + (lane & 15);
      v[j] = f2b(sR[rowl * FS + colp]);
    }
    *(short8*)(pnW2p + (((size_t)(2 * b + ktl) * 8 + ct) * 64 + lane) * 8) = v;
  }
}

// ---------------------------------------------------------------------------
// b2p = eb2 @ nW1b  (128 vector). 1 block x 128 threads, coalesced.
// ---------------------------------------------------------------------------
__global__ void k_b2p(const float* __restrict__ eb2, const float* __restrict__ nW1,
                      float* __restrict__ b2p) {
  int c = threadIdx.x;
  float acc = 0.f;
#pragma unroll 4
  for (int k = 0; k < 128; ++k)
    acc += eb2[k] * nW1[(size_t)(128 + k) * HH + c];
  b2p[c] = acc;
}

// ---------------------------------------------------------------------------
// k_pre: xb = bf16(x); Ps = x@W1a, Pd = x@W1b (bf16). 64 rows/block.
// ---------------------------------------------------------------------------
__global__ __launch_bounds__(256, 2) void k_pre(
    const float* __restrict__ x, const short* __restrict__ pW1,
    short* __restrict__ xb, short* __restrict__ Ps, short* __restrict__ Pd) {
  __shared__ short sX[64 * 136];
  const int tid = threadIdx.x;
  const int r0 = blockIdx.x * 64;
  const int le = tid >> 2, lq = tid & 3;
  const int wv = tid >> 6, l = tid & 63, lr = l & 15, kq = l >> 4;

  const short8* bp = (const short8*)pW1;
  short8 fa[8], fb[8];
#pragma unroll
  for (int kt = 0; kt < 4; ++kt)
#pragma unroll
    for (int c = 0; c < 2; ++c) {
      fa[kt * 2 + c] = bp[(kt * 8 + wv * 2 + c) * 64 + l];
      fb[kt * 2 + c] = bp[((kt + 4) * 8 + wv * 2 + c) * 64 + l];
    }
  {
    int gr = r0 + le;
    short* row = &sX[le * 136];
    if (gr < NN) {
      const float4* xs = (const float4*)(x + (size_t)gr * HH);
#pragma unroll
      for (int i = 0; i < 4; ++i) {
        short8 v = cvt8(xs[lq * 2 + i * 8], xs[lq * 2 + i * 8 + 1]);
        *(short8*)(row + lq * 8 + i * 32) = v;
        *(short8*)(xb + (size_t)gr * HH + lq * 8 + i * 32) = v;
      }
    } else {
      short8 z = {0, 0, 0, 0, 0, 0, 0, 0};
#pragma unroll
      for (int i = 0; i < 4; ++i) *(short8*)(row + lq * 8 + i * 32) = z;
    }
  }
  __syncthreads();

  f32x4 as_[4][2], ad[4][2];
  const f32x4 zero = {0.f, 0.f, 0.f, 0.f};
#pragma unroll
  for (int m = 0; m < 4; ++m) { as_[m][0] = zero; as_[m][1] = zero; ad[m][0] = zero; ad[m][1] = zero; }
  const short* ab = &sX[lr * 136 + kq * 8];
#pragma unroll
  for (int kt = 0; kt < 4; ++kt) {
    short8 af[4];
#pragma unroll
    for (int m = 0; m < 4; ++m) af[m] = *(const short8*)(ab + m * 16 * 136 + kt * 32);
#pragma unroll
    for (int m = 0; m < 4; ++m)
#pragma unroll
      for (int c = 0; c < 2; ++c) {
        as_[m][c] = __builtin_amdgcn_mfma_f32_16x16x32_bf16(af[m], fa[kt * 2 + c], as_[m][c], 0, 0, 0);
        ad[m][c] = __builtin_amdgcn_mfma_f32_16x16x32_bf16(af[m], fb[kt * 2 + c], ad[m][c], 0, 0, 0);
      }
  }
#pragma unroll
  for (int c = 0; c < 2; ++c) {
    const int col = wv * 32 + c * 16 + lr;
#pragma unroll
    for (int m = 0; m < 4; ++m)
#pragma unroll
      for (int r = 0; r < 4; ++r) {
        int grow = r0 + m * 16 + kq * 4 + r;
        if (grow < NN) {
          Ps[(size_t)grow * HH + col] = f2b(as_[m][c][r]);
          Pd[(size_t)grow * HH + col] = f2b(ad[m][c][r]);
        }
      }
  }
}

// ---------------------------------------------------------------------------
// k_edge: h = gelu(Ps[src]+Pd[dst] + ea@W1c + b1); segment-sum h -> Hagg[dst].
// 256 threads = 4 col-split waves; 64 sorted edges/block; 2 barriers.
// ---------------------------------------------------------------------------
#define EAS 40
__global__ __launch_bounds__(256, 4) void k_edge(
    const short* __restrict__ Ps, const short* __restrict__ Pd,
    const float* __restrict__ ea,
    const short* __restrict__ pW1, const float* __restrict__ b1,
    const int* __restrict__ srcS, const int* __restrict__ dstS,
    const int* __restrict__ eidS, float* __restrict__ Hagg) {
  __shared__ float sF[64 * FS];   // P sums, then h
  __shared__ short sH[64 * EAS];  // ea tile bf16
  __shared__ int sDst[64];

  const int tid = threadIdx.x;
  const int e0 = blockIdx.x * 64;
  const int le = tid >> 2, lq = tid & 3;
  const int wv = tid >> 6, l = tid & 63, lr = l & 15, kq = l >> 4;

  // W1c (kt=8 of packed eW1) -> registers
  const short8* bp1 = (const short8*)pW1;
  short8 w1c[2];
#pragma unroll
  for (int c = 0; c < 2; ++c) w1c[c] = bp1[(64 + wv * 2 + c) * 64 + l];

  if (tid < 64) sDst[tid] = dstS[e0 + tid];

  // ---- stage: sF = Ps[src]+Pd[dst] (f32); sH = bf16(ea[eid]) ----
  {
    const int gs = srcS[e0 + le];
    const int gd = dstS[e0 + le];
    const int ge = eidS[e0 + le];
    const short8* ps = (const short8*)(Ps + (size_t)gs * HH);
    const short8* pd = (const short8*)(Pd + (size_t)gd * HH);
    float* frow = &sF[le * FS];
#pragma unroll
    for (int i = 0; i < 4; ++i) {
      short8 a = ps[lq + i * 4];
      short8 b = pd[lq + i * 4];
      int c0 = lq * 8 + i * 32;
      float4 lo = {b2f(a[0]) + b2f(b[0]), b2f(a[1]) + b2f(b[1]),
                   b2f(a[2]) + b2f(b[2]), b2f(a[3]) + b2f(b[3])};
      float4 hi = {b2f(a[4]) + b2f(b[4]), b2f(a[5]) + b2f(b[5]),
                   b2f(a[6]) + b2f(b[6]), b2f(a[7]) + b2f(b[7])};
      *(float4*)(frow + c0) = lo;
      *(float4*)(frow + c0 + 4) = hi;
    }
    const float4* ep = (const float4*)(ea + (size_t)ge * EDD) + lq * 2;
    *(short8*)&sH[le * EAS + lq * 8] = cvt8(ep[0], ep[1]);
  }
  __syncthreads();

  // ---- ea @ W1c : single K=32 tile, 8 MFMA ----
  f32x4 acc[4][2];
  const f32x4 zero = {0.f, 0.f, 0.f, 0.f};
#pragma unroll
  for (int m = 0; m < 4; ++m) { acc[m][0] = zero; acc[m][1] = zero; }
  const short* ab = &sH[lr * EAS + kq * 8];
  {
    short8 af[4];
#pragma unroll
    for (int m = 0; m < 4; ++m) af[m] = *(const short8*)(ab + m * 16 * EAS);
#pragma unroll
    for (int m = 0; m < 4; ++m)
#pragma unroll
      for (int c = 0; c < 2; ++c)
        acc[m][c] = __builtin_amdgcn_mfma_f32_16x16x32_bf16(af[m], w1c[c], acc[m][c], 0, 0, 0);
  }

  // ---- h = gelu(acc + P + b1) -> sF (same slot each thread read) ----
#pragma unroll
  for (int c = 0; c < 2; ++c) {
    const int col = wv * 32 + c * 16 + lr;
    const float b1v = b1[col];
#pragma unroll
    for (int m = 0; m < 4; ++m)
#pragma unroll
      for (int r = 0; r < 4; ++r) {
        const int row = m * 16 + kq * 4 + r;
        float p = sF[row * FS + col];
        sF[row * FS + col] = gelu_f(acc[m][c][r] + p + b1v);
      }
  }
  __syncthreads();

  // ---- segmented sum over sorted dst runs, one atomic per segment ----
  {
    const int col = tid & 127;
    const int rs = (tid >> 7) * 32;
    float run = 0.f;
#pragma unroll 4
    for (int r = rs; r < rs + 32; ++r) {
      run += sF[r * FS + col];
      bool last = (r == rs + 31) || (sDst[r + 1] != sDst[r]);
      if (last) {
        atomicAdd(&Hagg[(size_t)sDst[r] * HH + col], run);
        run = 0.f;
      }
    }
  }
}

// ---------------------------------------------------------------------------
// k_node: hidden = gelu(x@nW1a + Hm@W2' + nb1 + f*b2p); out = LN(hidden@nW2
// + nb2 + x). Hm = Hagg*rinv, f = cnt*rinv.
// ---------------------------------------------------------------------------
#define NS 264
__global__ __launch_bounds__(256, 4) void k_node(
    const float* __restrict__ x, const short* __restrict__ xb,
    const float* __restrict__ Hagg, const int* __restrict__ chist,
    const short* __restrict__ pn1, const short* __restrict__ pnW2p,
    const float* __restrict__ nb1, const float* __restrict__ b2p,
    const short* __restrict__ pn2, const float* __restrict__ nb2,
    const float* __restrict__ g, const float* __restrict__ be,
    float* __restrict__ out) {
  __shared__ short sA[64 * NS];
  __shared__ float sP[64 * 4];
  __shared__ float sP2[64 * 4];
  __shared__ float sFac[64];

  const int tid = threadIdx.x;
  const int r0 = blockIdx.x * 64;
  const int le = tid >> 2;
  const int lq = tid & 3;
  const int wv = tid >> 6;
  const int l = tid & 63;
  const int lr = l & 15;
  const int kq = l >> 4;

  const short8* bpa = (const short8*)pn1;
  const short8* bpc = (const short8*)pnW2p;
  short8 b1f[16];
#pragma unroll
  for (int kt = 0; kt < 4; ++kt)
#pragma unroll
    for (int c = 0; c < 2; ++c) {
      b1f[kt * 2 + c] = bpa[(kt * 8 + wv * 2 + c) * 64 + l];
      b1f[(kt + 4) * 2 + c] = bpc[(kt * 8 + wv * 2 + c) * 64 + l];
    }

  {
    const int gr = r0 + le;
    short* row = &sA[le * NS];
    if (gr < NN) {
      float cntf = (float)chist[gr];
      float rinv = 1.0f / (cntf + 1e-8f);
      if (lq == 0) sFac[le] = cntf * rinv;
      const short8* xp = (const short8*)(xb + (size_t)gr * HH);
#pragma unroll
      for (int i = 0; i < 4; ++i)
        *(short8*)(row + lq * 32 + i * 8) = xp[lq * 4 + i];
      const float4* as_ = (const float4*)(Hagg + (size_t)gr * HH);
#pragma unroll
      for (int i = 0; i < 4; ++i) {
        float4 a = as_[lq * 8 + i * 2], b = as_[lq * 8 + i * 2 + 1];
        a.x *= rinv; a.y *= rinv; a.z *= rinv; a.w *= rinv;
        b.x *= rinv; b.y *= rinv; b.z *= rinv; b.w *= rinv;
        *(short8*)(row + 128 + lq * 32 + i * 8) = cvt8(a, b);
      }
    } else {
      if (lq == 0) sFac[le] = 0.f;
      short8 z = {0, 0, 0, 0, 0, 0, 0, 0};
#pragma unroll
      for (int i = 0; i < 8; ++i) *(short8*)(row + lq * 64 + i * 8) = z;
    }
  }
  __syncthreads();

  f32x4 acc[4][2];
  const f32x4 zero = {0.f, 0.f, 0.f, 0.f};
#pragma unroll
  for (int m = 0; m < 4; ++m) { acc[m][0] = zero; acc[m][1] = zero; }
  const short* ab = &sA[lr * NS + kq * 8];
#pragma unroll
  for (int kt = 0; kt < 8; ++kt) {
    short8 af[4];
#pragma unroll
    for (int m = 0; m < 4; ++m)
      af[m] = *(const short8*)(ab + m * 16 * NS + kt * 32);
#pragma unroll
    for (int m = 0; m < 4; ++m)
#pragma unroll
      for (int c = 0; c < 2; ++c)
        acc[m][c] = __builtin_amdgcn_mfma_f32_16x16x32_bf16(af[m], b1f[kt * 2 + c], acc[m][c], 0, 0, 0);
  }

  const short8* bp2 = (const short8*)pn2;
  short8 b2f_[8];
#pragma unroll
  for (int kt = 0; kt < 4; ++kt)
#pragma unroll
    for (int c = 0; c < 2; ++c)
      b2f_[kt * 2 + c] = bp2[(kt * 8 + wv * 2 + c) * 64 + l];

  __syncthreads();

  // ---- bias (nb1 + f*b2p) + GELU -> sA cols 0..127 ----
#pragma unroll
  for (int c = 0; c < 2; ++c) {
    const int col = wv * 32 + c * 16 + lr;
    const float b1v = nb1[col];
    const float b2pv = b2p[col];
#pragma unroll
    for (int m = 0; m < 4; ++m)
#pragma unroll
      for (int r = 0; r < 4; ++r) {
        const int row = m * 16 + kq * 4 + r;
        float fac = sFac[row];
        sA[row * NS + col] = f2b(gelu_f(acc[m][c][r] + b1v + fac * b2pv));
      }
  }
  __syncthreads();

  f32x4 acc2[4][2];
#pragma unroll
  for (int m = 0; m < 4; ++m) { acc2[m][0] = zero; acc2[m][1] = zero; }
#pragma unroll
  for (int kt = 0; kt < 4; ++kt) {
    short8 af[4];
#pragma unroll
    for (int m = 0; m < 4; ++m)
      af[m] = *(const short8*)(ab + m * 16 * NS + kt * 32);
#pragma unroll
    for (int m = 0; m < 4; ++m)
#pragma unroll
      for (int c = 0; c < 2; ++c)
        acc2[m][c] = __builtin_amdgcn_mfma_f32_16x16x32_bf16(af[m], b2f_[kt * 2 + c], acc2[m][c], 0, 0, 0);
  }

  float val[4][2][4];
#pragma unroll
  for (int c = 0; c < 2; ++c) {
    const int col = wv * 32 + c * 16 + lr;
    const float b2v = nb2[col];
#pragma unroll
    for (int m = 0; m < 4; ++m)
#pragma unroll
      for (int r = 0; r < 4; ++r) {
        const int row = r0 + m * 16 + kq * 4 + r;
        float xr = (row < NN) ? x[(size_t)row * HH + col] : 0.f;
        val[m][c][r] = acc2[m][c][r] + b2v + xr;
      }
  }
#pragma unroll
  for (int m = 0; m < 4; ++m)
#pragma unroll
    for (int r = 0; r < 4; ++r) {
      float s = val[m][0][r] + val[m][1][r];
      float s2 = val[m][0][r] * val[m][0][r] + val[m][1][r] * val[m][1][r];
#pragma unroll
      for (int o = 1; o < 16; o <<= 1) {
        s += __shfl_xor(s, o);
        s2 += __shfl_xor(s2, o);
      }
      if (lr == 0) {
        const int row = m * 16 + kq * 4 + r;
        sP[row * 4 + wv] = s;
        sP2[row * 4 + wv] = s2;
      }
    }
  __syncthreads();

#pragma unroll
  for (int c = 0; c < 2; ++c) {
    const int col = wv * 32 + c * 16 + lr;
    const float gv = g[col];
    const float bv = be[col];
#pragma unroll
    for (int m = 0; m < 4; ++m)
#pragma unroll
      for (int r = 0; r < 4; ++r) {
        const int lrow = m * 16 + kq * 4 + r;
        const int row = r0 + lrow;
        if (row < NN) {
          float4 ps = *(float4*)&sP[lrow * 4];
          float4 qs = *(float4*)&sP2[lrow * 4];
          float s = ps.x + ps.y + ps.z + ps.w;
          float s2 = qs.x + qs.y + qs.z + qs.w;
          float mu = s * 0.0078125f;
          float var = s2 * 0.0078125f - mu * mu;
          float rs = rsqrtf(var + 1e-5f);
          out[(size_t)row * HH + col] = (val[m][c][r] - mu) * rs * gv + bv;
        }
      }
  }
}

extern "C" void kernel_launch(void* const* d_in, const int* in_sizes, int n_in,
                              void* d_out, int out_size, void* d_ws, size_t ws_size,
                              hipStream_t stream) {
  const float* x = (const float*)d_in[0];
  const void* ei = d_in[1];
  const float* ea = (const float*)d_in[2];
  const float* eW1 = (const float*)d_in[3];
  const float* eb1 = (const float*)d_in[4];
  const float* eW2 = (const float*)d_in[5];
  const float* eb2 = (const float*)d_in[6];
  const float* nW1 = (const float*)d_in[7];
  const float* nb1 = (const float*)d_in[8];
  const float* nW2 = (const float*)d_in[9];
  const float* nb2 = (const float*)d_in[10];
  const float* lng = (const float*)d_in[11];
  const float* lnb = (const float*)d_in[12];
  float* out = (float*)d_out;

  char* w = (char*)d_ws;
  size_t off = 0;
  auto alloc = [&](size_t bytes) { void* p = w + off; off = (off + bytes + 255) & ~(size_t)255; return p; };
  float* Hagg = (float*)alloc((size_t)NN * HH * 4);     // 25.6 MB (zeroed)
  int* chist = (int*)alloc((size_t)NBINS * 4);          // zeroed (contiguous w/ Hagg)
  short* pe1 = (short*)alloc((size_t)72 * 512 * 2);
  short* pn1 = (short*)alloc((size_t)64 * 512 * 2);
  short* pn2 = (short*)alloc((size_t)32 * 512 * 2);
  short* pnW2p = (short*)alloc((size_t)32 * 512 * 2);
  float* b2p = (float*)alloc(HH * 4);
  int* srcS = (int*)alloc((size_t)EE * 4);
  int* dstS = (int*)alloc((size_t)EE * 4);
  int* eidS = (int*)alloc((size_t)EE * 4);
  int* tmpS = (int*)alloc((size_t)NBINS * 4);
  int* bsum = (int*)alloc(256 * 4);
  int* offsW = (int*)alloc((size_t)NBINS * 4);
  int* flag = (int*)alloc(256);
  short* xb = (short*)alloc((size_t)NN * HH * 2);
  short* Ps = (short*)alloc((size_t)NN * HH * 2);
  short* Pd = (short*)alloc((size_t)NN * HH * 2);

  hipMemsetAsync(Hagg, 0, (size_t)NN * HH * 4 + (size_t)NBINS * 4, stream);
  k_detect<<<1, 256, 0, stream>>>((const long long*)ei, 2048, (long long)NN, flag);
  k_hist<<<(EE + 255) / 256, 256, 0, stream>>>(ei, chist, flag);
  k_scan1<<<NBINS / 256, 256, 0, stream>>>(chist, tmpS, bsum);
  k_scan2<<<1, 256, 0, stream>>>(bsum);
  k_scan3<<<NBINS / 256, 256, 0, stream>>>(tmpS, chist, bsum, offsW);
  k_scatter<<<(EE + 255) / 256, 256, 0, stream>>>(ei, flag, offsW, srcS, dstS, eidS);
  k_pack_all<<<168, 64, 0, stream>>>(eW1, nW1, nW2, pe1, pn1, pn2);
  k_w2p<<<2, 256, 0, stream>>>(eW2, pn1, pnW2p);
  k_b2p<<<1, 128, 0, stream>>>(eb2, nW1, b2p);
  k_pre<<<(NN + 63) / 64, 256, 0, stream>>>(x, pe1, xb, Ps, Pd);
  k_edge<<<EE / 64, 256, 0, stream>>>(Ps, Pd, ea, pe1, eb1, srcS, dstS, eidS, Hagg);
  k_node<<<(NN + 63) / 64, 256, 0, stream>>>(x, xb, Hagg, chist, pn1, pnW2p, nb1, b2p, pn2, nb2, lng, lnb, out);
}

// Round 7
// 201.695 us; speedup vs baseline: 12.1781x; 1.0879x over previous
//
#include <hip/hip_runtime.h>
#include <hip/hip_fp16.h>
#include <math.h>

#define NN 50000
#define HH 128
#define EE 600000
#define EDD 32
#define NBINS 50176   // 196*256 >= NN

typedef __attribute__((ext_vector_type(8))) _Float16 half8;
typedef __attribute__((ext_vector_type(4))) float f32x4;

__device__ __forceinline__ unsigned pkh(float a, float b) {
  __half2 h = __floats2half2_rn(a, b);
  return *reinterpret_cast<unsigned*>(&h);
}
__device__ __forceinline__ unsigned hadd2u(unsigned a, unsigned b) {
  __half2 x = *reinterpret_cast<__half2*>(&a);
  __half2 y = *reinterpret_cast<__half2*>(&b);
  __half2 s = __hadd2(x, y);
  return *reinterpret_cast<unsigned*>(&s);
}
__device__ __forceinline__ float lo16f(unsigned u) {
  __half2 h = *reinterpret_cast<__half2*>(&u);
  return __low2float(h);
}
__device__ __forceinline__ float hi16f(unsigned u) {
  __half2 h = *reinterpret_cast<__half2*>(&u);
  return __high2float(h);
}
__device__ __forceinline__ short f2hs(float f) {
  __half h = __float2half_rn(f);
  return *reinterpret_cast<short*>(&h);
}

// overflow-safe tanh-form GELU
__device__ __forceinline__ float gelu_f(float v) {
  float u2 = 1.5957691216057308f * v * fmaf(0.044715f, v * v, 1.0f);
  float e = __expf(u2);
  float th = 1.0f - 2.0f / (e + 1.0f);
  return 0.5f * v * (1.0f + th);
}

// ---------------------------------------------------------------------------
// detect int64 vs int32 edge_index. flag=1 -> int64.
// ---------------------------------------------------------------------------
__global__ void k_detect(const long long* __restrict__ ei, int n_check,
                         long long nmax, int* __restrict__ flag) {
  __shared__ int bad;
  if (threadIdx.x == 0) bad = 0;
  __syncthreads();
  for (int i = threadIdx.x; i < n_check; i += blockDim.x) {
    long long v = ei[i];
    if (v < 0 || v >= nmax) bad = 1;
  }
  __syncthreads();
  if (threadIdx.x == 0) *flag = (bad ? 0 : 1);
}

// ---------------------------------------------------------------------------
// histogram of dst.
// ---------------------------------------------------------------------------
__global__ void k_hist(const void* __restrict__ eiv, int* __restrict__ chist,
                       const int* __restrict__ flag) {
  int e = blockIdx.x * blockDim.x + threadIdx.x;
  if (e >= EE) return;
  int d;
  if (*flag) d = (int)((const long long*)eiv)[EE + e];
  else       d = ((const int*)eiv)[EE + e];
  atomicAdd(&chist[d], 1);
}

// ---------------------------------------------------------------------------
// prefix scan (inclusive within block) + block sums.
// ---------------------------------------------------------------------------
__global__ void k_scan1(const int* __restrict__ chist, int* __restrict__ tmp,
                        int* __restrict__ bsum) {
  __shared__ int buf[2][256];
  int t = threadIdx.x;
  int i = blockIdx.x * 256 + t;
  buf[0][t] = chist[i];
  __syncthreads();
  int cur = 0;
  for (int o = 1; o < 256; o <<= 1) {
    int v = buf[cur][t];
    if (t >= o) v += buf[cur][t - o];
    buf[cur ^ 1][t] = v;
    __syncthreads();
    cur ^= 1;
  }
  tmp[i] = buf[cur][t];
  if (t == 255) bsum[blockIdx.x] = buf[cur][255];
}

__global__ void k_scan2(int* __restrict__ bsum) {
  __shared__ int buf[2][256];
  int t = threadIdx.x;
  int orig = (t < 196) ? bsum[t] : 0;
  buf[0][t] = orig;
  __syncthreads();
  int cur = 0;
  for (int o = 1; o < 256; o <<= 1) {
    int v = buf[cur][t];
    if (t >= o) v += buf[cur][t - o];
    buf[cur ^ 1][t] = v;
    __syncthreads();
    cur ^= 1;
  }
  if (t < 196) bsum[t] = buf[cur][t] - orig;   // exclusive
}

// ---------------------------------------------------------------------------
// scatter edges into dst-sorted int4 records (src, dst, eid, 0).
// global exclusive base computed on the fly (scan3 folded in).
// ---------------------------------------------------------------------------
__global__ void k_scatter(const void* __restrict__ eiv, const int* __restrict__ flag,
                          const int* __restrict__ tmp, const int* __restrict__ chist,
                          const int* __restrict__ bsum, int* __restrict__ cntW,
                          int4* __restrict__ e4) {
  int e = blockIdx.x * blockDim.x + threadIdx.x;
  if (e >= EE) return;
  int s, d;
  if (*flag) {
    const long long* p = (const long long*)eiv;
    s = (int)p[e];
    d = (int)p[EE + e];
  } else {
    const int* p = (const int*)eiv;
    s = p[e];
    d = p[EE + e];
  }
  int base = tmp[d] - chist[d] + bsum[d >> 8];
  int pos = base + atomicAdd(&cntW[d], 1);
  e4[pos] = make_int4(s, d, e, 0);
}

// ---------------------------------------------------------------------------
// pack eW1 / nW1 / nW2 into f16 MFMA B-fragment order:
//   P[((kt*8+ct)*64 + lane)*8 + j] = W[kt*32 + (lane>>4)*8 + j][ct*16 + (lane&15)]
// blocks: eW1 72 | nW1 64 | nW2 32  -> 168 x 64.
// ---------------------------------------------------------------------------
__global__ void k_pack_all(const float* __restrict__ eW1, const float* __restrict__ nW1,
                           const float* __restrict__ nW2,
                           short* __restrict__ pe1, short* __restrict__ pn1,
                           short* __restrict__ pn2) {
  int blk = blockIdx.x;
  const float* W;
  short* P;
  int b;
  if (blk < 72)       { W = eW1; P = pe1; b = blk; }
  else if (blk < 136) { W = nW1; P = pn1; b = blk - 72; }
  else                { W = nW2; P = pn2; b = blk - 136; }
  const int kt = b >> 3, ct = b & 7;
  const int l = threadIdx.x;
  short v[8];
#pragma unroll
  for (int j = 0; j < 8; ++j)
    v[j] = f2hs(W[(size_t)(kt * 32 + ((l >> 4) * 8 + j)) * HH + ct * 16 + (l & 15)]);
  short* dst = P + ((size_t)b * 64 + l) * 8;
#pragma unroll
  for (int j = 0; j < 8; ++j) dst[j] = v[j];
}

// ---------------------------------------------------------------------------
// blocks 0,1: W2' = eW2 @ nW1b (128x128) -> f16 B-frag pack order.
// block 2:    b2p = eb2 @ nW1b (128 vec, f32).
// ---------------------------------------------------------------------------
#define FS 132
__global__ __launch_bounds__(256, 2) void k_w2p(
    const float* __restrict__ eW2, const float* __restrict__ eb2,
    const float* __restrict__ nW1, const short* __restrict__ pn1,
    short* __restrict__ pnW2p, float* __restrict__ b2p) {
  const int b = blockIdx.x;
  const int tid = threadIdx.x;
  if (b == 2) {
    if (tid < 128) {
      float acc = 0.f;
#pragma unroll 4
      for (int k = 0; k < 128; ++k)
        acc += eb2[k] * nW1[(size_t)(128 + k) * HH + tid];
      b2p[tid] = acc;
    }
    return;
  }
  __shared__ short sA[64 * 136];
  __shared__ float sR[64 * FS];
  const int le = tid >> 2, lq = tid & 3;
  const int wv = tid >> 6, l = tid & 63, lr = l & 15, kq = l >> 4;

  const half8* bp = (const half8*)pn1;
  half8 bf[8];
#pragma unroll
  for (int kt = 0; kt < 4; ++kt)
#pragma unroll
    for (int c = 0; c < 2; ++c)
      bf[kt * 2 + c] = bp[((kt + 4) * 8 + wv * 2 + c) * 64 + l];

  {
    const float4* xs = (const float4*)(eW2 + (size_t)(64 * b + le) * HH);
#pragma unroll
    for (int i = 0; i < 4; ++i) {
      float4 a = xs[lq * 8 + i * 2], c = xs[lq * 8 + i * 2 + 1];
      uint4 u = {pkh(a.x, a.y), pkh(a.z, a.w), pkh(c.x, c.y), pkh(c.z, c.w)};
      *(uint4*)&sA[le * 136 + lq * 32 + i * 8] = u;
    }
  }
  __syncthreads();

  f32x4 acc[4][2];
  const f32x4 zero = {0.f, 0.f, 0.f, 0.f};
#pragma unroll
  for (int m = 0; m < 4; ++m) { acc[m][0] = zero; acc[m][1] = zero; }
  const short* ab = &sA[lr * 136 + kq * 8];
#pragma unroll
  for (int kt = 0; kt < 4; ++kt) {
    half8 af[4];
#pragma unroll
    for (int m = 0; m < 4; ++m) af[m] = *(const half8*)(ab + m * 16 * 136 + kt * 32);
#pragma unroll
    for (int m = 0; m < 4; ++m)
#pragma unroll
      for (int c = 0; c < 2; ++c)
        acc[m][c] = __builtin_amdgcn_mfma_f32_16x16x32_f16(af[m], bf[kt * 2 + c], acc[m][c], 0, 0, 0);
  }
#pragma unroll
  for (int c = 0; c < 2; ++c)
#pragma unroll
    for (int m = 0; m < 4; ++m)
#pragma unroll
      for (int r = 0; r < 4; ++r)
        sR[(m * 16 + kq * 4 + r) * FS + wv * 32 + c * 16 + lr] = acc[m][c][r];
  __syncthreads();

#pragma unroll
  for (int it = 0; it < 4; ++it) {
    int item = tid + 256 * it;
    int lane = item & 63;
    int pair = item >> 6;      // 0..15
    int ktl = pair >> 3, ct = pair & 7;
    short v[8];
#pragma unroll
    for (int j = 0; j < 8; ++j) {
      int rowl = ktl * 32 + ((lane >> 4) * 8 + j);
      int colp = ct * 16 + (lane & 15);
      v[j] = f2hs(sR[rowl * FS + colp]);
    }
    short* dst = pnW2p + (((size_t)(2 * b + ktl) * 8 + ct) * 64 + lane) * 8;
#pragma unroll
    for (int j = 0; j < 8; ++j) dst[j] = v[j];
  }
}

// ---------------------------------------------------------------------------
// k_pre: Psw/Pdw = packed-pair f16 of x@W1a, x@W1b.
// Pair slot [node*64 + wv*16 + lr] = (col, col+16) where col = wv*32+lr.
// ---------------------------------------------------------------------------
__global__ __launch_bounds__(256, 4) void k_pre(
    const float* __restrict__ x, const short* __restrict__ pW1,
    unsigned* __restrict__ Psw, unsigned* __restrict__ Pdw) {
  __shared__ short sX[64 * 136];
  const int tid = threadIdx.x;
  const int r0 = blockIdx.x * 64;
  const int le = tid >> 2, lq = tid & 3;
  const int wv = tid >> 6, l = tid & 63, lr = l & 15, kq = l >> 4;

  const half8* bp = (const half8*)pW1;
  half8 fa[8], fb[8];
#pragma unroll
  for (int kt = 0; kt < 4; ++kt)
#pragma unroll
    for (int c = 0; c < 2; ++c) {
      fa[kt * 2 + c] = bp[(kt * 8 + wv * 2 + c) * 64 + l];
      fb[kt * 2 + c] = bp[((kt + 4) * 8 + wv * 2 + c) * 64 + l];
    }
  {
    int gr = r0 + le;
    if (gr < NN) {
      const float4* xs = (const float4*)(x + (size_t)gr * HH);
#pragma unroll
      for (int i = 0; i < 4; ++i) {
        float4 a = xs[lq * 8 + i * 2], c = xs[lq * 8 + i * 2 + 1];
        uint4 u = {pkh(a.x, a.y), pkh(a.z, a.w), pkh(c.x, c.y), pkh(c.z, c.w)};
        *(uint4*)&sX[le * 136 + lq * 32 + i * 8] = u;
      }
    } else {
      uint4 z = {0, 0, 0, 0};
#pragma unroll
      for (int i = 0; i < 4; ++i) *(uint4*)&sX[le * 136 + lq * 32 + i * 8] = z;
    }
  }
  __syncthreads();

  f32x4 as_[4][2], ad[4][2];
  const f32x4 zero = {0.f, 0.f, 0.f, 0.f};
#pragma unroll
  for (int m = 0; m < 4; ++m) { as_[m][0] = zero; as_[m][1] = zero; ad[m][0] = zero; ad[m][1] = zero; }
  const short* ab = &sX[lr * 136 + kq * 8];
#pragma unroll
  for (int kt = 0; kt < 4; ++kt) {
    half8 af[4];
#pragma unroll
    for (int m = 0; m < 4; ++m) af[m] = *(const half8*)(ab + m * 16 * 136 + kt * 32);
#pragma unroll
    for (int m = 0; m < 4; ++m)
#pragma unroll
      for (int c = 0; c < 2; ++c) {
        as_[m][c] = __builtin_amdgcn_mfma_f32_16x16x32_f16(af[m], fa[kt * 2 + c], as_[m][c], 0, 0, 0);
        ad[m][c] = __builtin_amdgcn_mfma_f32_16x16x32_f16(af[m], fb[kt * 2 + c], ad[m][c], 0, 0, 0);
      }
  }
#pragma unroll
  for (int m = 0; m < 4; ++m)
#pragma unroll
    for (int r = 0; r < 4; ++r) {
      int grow = r0 + m * 16 + kq * 4 + r;
      if (grow < NN) {
        Psw[(size_t)grow * 64 + wv * 16 + lr] = pkh(as_[m][0][r], as_[m][1][r]);
        Pdw[(size_t)grow * 64 + wv * 16 + lr] = pkh(ad[m][0][r], ad[m][1][r]);
      }
    }
}

// ---------------------------------------------------------------------------
// k_edge: h = gelu(Ps[src]+Pd[dst] + ea@W1c + b1); segment-sum h -> Hagg[dst].
// Packed f16 pair pipeline; 23.5 KB LDS -> 6 blocks/CU.
// ---------------------------------------------------------------------------
#define SFP 68
__global__ __launch_bounds__(256, 6) void k_edge(
    const unsigned* __restrict__ Psw, const unsigned* __restrict__ Pdw,
    const float* __restrict__ ea,
    const short* __restrict__ pW1, const float* __restrict__ b1,
    const int4* __restrict__ e4, float* __restrict__ Hagg) {
  __shared__ unsigned sFp[64 * SFP];   // packed P-sum pairs, then packed h
  __shared__ short sEA[64 * 40];       // ea tile f16
  __shared__ int4 sE4[64];

  const int tid = threadIdx.x;
  const int e0 = blockIdx.x * 64;
  const int le = tid >> 2, lq = tid & 3;
  const int wv = tid >> 6, l = tid & 63, lr = l & 15, kq = l >> 4;

  // W1c (kt=8 of packed eW1) -> registers
  half8 w1c[2];
#pragma unroll
  for (int c = 0; c < 2; ++c)
    w1c[c] = ((const half8*)pW1)[(64 + wv * 2 + c) * 64 + l];

  const int4 er = e4[e0 + le];
  if (tid < 64) sE4[tid] = e4[e0 + tid];

  // ---- stage: packed P-sum pairs + ea ----
  {
    const uint4* ps = (const uint4*)(Psw + (size_t)er.x * 64);
    const uint4* pd = (const uint4*)(Pdw + (size_t)er.y * 64);
#pragma unroll
    for (int i = 0; i < 4; ++i) {
      uint4 a = ps[lq * 4 + i];
      uint4 b = pd[lq * 4 + i];
      uint4 s = {hadd2u(a.x, b.x), hadd2u(a.y, b.y), hadd2u(a.z, b.z), hadd2u(a.w, b.w)};
      *(uint4*)&sFp[le * SFP + lq * 16 + i * 4] = s;
    }
    const float4* ep = (const float4*)(ea + (size_t)er.z * EDD);
    float4 a = ep[lq * 2], b = ep[lq * 2 + 1];
    uint4 u = {pkh(a.x, a.y), pkh(a.z, a.w), pkh(b.x, b.y), pkh(b.z, b.w)};
    *(uint4*)&sEA[le * 40 + lq * 8] = u;
  }
  __syncthreads();

  // ---- ea @ W1c : single K=32 tile, 8 MFMA ----
  f32x4 acc[4][2];
  const f32x4 zero = {0.f, 0.f, 0.f, 0.f};
#pragma unroll
  for (int m = 0; m < 4; ++m) { acc[m][0] = zero; acc[m][1] = zero; }
  {
#pragma unroll
    for (int m = 0; m < 4; ++m) {
      half8 af = *(const half8*)&sEA[(m * 16 + lr) * 40 + kq * 8];
#pragma unroll
      for (int c = 0; c < 2; ++c)
        acc[m][c] = __builtin_amdgcn_mfma_f32_16x16x32_f16(af, w1c[c], acc[m][c], 0, 0, 0);
    }
  }

  // ---- h = gelu(acc + P + b1) -> same packed slot ----
  const float b1c0 = b1[wv * 32 + lr];
  const float b1c1 = b1[wv * 32 + 16 + lr];
#pragma unroll
  for (int m = 0; m < 4; ++m)
#pragma unroll
    for (int r = 0; r < 4; ++r) {
      const int row = m * 16 + kq * 4 + r;
      unsigned up = sFp[row * SFP + wv * 16 + lr];
      float v0 = acc[m][0][r] + lo16f(up) + b1c0;
      float v1 = acc[m][1][r] + hi16f(up) + b1c1;
      sFp[row * SFP + wv * 16 + lr] = pkh(gelu_f(v0), gelu_f(v1));
    }
  __syncthreads();

  // ---- segmented sum over sorted dst runs (f32 accum, packed reads) ----
  {
    const int p = tid & 63;
    const int q = tid >> 6;
    const int c0 = (p >> 4) * 32 + (p & 15);
    const int rend = q * 16 + 15;
    float r0s = 0.f, r1s = 0.f;
#pragma unroll 4
    for (int r = q * 16; r <= rend; ++r) {
      unsigned u = sFp[r * SFP + p];
      r0s += lo16f(u);
      r1s += hi16f(u);
      int dcur = sE4[r].y;
      bool last = (r == rend) || (sE4[r + 1].y != dcur);
      if (last) {
        atomicAdd(&Hagg[(size_t)dcur * HH + c0], r0s);
        atomicAdd(&Hagg[(size_t)dcur * HH + c0 + 16], r1s);
        r0s = 0.f;
        r1s = 0.f;
      }
    }
  }
}

// ---------------------------------------------------------------------------
// k_node: hidden = gelu(x@nW1a + Hm@W2' + nb1 + f*b2p); out = LN(hidden@nW2
// + nb2 + x). Hm = Hagg*rinv, f = cnt*rinv. f16 MFMA, x converted inline.
// ---------------------------------------------------------------------------
#define NS 264
__global__ __launch_bounds__(256, 4) void k_node(
    const float* __restrict__ x,
    const float* __restrict__ Hagg, const int* __restrict__ chist,
    const short* __restrict__ pn1, const short* __restrict__ pnW2p,
    const float* __restrict__ nb1, const float* __restrict__ b2p,
    const short* __restrict__ pn2, const float* __restrict__ nb2,
    const float* __restrict__ g, const float* __restrict__ be,
    float* __restrict__ out) {
  __shared__ short sA[64 * NS];
  __shared__ float sP[64 * 4];
  __shared__ float sP2[64 * 4];
  __shared__ float sFac[64];

  const int tid = threadIdx.x;
  const int r0 = blockIdx.x * 64;
  const int le = tid >> 2;
  const int lq = tid & 3;
  const int wv = tid >> 6;
  const int l = tid & 63;
  const int lr = l & 15;
  const int kq = l >> 4;

  const half8* bpa = (const half8*)pn1;
  const half8* bpc = (const half8*)pnW2p;
  half8 b1f[16];
#pragma unroll
  for (int kt = 0; kt < 4; ++kt)
#pragma unroll
    for (int c = 0; c < 2; ++c) {
      b1f[kt * 2 + c] = bpa[(kt * 8 + wv * 2 + c) * 64 + l];
      b1f[(kt + 4) * 2 + c] = bpc[(kt * 8 + wv * 2 + c) * 64 + l];
    }

  {
    const int gr = r0 + le;
    short* row = &sA[le * NS];
    if (gr < NN) {
      float cntf = (float)chist[gr];
      float rinv = 1.0f / (cntf + 1e-8f);
      if (lq == 0) sFac[le] = cntf * rinv;
      const float4* xs = (const float4*)(x + (size_t)gr * HH);
#pragma unroll
      for (int i = 0; i < 4; ++i) {
        float4 a = xs[lq * 8 + i * 2], c = xs[lq * 8 + i * 2 + 1];
        uint4 u = {pkh(a.x, a.y), pkh(a.z, a.w), pkh(c.x, c.y), pkh(c.z, c.w)};
        *(uint4*)(row + lq * 32 + i * 8) = u;
      }
      const float4* hs = (const float4*)(Hagg + (size_t)gr * HH);
#pragma unroll
      for (int i = 0; i < 4; ++i) {
        float4 a = hs[lq * 8 + i * 2], c = hs[lq * 8 + i * 2 + 1];
        uint4 u = {pkh(a.x * rinv, a.y * rinv), pkh(a.z * rinv, a.w * rinv),
                   pkh(c.x * rinv, c.y * rinv), pkh(c.z * rinv, c.w * rinv)};
        *(uint4*)(row + 128 + lq * 32 + i * 8) = u;
      }
    } else {
      if (lq == 0) sFac[le] = 0.f;
      uint4 z = {0, 0, 0, 0};
#pragma unroll
      for (int i = 0; i < 8; ++i) *(uint4*)(row + lq * 64 + i * 8) = z;
    }
  }
  __syncthreads();

  f32x4 acc[4][2];
  const f32x4 zero = {0.f, 0.f, 0.f, 0.f};
#pragma unroll
  for (int m = 0; m < 4; ++m) { acc[m][0] = zero; acc[m][1] = zero; }
  const short* ab = &sA[lr * NS + kq * 8];
#pragma unroll
  for (int kt = 0; kt < 8; ++kt) {
    half8 af[4];
#pragma unroll
    for (int m = 0; m < 4; ++m)
      af[m] = *(const half8*)(ab + m * 16 * NS + kt * 32);
#pragma unroll
    for (int m = 0; m < 4; ++m)
#pragma unroll
      for (int c = 0; c < 2; ++c)
        acc[m][c] = __builtin_amdgcn_mfma_f32_16x16x32_f16(af[m], b1f[kt * 2 + c], acc[m][c], 0, 0, 0);
  }

  const half8* bp2 = (const half8*)pn2;
  half8 b2f_[8];
#pragma unroll
  for (int kt = 0; kt < 4; ++kt)
#pragma unroll
    for (int c = 0; c < 2; ++c)
      b2f_[kt * 2 + c] = bp2[(kt * 8 + wv * 2 + c) * 64 + l];

  __syncthreads();

  // ---- bias (nb1 + f*b2p) + GELU -> sA cols 0..127 ----
#pragma unroll
  for (int c = 0; c < 2; ++c) {
    const int col = wv * 32 + c * 16 + lr;
    const float b1v = nb1[col];
    const float b2pv = b2p[col];
#pragma unroll
    for (int m = 0; m < 4; ++m)
#pragma unroll
      for (int r = 0; r < 4; ++r) {
        const int row = m * 16 + kq * 4 + r;
        float fac = sFac[row];
        sA[row * NS + col] = f2hs(gelu_f(acc[m][c][r] + b1v + fac * b2pv));
      }
  }
  __syncthreads();

  f32x4 acc2[4][2];
#pragma unroll
  for (int m = 0; m < 4; ++m) { acc2[m][0] = zero; acc2[m][1] = zero; }
#pragma unroll
  for (int kt = 0; kt < 4; ++kt) {
    half8 af[4];
#pragma unroll
    for (int m = 0; m < 4; ++m)
      af[m] = *(const half8*)(ab + m * 16 * NS + kt * 32);
#pragma unroll
    for (int m = 0; m < 4; ++m)
#pragma unroll
      for (int c = 0; c < 2; ++c)
        acc2[m][c] = __builtin_amdgcn_mfma_f32_16x16x32_f16(af[m], b2f_[kt * 2 + c], acc2[m][c], 0, 0, 0);
  }

  float val[4][2][4];
#pragma unroll
  for (int c = 0; c < 2; ++c) {
    const int col = wv * 32 + c * 16 + lr;
    const float b2v = nb2[col];
#pragma unroll
    for (int m = 0; m < 4; ++m)
#pragma unroll
      for (int r = 0; r < 4; ++r) {
        const int row = r0 + m * 16 + kq * 4 + r;
        float xr = (row < NN) ? x[(size_t)row * HH + col] : 0.f;
        val[m][c][r] = acc2[m][c][r] + b2v + xr;
      }
  }
#pragma unroll
  for (int m = 0; m < 4; ++m)
#pragma unroll
    for (int r = 0; r < 4; ++r) {
      float s = val[m][0][r] + val[m][1][r];
      float s2 = val[m][0][r] * val[m][0][r] + val[m][1][r] * val[m][1][r];
#pragma unroll
      for (int o = 1; o < 16; o <<= 1) {
        s += __shfl_xor(s, o);
        s2 += __shfl_xor(s2, o);
      }
      if (lr == 0) {
        const int row = m * 16 + kq * 4 + r;
        sP[row * 4 + wv] = s;
        sP2[row * 4 + wv] = s2;
      }
    }
  __syncthreads();

#pragma unroll
  for (int c = 0; c < 2; ++c) {
    const int col = wv * 32 + c * 16 + lr;
    const float gv = g[col];
    const float bv = be[col];
#pragma unroll
    for (int m = 0; m < 4; ++m)
#pragma unroll
      for (int r = 0; r < 4; ++r) {
        const int lrow = m * 16 + kq * 4 + r;
        const int row = r0 + lrow;
        if (row < NN) {
          float4 ps = *(float4*)&sP[lrow * 4];
          float4 qs = *(float4*)&sP2[lrow * 4];
          float s = ps.x + ps.y + ps.z + ps.w;
          float s2 = qs.x + qs.y + qs.z + qs.w;
          float mu = s * 0.0078125f;
          float var = s2 * 0.0078125f - mu * mu;
          float rs = rsqrtf(var + 1e-5f);
          out[(size_t)row * HH + col] = (val[m][c][r] - mu) * rs * gv + bv;
        }
      }
  }
}

extern "C" void kernel_launch(void* const* d_in, const int* in_sizes, int n_in,
                              void* d_out, int out_size, void* d_ws, size_t ws_size,
                              hipStream_t stream) {
  const float* x = (const float*)d_in[0];
  const void* ei = d_in[1];
  const float* ea = (const float*)d_in[2];
  const float* eW1 = (const float*)d_in[3];
  const float* eb1 = (const float*)d_in[4];
  const float* eW2 = (const float*)d_in[5];
  const float* eb2 = (const float*)d_in[6];
  const float* nW1 = (const float*)d_in[7];
  const float* nb1 = (const float*)d_in[8];
  const float* nW2 = (const float*)d_in[9];
  const float* nb2 = (const float*)d_in[10];
  const float* lng = (const float*)d_in[11];
  const float* lnb = (const float*)d_in[12];
  float* out = (float*)d_out;

  char* w = (char*)d_ws;
  size_t off = 0;
  auto alloc = [&](size_t bytes) { void* p = w + off; off = (off + bytes + 255) & ~(size_t)255; return p; };
  float* Hagg = (float*)alloc((size_t)NN * HH * 4);     // zeroed
  int* chist = (int*)alloc((size_t)NBINS * 4);          // zeroed (contiguous)
  int* cntW = (int*)alloc((size_t)NBINS * 4);           // zeroed (contiguous)
  short* pe1 = (short*)alloc((size_t)72 * 512 * 2);
  short* pn1 = (short*)alloc((size_t)64 * 512 * 2);
  short* pn2 = (short*)alloc((size_t)32 * 512 * 2);
  short* pnW2p = (short*)alloc((size_t)32 * 512 * 2);
  float* b2p = (float*)alloc(HH * 4);
  int4* e4 = (int4*)alloc((size_t)EE * 16);
  int* tmpS = (int*)alloc((size_t)NBINS * 4);
  int* bsum = (int*)alloc(256 * 4);
  int* flag = (int*)alloc(256);
  unsigned* Psw = (unsigned*)alloc((size_t)NN * 64 * 4);
  unsigned* Pdw = (unsigned*)alloc((size_t)NN * 64 * 4);

  hipMemsetAsync(Hagg, 0, (size_t)NN * HH * 4 + (size_t)NBINS * 4 * 2, stream);
  k_detect<<<1, 256, 0, stream>>>((const long long*)ei, 2048, (long long)NN, flag);
  k_hist<<<(EE + 255) / 256, 256, 0, stream>>>(ei, chist, flag);
  k_scan1<<<NBINS / 256, 256, 0, stream>>>(chist, tmpS, bsum);
  k_scan2<<<1, 256, 0, stream>>>(bsum);
  k_scatter<<<(EE + 255) / 256, 256, 0, stream>>>(ei, flag, tmpS, chist, bsum, cntW, e4);
  k_pack_all<<<168, 64, 0, stream>>>(eW1, nW1, nW2, pe1, pn1, pn2);
  k_w2p<<<3, 256, 0, stream>>>(eW2, eb2, nW1, pn1, pnW2p, b2p);
  k_pre<<<(NN + 63) / 64, 256, 0, stream>>>(x, pe1, Psw, Pdw);
  k_edge<<<EE / 64, 256, 0, stream>>>(Psw, Pdw, ea, pe1, eb1, e4, Hagg);
  k_node<<<(NN + 63) / 64, 256, 0, stream>>>(x, Hagg, chist, pn1, pnW2p, nb1, b2p, pn2, nb2, lng, lnb, out);
}

// Round 8
// 198.259 us; speedup vs baseline: 12.3891x; 1.0173x over previous
//
#include <hip/hip_runtime.h>
#include <hip/hip_fp16.h>
#include <math.h>

#define NN 50000
#define HH 128
#define EE 600000
#define EDD 32
#define NBINS 50176   // 196*256 >= NN

typedef __attribute__((ext_vector_type(8))) _Float16 half8;
typedef __attribute__((ext_vector_type(4))) float f32x4;

__device__ __forceinline__ unsigned pkh(float a, float b) {
  __half2 h = __floats2half2_rn(a, b);
  return *reinterpret_cast<unsigned*>(&h);
}
__device__ __forceinline__ unsigned hadd2u(unsigned a, unsigned b) {
  __half2 x = *reinterpret_cast<__half2*>(&a);
  __half2 y = *reinterpret_cast<__half2*>(&b);
  __half2 s = __hadd2(x, y);
  return *reinterpret_cast<unsigned*>(&s);
}
__device__ __forceinline__ float lo16f(unsigned u) {
  __half2 h = *reinterpret_cast<__half2*>(&u);
  return __low2float(h);
}
__device__ __forceinline__ float hi16f(unsigned u) {
  __half2 h = *reinterpret_cast<__half2*>(&u);
  return __high2float(h);
}
__device__ __forceinline__ short f2hs(float f) {
  __half h = __float2half_rn(f);
  return *reinterpret_cast<short*>(&h);
}

// tanh-form GELU via native v_exp_f32 / v_rcp_f32:
// gelu(v) = v * (1 - 1/(exp2(K*v*(1+0.044715 v^2)) + 1)),
// K = 2*sqrt(2/pi)*log2(e) = 2.3022082. Saturates exactly: v (v>>0), 0 (v<<0).
__device__ __forceinline__ float gelu_f(float v) {
  float u = 2.3022082f * v * fmaf(0.044715f, v * v, 1.0f);
  float e = __builtin_amdgcn_exp2f(u);
  float r = __builtin_amdgcn_rcpf(e + 1.0f);
  return fmaf(-v, r, v);
}

// ---------------------------------------------------------------------------
// k_setup: blocks 0..167 pack eW1/nW1/nW2 into f16 MFMA B-fragment order;
// block 168 detects int64 vs int32 edge_index (flag=1 -> int64).
//   P[((kt*8+ct)*64 + lane)*8 + j] = W[kt*32 + (lane>>4)*8 + j][ct*16 + (lane&15)]
// ---------------------------------------------------------------------------
__global__ void k_setup(const float* __restrict__ eW1, const float* __restrict__ nW1,
                        const float* __restrict__ nW2, const long long* __restrict__ ei,
                        long long nmax,
                        short* __restrict__ pe1, short* __restrict__ pn1,
                        short* __restrict__ pn2, int* __restrict__ flag) {
  __shared__ int bad;
  const int blk = blockIdx.x;
  const int l = threadIdx.x;
  if (blk == 168) {
    if (l == 0) bad = 0;
    __syncthreads();
    for (int i = l; i < 2048; i += 64) {
      long long v = ei[i];
      if (v < 0 || v >= nmax) bad = 1;
    }
    __syncthreads();
    if (l == 0) *flag = (bad ? 0 : 1);
    return;
  }
  const float* W;
  short* P;
  int b;
  if (blk < 72)       { W = eW1; P = pe1; b = blk; }
  else if (blk < 136) { W = nW1; P = pn1; b = blk - 72; }
  else                { W = nW2; P = pn2; b = blk - 136; }
  const int kt = b >> 3, ct = b & 7;
  short v[8];
#pragma unroll
  for (int j = 0; j < 8; ++j)
    v[j] = f2hs(W[(size_t)(kt * 32 + ((l >> 4) * 8 + j)) * HH + ct * 16 + (l & 15)]);
  short* dst = P + ((size_t)b * 64 + l) * 8;
#pragma unroll
  for (int j = 0; j < 8; ++j) dst[j] = v[j];
}

// ---------------------------------------------------------------------------
// histogram of dst.
// ---------------------------------------------------------------------------
__global__ void k_hist(const void* __restrict__ eiv, int* __restrict__ chist,
                       const int* __restrict__ flag) {
  int e = blockIdx.x * blockDim.x + threadIdx.x;
  if (e >= EE) return;
  int d;
  if (*flag) d = (int)((const long long*)eiv)[EE + e];
  else       d = ((const int*)eiv)[EE + e];
  atomicAdd(&chist[d], 1);
}

// ---------------------------------------------------------------------------
// prefix scan (inclusive within block) + block sums; then exclusive over blocks.
// ---------------------------------------------------------------------------
__global__ void k_scan1(const int* __restrict__ chist, int* __restrict__ tmp,
                        int* __restrict__ bsum) {
  __shared__ int buf[2][256];
  int t = threadIdx.x;
  int i = blockIdx.x * 256 + t;
  buf[0][t] = chist[i];
  __syncthreads();
  int cur = 0;
  for (int o = 1; o < 256; o <<= 1) {
    int v = buf[cur][t];
    if (t >= o) v += buf[cur][t - o];
    buf[cur ^ 1][t] = v;
    __syncthreads();
    cur ^= 1;
  }
  tmp[i] = buf[cur][t];
  if (t == 255) bsum[blockIdx.x] = buf[cur][255];
}

__global__ void k_scan2(int* __restrict__ bsum) {
  __shared__ int buf[2][256];
  int t = threadIdx.x;
  int orig = (t < 196) ? bsum[t] : 0;
  buf[0][t] = orig;
  __syncthreads();
  int cur = 0;
  for (int o = 1; o < 256; o <<= 1) {
    int v = buf[cur][t];
    if (t >= o) v += buf[cur][t - o];
    buf[cur ^ 1][t] = v;
    __syncthreads();
    cur ^= 1;
  }
  if (t < 196) bsum[t] = buf[cur][t] - orig;   // exclusive
}

// ---------------------------------------------------------------------------
// scatter edges into dst-sorted int4 records (src, dst, eid, 0).
// ---------------------------------------------------------------------------
__global__ void k_scatter(const void* __restrict__ eiv, const int* __restrict__ flag,
                          const int* __restrict__ tmp, const int* __restrict__ chist,
                          const int* __restrict__ bsum, int* __restrict__ cntW,
                          int4* __restrict__ e4) {
  int e = blockIdx.x * blockDim.x + threadIdx.x;
  if (e >= EE) return;
  int s, d;
  if (*flag) {
    const long long* p = (const long long*)eiv;
    s = (int)p[e];
    d = (int)p[EE + e];
  } else {
    const int* p = (const int*)eiv;
    s = p[e];
    d = p[EE + e];
  }
  int base = tmp[d] - chist[d] + bsum[d >> 8];
  int pos = base + atomicAdd(&cntW[d], 1);
  e4[pos] = make_int4(s, d, e, 0);
}

// ---------------------------------------------------------------------------
// blocks 0,1: W2' = eW2 @ nW1b (128x128) -> f16 B-frag pack order.
// block 2:    b2p = eb2 @ nW1b (128 vec, f32).
// ---------------------------------------------------------------------------
#define FS 132
__global__ __launch_bounds__(256, 2) void k_w2p(
    const float* __restrict__ eW2, const float* __restrict__ eb2,
    const float* __restrict__ nW1, const short* __restrict__ pn1,
    short* __restrict__ pnW2p, float* __restrict__ b2p) {
  const int b = blockIdx.x;
  const int tid = threadIdx.x;
  if (b == 2) {
    if (tid < 128) {
      float acc = 0.f;
#pragma unroll 4
      for (int k = 0; k < 128; ++k)
        acc += eb2[k] * nW1[(size_t)(128 + k) * HH + tid];
      b2p[tid] = acc;
    }
    return;
  }
  __shared__ short sA[64 * 136];
  __shared__ float sR[64 * FS];
  const int le = tid >> 2, lq = tid & 3;
  const int wv = tid >> 6, l = tid & 63, lr = l & 15, kq = l >> 4;

  const half8* bp = (const half8*)pn1;
  half8 bf[8];
#pragma unroll
  for (int kt = 0; kt < 4; ++kt)
#pragma unroll
    for (int c = 0; c < 2; ++c)
      bf[kt * 2 + c] = bp[((kt + 4) * 8 + wv * 2 + c) * 64 + l];

  {
    const float4* xs = (const float4*)(eW2 + (size_t)(64 * b + le) * HH);
#pragma unroll
    for (int i = 0; i < 4; ++i) {
      float4 a = xs[lq * 8 + i * 2], c = xs[lq * 8 + i * 2 + 1];
      uint4 u = {pkh(a.x, a.y), pkh(a.z, a.w), pkh(c.x, c.y), pkh(c.z, c.w)};
      *(uint4*)&sA[le * 136 + lq * 32 + i * 8] = u;
    }
  }
  __syncthreads();

  f32x4 acc[4][2];
  const f32x4 zero = {0.f, 0.f, 0.f, 0.f};
#pragma unroll
  for (int m = 0; m < 4; ++m) { acc[m][0] = zero; acc[m][1] = zero; }
  const short* ab = &sA[lr * 136 + kq * 8];
#pragma unroll
  for (int kt = 0; kt < 4; ++kt) {
    half8 af[4];
#pragma unroll
    for (int m = 0; m < 4; ++m) af[m] = *(const half8*)(ab + m * 16 * 136 + kt * 32);
#pragma unroll
    for (int m = 0; m < 4; ++m)
#pragma unroll
      for (int c = 0; c < 2; ++c)
        acc[m][c] = __builtin_amdgcn_mfma_f32_16x16x32_f16(af[m], bf[kt * 2 + c], acc[m][c], 0, 0, 0);
  }
#pragma unroll
  for (int c = 0; c < 2; ++c)
#pragma unroll
    for (int m = 0; m < 4; ++m)
#pragma unroll
      for (int r = 0; r < 4; ++r)
        sR[(m * 16 + kq * 4 + r) * FS + wv * 32 + c * 16 + lr] = acc[m][c][r];
  __syncthreads();

#pragma unroll
  for (int it = 0; it < 4; ++it) {
    int item = tid + 256 * it;
    int lane = item & 63;
    int pair = item >> 6;      // 0..15
    int ktl = pair >> 3, ct = pair & 7;
    short v[8];
#pragma unroll
    for (int j = 0; j < 8; ++j) {
      int rowl = ktl * 32 + ((lane >> 4) * 8 + j);
      int colp = ct * 16 + (lane & 15);
      v[j] = f2hs(sR[rowl * FS + colp]);
    }
    short* dst = pnW2p + (((size_t)(2 * b + ktl) * 8 + ct) * 64 + lane) * 8;
#pragma unroll
    for (int j = 0; j < 8; ++j) dst[j] = v[j];
  }
}

// ---------------------------------------------------------------------------
// k_pre: Psw/Pdw = packed-pair f16 of x@W1a, x@W1b; also zeroes its Hagg rows.
// Pair slot [node*64 + wv*16 + lr] = (col, col+16) where col = wv*32+lr.
// ---------------------------------------------------------------------------
__global__ __launch_bounds__(256, 4) void k_pre(
    const float* __restrict__ x, const short* __restrict__ pW1,
    unsigned* __restrict__ Psw, unsigned* __restrict__ Pdw,
    float* __restrict__ Hagg) {
  __shared__ short sX[64 * 136];
  const int tid = threadIdx.x;
  const int r0 = blockIdx.x * 64;
  const int le = tid >> 2, lq = tid & 3;
  const int wv = tid >> 6, l = tid & 63, lr = l & 15, kq = l >> 4;

  // zero this block's Hagg rows (replaces the big memset)
  {
    int gr = r0 + le;
    if (gr < NN) {
      float4 z = {0.f, 0.f, 0.f, 0.f};
      float4* hp = (float4*)(Hagg + (size_t)gr * HH) + lq * 8;
#pragma unroll
      for (int i = 0; i < 8; ++i) hp[i] = z;
    }
  }

  const half8* bp = (const half8*)pW1;
  half8 fa[8], fb[8];
#pragma unroll
  for (int kt = 0; kt < 4; ++kt)
#pragma unroll
    for (int c = 0; c < 2; ++c) {
      fa[kt * 2 + c] = bp[(kt * 8 + wv * 2 + c) * 64 + l];
      fb[kt * 2 + c] = bp[((kt + 4) * 8 + wv * 2 + c) * 64 + l];
    }
  {
    int gr = r0 + le;
    if (gr < NN) {
      const float4* xs = (const float4*)(x + (size_t)gr * HH);
#pragma unroll
      for (int i = 0; i < 4; ++i) {
        float4 a = xs[lq * 8 + i * 2], c = xs[lq * 8 + i * 2 + 1];
        uint4 u = {pkh(a.x, a.y), pkh(a.z, a.w), pkh(c.x, c.y), pkh(c.z, c.w)};
        *(uint4*)&sX[le * 136 + lq * 32 + i * 8] = u;
      }
    } else {
      uint4 z = {0, 0, 0, 0};
#pragma unroll
      for (int i = 0; i < 4; ++i) *(uint4*)&sX[le * 136 + lq * 32 + i * 8] = z;
    }
  }
  __syncthreads();

  f32x4 as_[4][2], ad[4][2];
  const f32x4 zero = {0.f, 0.f, 0.f, 0.f};
#pragma unroll
  for (int m = 0; m < 4; ++m) { as_[m][0] = zero; as_[m][1] = zero; ad[m][0] = zero; ad[m][1] = zero; }
  const short* ab = &sX[lr * 136 + kq * 8];
#pragma unroll
  for (int kt = 0; kt < 4; ++kt) {
    half8 af[4];
#pragma unroll
    for (int m = 0; m < 4; ++m) af[m] = *(const half8*)(ab + m * 16 * 136 + kt * 32);
#pragma unroll
    for (int m = 0; m < 4; ++m)
#pragma unroll
      for (int c = 0; c < 2; ++c) {
        as_[m][c] = __builtin_amdgcn_mfma_f32_16x16x32_f16(af[m], fa[kt * 2 + c], as_[m][c], 0, 0, 0);
        ad[m][c] = __builtin_amdgcn_mfma_f32_16x16x32_f16(af[m], fb[kt * 2 + c], ad[m][c], 0, 0, 0);
      }
  }
#pragma unroll
  for (int m = 0; m < 4; ++m)
#pragma unroll
    for (int r = 0; r < 4; ++r) {
      int grow = r0 + m * 16 + kq * 4 + r;
      if (grow < NN) {
        Psw[(size_t)grow * 64 + wv * 16 + lr] = pkh(as_[m][0][r], as_[m][1][r]);
        Pdw[(size_t)grow * 64 + wv * 16 + lr] = pkh(ad[m][0][r], ad[m][1][r]);
      }
    }
}

// ---------------------------------------------------------------------------
// k_edge: h = gelu(Ps[src]+Pd[dst] + ea@W1c + b1); segment-sum h -> Hagg[dst].
// Packed f16 pair pipeline; 22.8 KB LDS -> 7 blocks/CU.
// ---------------------------------------------------------------------------
#define SFP 68
__global__ __launch_bounds__(256, 6) void k_edge(
    const unsigned* __restrict__ Psw, const unsigned* __restrict__ Pdw,
    const float* __restrict__ ea,
    const short* __restrict__ pW1, const float* __restrict__ b1,
    const int4* __restrict__ e4, float* __restrict__ Hagg) {
  __shared__ unsigned sFp[64 * SFP];   // packed P-sum pairs, then packed h
  __shared__ short sEA[64 * 40];       // ea tile f16
  __shared__ int sDst[64];

  const int tid = threadIdx.x;
  const int e0 = blockIdx.x * 64;
  const int le = tid >> 2, lq = tid & 3;
  const int wv = tid >> 6, l = tid & 63, lr = l & 15, kq = l >> 4;

  // W1c (kt=8 of packed eW1) -> registers
  half8 w1c[2];
#pragma unroll
  for (int c = 0; c < 2; ++c)
    w1c[c] = ((const half8*)pW1)[(64 + wv * 2 + c) * 64 + l];

  const int4 er = e4[e0 + le];
  if (tid < 64) sDst[tid] = e4[e0 + tid].y;

  // ---- stage: packed P-sum pairs + ea ----
  {
    const uint4* ps = (const uint4*)(Psw + (size_t)er.x * 64);
    const uint4* pd = (const uint4*)(Pdw + (size_t)er.y * 64);
#pragma unroll
    for (int i = 0; i < 4; ++i) {
      uint4 a = ps[lq * 4 + i];
      uint4 b = pd[lq * 4 + i];
      uint4 s = {hadd2u(a.x, b.x), hadd2u(a.y, b.y), hadd2u(a.z, b.z), hadd2u(a.w, b.w)};
      *(uint4*)&sFp[le * SFP + lq * 16 + i * 4] = s;
    }
    const float4* ep = (const float4*)(ea + (size_t)er.z * EDD);
    float4 a = ep[lq * 2], b = ep[lq * 2 + 1];
    uint4 u = {pkh(a.x, a.y), pkh(a.z, a.w), pkh(b.x, b.y), pkh(b.z, b.w)};
    *(uint4*)&sEA[le * 40 + lq * 8] = u;
  }
  __syncthreads();

  // ---- ea @ W1c : single K=32 tile, 8 MFMA ----
  f32x4 acc[4][2];
  const f32x4 zero = {0.f, 0.f, 0.f, 0.f};
#pragma unroll
  for (int m = 0; m < 4; ++m) { acc[m][0] = zero; acc[m][1] = zero; }
  {
#pragma unroll
    for (int m = 0; m < 4; ++m) {
      half8 af = *(const half8*)&sEA[(m * 16 + lr) * 40 + kq * 8];
#pragma unroll
      for (int c = 0; c < 2; ++c)
        acc[m][c] = __builtin_amdgcn_mfma_f32_16x16x32_f16(af, w1c[c], acc[m][c], 0, 0, 0);
    }
  }

  // ---- h = gelu(acc + P + b1) -> same packed slot ----
  const float b1c0 = b1[wv * 32 + lr];
  const float b1c1 = b1[wv * 32 + 16 + lr];
#pragma unroll
  for (int m = 0; m < 4; ++m)
#pragma unroll
    for (int r = 0; r < 4; ++r) {
      const int row = m * 16 + kq * 4 + r;
      unsigned up = sFp[row * SFP + wv * 16 + lr];
      float v0 = acc[m][0][r] + lo16f(up) + b1c0;
      float v1 = acc[m][1][r] + hi16f(up) + b1c1;
      sFp[row * SFP + wv * 16 + lr] = pkh(gelu_f(v0), gelu_f(v1));
    }
  __syncthreads();

  // ---- segmented sum over sorted dst runs (f32 accum, packed reads) ----
  {
    const int p = tid & 63;
    const int q = tid >> 6;
    const int c0 = (p >> 4) * 32 + (p & 15);
    const int rend = q * 16 + 15;
    float r0s = 0.f, r1s = 0.f;
#pragma unroll 4
    for (int r = q * 16; r <= rend; ++r) {
      unsigned u = sFp[r * SFP + p];
      r0s += lo16f(u);
      r1s += hi16f(u);
      int dcur = sDst[r];
      bool last = (r == rend) || (sDst[r + 1] != dcur);
      if (last) {
        atomicAdd(&Hagg[(size_t)dcur * HH + c0], r0s);
        atomicAdd(&Hagg[(size_t)dcur * HH + c0 + 16], r1s);
        r0s = 0.f;
        r1s = 0.f;
      }
    }
  }
}

// ---------------------------------------------------------------------------
// k_node: hidden = gelu(x@nW1a + Hm@W2' + nb1 + f*b2p); out = LN(hidden@nW2
// + nb2 + x). Hm = Hagg*rinv, f = cnt*rinv. f16 MFMA, x converted inline.
// ---------------------------------------------------------------------------
#define NS 264
__global__ __launch_bounds__(256, 4) void k_node(
    const float* __restrict__ x,
    const float* __restrict__ Hagg, const int* __restrict__ chist,
    const short* __restrict__ pn1, const short* __restrict__ pnW2p,
    const float* __restrict__ nb1, const float* __restrict__ b2p,
    const short* __restrict__ pn2, const float* __restrict__ nb2,
    const float* __restrict__ g, const float* __restrict__ be,
    float* __restrict__ out) {
  __shared__ short sA[64 * NS];
  __shared__ float sP[64 * 4];
  __shared__ float sP2[64 * 4];
  __shared__ float sFac[64];

  const int tid = threadIdx.x;
  const int r0 = blockIdx.x * 64;
  const int le = tid >> 2;
  const int lq = tid & 3;
  const int wv = tid >> 6;
  const int l = tid & 63;
  const int lr = l & 15;
  const int kq = l >> 4;

  const half8* bpa = (const half8*)pn1;
  const half8* bpc = (const half8*)pnW2p;
  half8 b1f[16];
#pragma unroll
  for (int kt = 0; kt < 4; ++kt)
#pragma unroll
    for (int c = 0; c < 2; ++c) {
      b1f[kt * 2 + c] = bpa[(kt * 8 + wv * 2 + c) * 64 + l];
      b1f[(kt + 4) * 2 + c] = bpc[(kt * 8 + wv * 2 + c) * 64 + l];
    }

  {
    const int gr = r0 + le;
    short* row = &sA[le * NS];
    if (gr < NN) {
      float cntf = (float)chist[gr];
      float rinv = 1.0f / (cntf + 1e-8f);
      if (lq == 0) sFac[le] = cntf * rinv;
      const float4* xs = (const float4*)(x + (size_t)gr * HH);
#pragma unroll
      for (int i = 0; i < 4; ++i) {
        float4 a = xs[lq * 8 + i * 2], c = xs[lq * 8 + i * 2 + 1];
        uint4 u = {pkh(a.x, a.y), pkh(a.z, a.w), pkh(c.x, c.y), pkh(c.z, c.w)};
        *(uint4*)(row + lq * 32 + i * 8) = u;
      }
      const float4* hs = (const float4*)(Hagg + (size_t)gr * HH);
#pragma unroll
      for (int i = 0; i < 4; ++i) {
        float4 a = hs[lq * 8 + i * 2], c = hs[lq * 8 + i * 2 + 1];
        uint4 u = {pkh(a.x * rinv, a.y * rinv), pkh(a.z * rinv, a.w * rinv),
                   pkh(c.x * rinv, c.y * rinv), pkh(c.z * rinv, c.w * rinv)};
        *(uint4*)(row + 128 + lq * 32 + i * 8) = u;
      }
    } else {
      if (lq == 0) sFac[le] = 0.f;
      uint4 z = {0, 0, 0, 0};
#pragma unroll
      for (int i = 0; i < 8; ++i) *(uint4*)(row + lq * 64 + i * 8) = z;
    }
  }
  __syncthreads();

  f32x4 acc[4][2];
  const f32x4 zero = {0.f, 0.f, 0.f, 0.f};
#pragma unroll
  for (int m = 0; m < 4; ++m) { acc[m][0] = zero; acc[m][1] = zero; }
  const short* ab = &sA[lr * NS + kq * 8];
#pragma unroll
  for (int kt = 0; kt < 8; ++kt) {
    half8 af[4];
#pragma unroll
    for (int m = 0; m < 4; ++m)
      af[m] = *(const half8*)(ab + m * 16 * NS + kt * 32);
#pragma unroll
    for (int m = 0; m < 4; ++m)
#pragma unroll
      for (int c = 0; c < 2; ++c)
        acc[m][c] = __builtin_amdgcn_mfma_f32_16x16x32_f16(af[m], b1f[kt * 2 + c], acc[m][c], 0, 0, 0);
  }

  const half8* bp2 = (const half8*)pn2;
  half8 b2f_[8];
#pragma unroll
  for (int kt = 0; kt < 4; ++kt)
#pragma unroll
    for (int c = 0; c < 2; ++c)
      b2f_[kt * 2 + c] = bp2[(kt * 8 + wv * 2 + c) * 64 + l];

  __syncthreads();

  // ---- bias (nb1 + f*b2p) + GELU -> sA cols 0..127 ----
#pragma unroll
  for (int c = 0; c < 2; ++c) {
    const int col = wv * 32 + c * 16 + lr;
    const float b1v = nb1[col];
    const float b2pv = b2p[col];
#pragma unroll
    for (int m = 0; m < 4; ++m)
#pragma unroll
      for (int r = 0; r < 4; ++r) {
        const int row = m * 16 + kq * 4 + r;
        float fac = sFac[row];
        sA[row * NS + col] = f2hs(gelu_f(acc[m][c][r] + b1v + fac * b2pv));
      }
  }
  __syncthreads();

  f32x4 acc2[4][2];
#pragma unroll
  for (int m = 0; m < 4; ++m) { acc2[m][0] = zero; acc2[m][1] = zero; }
#pragma unroll
  for (int kt = 0; kt < 4; ++kt) {
    half8 af[4];
#pragma unroll
    for (int m = 0; m < 4; ++m)
      af[m] = *(const half8*)(ab + m * 16 * NS + kt * 32);
#pragma unroll
    for (int m = 0; m < 4; ++m)
#pragma unroll
      for (int c = 0; c < 2; ++c)
        acc2[m][c] = __builtin_amdgcn_mfma_f32_16x16x32_f16(af[m], b2f_[kt * 2 + c], acc2[m][c], 0, 0, 0);
  }

  float val[4][2][4];
#pragma unroll
  for (int c = 0; c < 2; ++c) {
    const int col = wv * 32 + c * 16 + lr;
    const float b2v = nb2[col];
#pragma unroll
    for (int m = 0; m < 4; ++m)
#pragma unroll
      for (int r = 0; r < 4; ++r) {
        const int row = r0 + m * 16 + kq * 4 + r;
        float xr = (row < NN) ? x[(size_t)row * HH + col] : 0.f;
        val[m][c][r] = acc2[m][c][r] + b2v + xr;
      }
  }
#pragma unroll
  for (int m = 0; m < 4; ++m)
#pragma unroll
    for (int r = 0; r < 4; ++r) {
      float s = val[m][0][r] + val[m][1][r];
      float s2 = val[m][0][r] * val[m][0][r] + val[m][1][r] * val[m][1][r];
#pragma unroll
      for (int o = 1; o < 16; o <<= 1) {
        s += __shfl_xor(s, o);
        s2 += __shfl_xor(s2, o);
      }
      if (lr == 0) {
        const int row = m * 16 + kq * 4 + r;
        sP[row * 4 + wv] = s;
        sP2[row * 4 + wv] = s2;
      }
    }
  __syncthreads();

#pragma unroll
  for (int c = 0; c < 2; ++c) {
    const int col = wv * 32 + c * 16 + lr;
    const float gv = g[col];
    const float bv = be[col];
#pragma unroll
    for (int m = 0; m < 4; ++m)
#pragma unroll
      for (int r = 0; r < 4; ++r) {
        const int lrow = m * 16 + kq * 4 + r;
        const int row = r0 + lrow;
        if (row < NN) {
          float4 ps = *(float4*)&sP[lrow * 4];
          float4 qs = *(float4*)&sP2[lrow * 4];
          float s = ps.x + ps.y + ps.z + ps.w;
          float s2 = qs.x + qs.y + qs.z + qs.w;
          float mu = s * 0.0078125f;
          float var = s2 * 0.0078125f - mu * mu;
          float rs = rsqrtf(var + 1e-5f);
          out[(size_t)row * HH + col] = (val[m][c][r] - mu) * rs * gv + bv;
        }
      }
  }
}

extern "C" void kernel_launch(void* const* d_in, const int* in_sizes, int n_in,
                              void* d_out, int out_size, void* d_ws, size_t ws_size,
                              hipStream_t stream) {
  const float* x = (const float*)d_in[0];
  const void* ei = d_in[1];
  const float* ea = (const float*)d_in[2];
  const float* eW1 = (const float*)d_in[3];
  const float* eb1 = (const float*)d_in[4];
  const float* eW2 = (const float*)d_in[5];
  const float* eb2 = (const float*)d_in[6];
  const float* nW1 = (const float*)d_in[7];
  const float* nb1 = (const float*)d_in[8];
  const float* nW2 = (const float*)d_in[9];
  const float* nb2 = (const float*)d_in[10];
  const float* lng = (const float*)d_in[11];
  const float* lnb = (const float*)d_in[12];
  float* out = (float*)d_out;

  char* w = (char*)d_ws;
  size_t off = 0;
  auto alloc = [&](size_t bytes) { void* p = w + off; off = (off + bytes + 255) & ~(size_t)255; return p; };
  float* Hagg = (float*)alloc((size_t)NN * HH * 4);     // zeroed by k_pre
  int* chist = (int*)alloc((size_t)NBINS * 4);          // zeroed (contiguous)
  int* cntW = (int*)alloc((size_t)NBINS * 4);           // zeroed (contiguous)
  short* pe1 = (short*)alloc((size_t)72 * 512 * 2);
  short* pn1 = (short*)alloc((size_t)64 * 512 * 2);
  short* pn2 = (short*)alloc((size_t)32 * 512 * 2);
  short* pnW2p = (short*)alloc((size_t)32 * 512 * 2);
  float* b2p = (float*)alloc(HH * 4);
  int4* e4 = (int4*)alloc((size_t)EE * 16);
  int* tmpS = (int*)alloc((size_t)NBINS * 4);
  int* bsum = (int*)alloc(256 * 4);
  int* flag = (int*)alloc(256);
  unsigned* Psw = (unsigned*)alloc((size_t)NN * 64 * 4);
  unsigned* Pdw = (unsigned*)alloc((size_t)NN * 64 * 4);

  hipMemsetAsync(chist, 0, (size_t)NBINS * 4 * 2, stream);
  k_setup<<<169, 64, 0, stream>>>(eW1, nW1, nW2, (const long long*)ei, (long long)NN,
                                  pe1, pn1, pn2, flag);
  k_hist<<<(EE + 255) / 256, 256, 0, stream>>>(ei, chist, flag);
  k_scan1<<<NBINS / 256, 256, 0, stream>>>(chist, tmpS, bsum);
  k_scan2<<<1, 256, 0, stream>>>(bsum);
  k_scatter<<<(EE + 255) / 256, 256, 0, stream>>>(ei, flag, tmpS, chist, bsum, cntW, e4);
  k_w2p<<<3, 256, 0, stream>>>(eW2, eb2, nW1, pn1, pnW2p, b2p);
  k_pre<<<(NN + 63) / 64, 256, 0, stream>>>(x, pe1, Psw, Pdw, Hagg);
  k_edge<<<EE / 64, 256, 0, stream>>>(Psw, Pdw, ea, pe1, eb1, e4, Hagg);
  k_node<<<(NN + 63) / 64, 256, 0, stream>>>(x, Hagg, chist, pn1, pnW2p, nb1, b2p, pn2, nb2, lng, lnb, out);
}

// Round 9
// 170.927 us; speedup vs baseline: 14.3702x; 1.1599x over previous
//
#include <hip/hip_runtime.h>
#include <hip/hip_fp16.h>
#include <math.h>

#define NN 50000
#define HH 128
#define EE 600000
#define EDD 32
#define NBINS 50176   // 196*256 >= NN
#define NPRE 782      // (NN+63)/64

typedef __attribute__((ext_vector_type(8))) _Float16 half8;
typedef __attribute__((ext_vector_type(4))) float f32x4;

__device__ __forceinline__ unsigned pkh(float a, float b) {
  __half2 h = __floats2half2_rn(a, b);
  return *reinterpret_cast<unsigned*>(&h);
}
__device__ __forceinline__ unsigned hadd2u(unsigned a, unsigned b) {
  __half2 x = *reinterpret_cast<__half2*>(&a);
  __half2 y = *reinterpret_cast<__half2*>(&b);
  __half2 s = __hadd2(x, y);
  return *reinterpret_cast<unsigned*>(&s);
}
__device__ __forceinline__ float lo16f(unsigned u) {
  __half2 h = *reinterpret_cast<__half2*>(&u);
  return __low2float(h);
}
__device__ __forceinline__ float hi16f(unsigned u) {
  __half2 h = *reinterpret_cast<__half2*>(&u);
  return __high2float(h);
}
__device__ __forceinline__ short f2hs(float f) {
  __half h = __float2half_rn(f);
  return *reinterpret_cast<short*>(&h);
}
__device__ __forceinline__ float h2f(short s) {
  __half h = *reinterpret_cast<__half*>(&s);
  return __half2float(h);
}

// tanh-form GELU via native v_exp_f32 / v_rcp_f32 (saturates exactly).
__device__ __forceinline__ float gelu_f(float v) {
  float u = 2.3022082f * v * fmaf(0.044715f, v * v, 1.0f);
  float e = __builtin_amdgcn_exp2f(u);
  float r = __builtin_amdgcn_rcpf(e + 1.0f);
  return fmaf(-v, r, v);
}

// ---------------------------------------------------------------------------
// k_setup (one launch, 95 blocks x 256):
//   blocks 0..41 : pack eW1/nW1/nW2 into f16 MFMA B-frag order (4 sub-tiles each)
//   block 42     : detect int64 vs int32 edge_index (flag=1 -> int64)
//   blocks 43..91: zero chist+cntW (2*NBINS ints)
//   blocks 92,93 : W2' = eW2 @ nW1b (f16 B-frag pack order), nW1b read direct
//   block 94     : b2p = eb2 @ nW1b (f32 vector)
// pack formula: P[((kt*8+ct)*64+lane)*8+j] = W[kt*32+(lane>>4)*8+j][ct*16+(lane&15)]
// ---------------------------------------------------------------------------
#define FS 132
__global__ __launch_bounds__(256) void k_setup(
    const float* __restrict__ eW1, const float* __restrict__ nW1,
    const float* __restrict__ nW2, const float* __restrict__ eW2,
    const float* __restrict__ eb2, const long long* __restrict__ ei,
    long long nmax,
    short* __restrict__ pe1, short* __restrict__ pn1, short* __restrict__ pn2,
    short* __restrict__ pnW2p, float* __restrict__ b2p,
    int* __restrict__ zbase, int* __restrict__ flag) {
  __shared__ short sA[64 * 136];
  __shared__ float sR[64 * FS];
  __shared__ int bad;
  const int blk = blockIdx.x;
  const int tid = threadIdx.x;

  if (blk < 42) {                       // ---- weight pack ----
    const int b = blk * 4 + (tid >> 6);
    const int l = tid & 63;
    const float* W;
    short* P;
    int bb;
    if (b < 72)       { W = eW1; P = pe1; bb = b; }
    else if (b < 136) { W = nW1; P = pn1; bb = b - 72; }
    else              { W = nW2; P = pn2; bb = b - 136; }
    const int kt = bb >> 3, ct = bb & 7;
    short v[8];
#pragma unroll
    for (int j = 0; j < 8; ++j)
      v[j] = f2hs(W[(size_t)(kt * 32 + ((l >> 4) * 8 + j)) * HH + ct * 16 + (l & 15)]);
    short* dst = P + ((size_t)bb * 64 + l) * 8;
#pragma unroll
    for (int j = 0; j < 8; ++j) dst[j] = v[j];
    return;
  }
  if (blk == 42) {                      // ---- dtype detect ----
    if (tid == 0) bad = 0;
    __syncthreads();
    for (int i = tid; i < 2048; i += 256) {
      long long v = ei[i];
      if (v < 0 || v >= nmax) bad = 1;
    }
    __syncthreads();
    if (tid == 0) *flag = (bad ? 0 : 1);
    return;
  }
  if (blk < 92) {                       // ---- zero chist+cntW ----
    int idx = (blk - 43) * 2048 + tid * 8;
    int4 z = {0, 0, 0, 0};
    *(int4*)(zbase + idx) = z;
    *(int4*)(zbase + idx + 4) = z;
    return;
  }
  if (blk == 94) {                      // ---- b2p ----
    if (tid < 128) {
      float acc = 0.f;
#pragma unroll 4
      for (int k = 0; k < 128; ++k)
        acc += eb2[k] * nW1[(size_t)(128 + k) * HH + tid];
      b2p[tid] = acc;
    }
    return;
  }
  // ---- W2' GEMM (blocks 92,93) ----
  {
    const int b = blk - 92;
    const int le = tid >> 2, lq = tid & 3;
    const int wv = tid >> 6, l = tid & 63, lr = l & 15, kq = l >> 4;

    half8 bf[8];
#pragma unroll
    for (int kt = 0; kt < 4; ++kt)
#pragma unroll
      for (int c = 0; c < 2; ++c) {
        half8 v;
#pragma unroll
        for (int j = 0; j < 8; ++j)
          v[j] = (_Float16)nW1[(size_t)(128 + kt * 32 + ((l >> 4) * 8 + j)) * HH +
                               (wv * 2 + c) * 16 + (l & 15)];
        bf[kt * 2 + c] = v;
      }
    {
      const float4* xs = (const float4*)(eW2 + (size_t)(64 * b + le) * HH);
#pragma unroll
      for (int i = 0; i < 4; ++i) {
        float4 a = xs[lq * 8 + i * 2], c = xs[lq * 8 + i * 2 + 1];
        uint4 u = {pkh(a.x, a.y), pkh(a.z, a.w), pkh(c.x, c.y), pkh(c.z, c.w)};
        *(uint4*)&sA[le * 136 + lq * 32 + i * 8] = u;
      }
    }
    __syncthreads();

    f32x4 acc[4][2];
    const f32x4 zero = {0.f, 0.f, 0.f, 0.f};
#pragma unroll
    for (int m = 0; m < 4; ++m) { acc[m][0] = zero; acc[m][1] = zero; }
    const short* ab = &sA[lr * 136 + kq * 8];
#pragma unroll
    for (int kt = 0; kt < 4; ++kt) {
      half8 af[4];
#pragma unroll
      for (int m = 0; m < 4; ++m) af[m] = *(const half8*)(ab + m * 16 * 136 + kt * 32);
#pragma unroll
      for (int m = 0; m < 4; ++m)
#pragma unroll
        for (int c = 0; c < 2; ++c)
          acc[m][c] = __builtin_amdgcn_mfma_f32_16x16x32_f16(af[m], bf[kt * 2 + c], acc[m][c], 0, 0, 0);
    }
#pragma unroll
    for (int c = 0; c < 2; ++c)
#pragma unroll
      for (int m = 0; m < 4; ++m)
#pragma unroll
        for (int r = 0; r < 4; ++r)
          sR[(m * 16 + kq * 4 + r) * FS + wv * 32 + c * 16 + lr] = acc[m][c][r];
    __syncthreads();

#pragma unroll
    for (int it = 0; it < 4; ++it) {
      int item = tid + 256 * it;
      int lane = item & 63;
      int pair = item >> 6;      // 0..15
      int ktl = pair >> 3, ct = pair & 7;
      short v[8];
#pragma unroll
      for (int j = 0; j < 8; ++j) {
        int rowl = ktl * 32 + ((lane >> 4) * 8 + j);
        int colp = ct * 16 + (lane & 15);
        v[j] = f2hs(sR[rowl * FS + colp]);
      }
      short* dst = pnW2p + (((size_t)(2 * b + ktl) * 8 + ct) * 64 + lane) * 8;
#pragma unroll
      for (int j = 0; j < 8; ++j) dst[j] = v[j];
    }
  }
}

// ---------------------------------------------------------------------------
// k_preh: blocks 0..NPRE-1: Psw/Pdw = packed-pair f16 of x@W1a/x@W1b + zero
// Hagg rows. blocks NPRE.. : dst histogram.
// ---------------------------------------------------------------------------
__global__ __launch_bounds__(256, 4) void k_preh(
    const float* __restrict__ x, const short* __restrict__ pW1,
    const void* __restrict__ eiv, const int* __restrict__ flag,
    unsigned* __restrict__ Psw, unsigned* __restrict__ Pdw,
    float* __restrict__ Hagg, int* __restrict__ chist) {
  __shared__ short sX[64 * 136];
  const int blk = blockIdx.x;
  const int tid = threadIdx.x;

  if (blk >= NPRE) {                    // ---- histogram ----
    int e = (blk - NPRE) * 256 + tid;
    if (e < EE) {
      int d;
      if (*flag) d = (int)((const long long*)eiv)[EE + e];
      else       d = ((const int*)eiv)[EE + e];
      atomicAdd(&chist[d], 1);
    }
    return;
  }

  const int r0 = blk * 64;
  const int le = tid >> 2, lq = tid & 3;
  const int wv = tid >> 6, l = tid & 63, lr = l & 15, kq = l >> 4;

  // zero this block's Hagg rows
  {
    int gr = r0 + le;
    if (gr < NN) {
      float4 z = {0.f, 0.f, 0.f, 0.f};
      float4* hp = (float4*)(Hagg + (size_t)gr * HH) + lq * 8;
#pragma unroll
      for (int i = 0; i < 8; ++i) hp[i] = z;
    }
  }

  const half8* bp = (const half8*)pW1;
  half8 fa[8], fb[8];
#pragma unroll
  for (int kt = 0; kt < 4; ++kt)
#pragma unroll
    for (int c = 0; c < 2; ++c) {
      fa[kt * 2 + c] = bp[(kt * 8 + wv * 2 + c) * 64 + l];
      fb[kt * 2 + c] = bp[((kt + 4) * 8 + wv * 2 + c) * 64 + l];
    }
  {
    int gr = r0 + le;
    if (gr < NN) {
      const float4* xs = (const float4*)(x + (size_t)gr * HH);
#pragma unroll
      for (int i = 0; i < 4; ++i) {
        float4 a = xs[lq * 8 + i * 2], c = xs[lq * 8 + i * 2 + 1];
        uint4 u = {pkh(a.x, a.y), pkh(a.z, a.w), pkh(c.x, c.y), pkh(c.z, c.w)};
        *(uint4*)&sX[le * 136 + lq * 32 + i * 8] = u;
      }
    } else {
      uint4 z = {0, 0, 0, 0};
#pragma unroll
      for (int i = 0; i < 4; ++i) *(uint4*)&sX[le * 136 + lq * 32 + i * 8] = z;
    }
  }
  __syncthreads();

  f32x4 as_[4][2], ad[4][2];
  const f32x4 zero = {0.f, 0.f, 0.f, 0.f};
#pragma unroll
  for (int m = 0; m < 4; ++m) { as_[m][0] = zero; as_[m][1] = zero; ad[m][0] = zero; ad[m][1] = zero; }
  const short* ab = &sX[lr * 136 + kq * 8];
#pragma unroll
  for (int kt = 0; kt < 4; ++kt) {
    half8 af[4];
#pragma unroll
    for (int m = 0; m < 4; ++m) af[m] = *(const half8*)(ab + m * 16 * 136 + kt * 32);
#pragma unroll
    for (int m = 0; m < 4; ++m)
#pragma unroll
      for (int c = 0; c < 2; ++c) {
        as_[m][c] = __builtin_amdgcn_mfma_f32_16x16x32_f16(af[m], fa[kt * 2 + c], as_[m][c], 0, 0, 0);
        ad[m][c] = __builtin_amdgcn_mfma_f32_16x16x32_f16(af[m], fb[kt * 2 + c], ad[m][c], 0, 0, 0);
      }
  }
#pragma unroll
  for (int m = 0; m < 4; ++m)
#pragma unroll
    for (int r = 0; r < 4; ++r) {
      int grow = r0 + m * 16 + kq * 4 + r;
      if (grow < NN) {
        Psw[(size_t)grow * 64 + wv * 16 + lr] = pkh(as_[m][0][r], as_[m][1][r]);
        Pdw[(size_t)grow * 64 + wv * 16 + lr] = pkh(ad[m][0][r], ad[m][1][r]);
      }
    }
}

// ---------------------------------------------------------------------------
// prefix scan (inclusive within block) + block sums; then exclusive over blocks.
// ---------------------------------------------------------------------------
__global__ void k_scan1(const int* __restrict__ chist, int* __restrict__ tmp,
                        int* __restrict__ bsum) {
  __shared__ int buf[2][256];
  int t = threadIdx.x;
  int i = blockIdx.x * 256 + t;
  buf[0][t] = chist[i];
  __syncthreads();
  int cur = 0;
  for (int o = 1; o < 256; o <<= 1) {
    int v = buf[cur][t];
    if (t >= o) v += buf[cur][t - o];
    buf[cur ^ 1][t] = v;
    __syncthreads();
    cur ^= 1;
  }
  tmp[i] = buf[cur][t];
  if (t == 255) bsum[blockIdx.x] = buf[cur][255];
}

__global__ void k_scan2(int* __restrict__ bsum) {
  __shared__ int buf[2][256];
  int t = threadIdx.x;
  int orig = (t < 196) ? bsum[t] : 0;
  buf[0][t] = orig;
  __syncthreads();
  int cur = 0;
  for (int o = 1; o < 256; o <<= 1) {
    int v = buf[cur][t];
    if (t >= o) v += buf[cur][t - o];
    buf[cur ^ 1][t] = v;
    __syncthreads();
    cur ^= 1;
  }
  if (t < 196) bsum[t] = buf[cur][t] - orig;   // exclusive
}

// ---------------------------------------------------------------------------
// scatter edges into dst-sorted int4 records (src, dst, eid, 0).
// ---------------------------------------------------------------------------
__global__ void k_scatter(const void* __restrict__ eiv, const int* __restrict__ flag,
                          const int* __restrict__ tmp, const int* __restrict__ chist,
                          const int* __restrict__ bsum, int* __restrict__ cntW,
                          int4* __restrict__ e4) {
  int e = blockIdx.x * blockDim.x + threadIdx.x;
  if (e >= EE) return;
  int s, d;
  if (*flag) {
    const long long* p = (const long long*)eiv;
    s = (int)p[e];
    d = (int)p[EE + e];
  } else {
    const int* p = (const int*)eiv;
    s = p[e];
    d = p[EE + e];
  }
  int base = tmp[d] - chist[d] + bsum[d >> 8];
  int pos = base + atomicAdd(&cntW[d], 1);
  e4[pos] = make_int4(s, d, e, 0);
}

// ---------------------------------------------------------------------------
// k_edge: h = gelu(Ps[src]+Pd[dst] + ea@W1c + b1); segment-sum h -> Hagg[dst].
// Packed f16 pair pipeline; 22.8 KB LDS -> 7 blocks/CU.
// ---------------------------------------------------------------------------
#define SFP 68
__global__ __launch_bounds__(256, 7) void k_edge(
    const unsigned* __restrict__ Psw, const unsigned* __restrict__ Pdw,
    const float* __restrict__ ea,
    const short* __restrict__ pW1, const float* __restrict__ b1,
    const int4* __restrict__ e4, float* __restrict__ Hagg) {
  __shared__ unsigned sFp[64 * SFP];   // packed P-sum pairs, then packed h
  __shared__ short sEA[64 * 40];       // ea tile f16
  __shared__ int sDst[64];

  const int tid = threadIdx.x;
  const int e0 = blockIdx.x * 64;
  const int le = tid >> 2, lq = tid & 3;
  const int wv = tid >> 6, l = tid & 63, lr = l & 15, kq = l >> 4;

  // W1c (kt=8 of packed eW1) -> registers
  half8 w1c[2];
#pragma unroll
  for (int c = 0; c < 2; ++c)
    w1c[c] = ((const half8*)pW1)[(64 + wv * 2 + c) * 64 + l];

  const int4 er = e4[e0 + le];
  if (lq == 0) sDst[le] = er.y;

  // ---- stage: packed P-sum pairs + ea ----
  {
    const uint4* ps = (const uint4*)(Psw + (size_t)er.x * 64);
    const uint4* pd = (const uint4*)(Pdw + (size_t)er.y * 64);
#pragma unroll
    for (int i = 0; i < 4; ++i) {
      uint4 a = ps[lq * 4 + i];
      uint4 b = pd[lq * 4 + i];
      uint4 s = {hadd2u(a.x, b.x), hadd2u(a.y, b.y), hadd2u(a.z, b.z), hadd2u(a.w, b.w)};
      *(uint4*)&sFp[le * SFP + lq * 16 + i * 4] = s;
    }
    const float4* ep = (const float4*)(ea + (size_t)er.z * EDD);
    float4 a = ep[lq * 2], b = ep[lq * 2 + 1];
    uint4 u = {pkh(a.x, a.y), pkh(a.z, a.w), pkh(b.x, b.y), pkh(b.z, b.w)};
    *(uint4*)&sEA[le * 40 + lq * 8] = u;
  }
  __syncthreads();

  // ---- ea @ W1c : single K=32 tile, 8 MFMA ----
  f32x4 acc[4][2];
  const f32x4 zero = {0.f, 0.f, 0.f, 0.f};
#pragma unroll
  for (int m = 0; m < 4; ++m) { acc[m][0] = zero; acc[m][1] = zero; }
  {
#pragma unroll
    for (int m = 0; m < 4; ++m) {
      half8 af = *(const half8*)&sEA[(m * 16 + lr) * 40 + kq * 8];
#pragma unroll
      for (int c = 0; c < 2; ++c)
        acc[m][c] = __builtin_amdgcn_mfma_f32_16x16x32_f16(af, w1c[c], acc[m][c], 0, 0, 0);
    }
  }

  // ---- h = gelu(acc + P + b1) -> same packed slot ----
  const float b1c0 = b1[wv * 32 + lr];
  const float b1c1 = b1[wv * 32 + 16 + lr];
#pragma unroll
  for (int m = 0; m < 4; ++m)
#pragma unroll
    for (int r = 0; r < 4; ++r) {
      const int row = m * 16 + kq * 4 + r;
      unsigned up = sFp[row * SFP + wv * 16 + lr];
      float v0 = acc[m][0][r] + lo16f(up) + b1c0;
      float v1 = acc[m][1][r] + hi16f(up) + b1c1;
      sFp[row * SFP + wv * 16 + lr] = pkh(gelu_f(v0), gelu_f(v1));
    }
  __syncthreads();

  // ---- segmented sum over sorted dst runs (f32 accum, packed reads) ----
  {
    const int p = tid & 63;
    const int q = tid >> 6;
    const int c0 = (p >> 4) * 32 + (p & 15);
    const int rend = q * 16 + 15;
    float r0s = 0.f, r1s = 0.f;
#pragma unroll 4
    for (int r = q * 16; r <= rend; ++r) {
      unsigned u = sFp[r * SFP + p];
      r0s += lo16f(u);
      r1s += hi16f(u);
      int dcur = sDst[r];
      bool last = (r == rend) || (sDst[r + 1] != dcur);
      if (last) {
        atomicAdd(&Hagg[(size_t)dcur * HH + c0], r0s);
        atomicAdd(&Hagg[(size_t)dcur * HH + c0 + 16], r1s);
        r0s = 0.f;
        r1s = 0.f;
      }
    }
  }
}

// ---------------------------------------------------------------------------
// k_node: hidden = gelu(x@nW1a + Hm@W2' + nb1 + f*b2p); out = LN(hidden@nW2
// + nb2 + x). Hidden lives in sA cols 128..255; x f16 in cols 0..127 is
// reused for the residual (no second global x read).
// ---------------------------------------------------------------------------
#define NS 264
__global__ __launch_bounds__(256, 4) void k_node(
    const float* __restrict__ x,
    const float* __restrict__ Hagg, const int* __restrict__ chist,
    const short* __restrict__ pn1, const short* __restrict__ pnW2p,
    const float* __restrict__ nb1, const float* __restrict__ b2p,
    const short* __restrict__ pn2, const float* __restrict__ nb2,
    const float* __restrict__ g, const float* __restrict__ be,
    float* __restrict__ out) {
  __shared__ short sA[64 * NS];
  __shared__ float sP[64 * 4];
  __shared__ float sP2[64 * 4];
  __shared__ float sFac[64];

  const int tid = threadIdx.x;
  const int r0 = blockIdx.x * 64;
  const int le = tid >> 2;
  const int lq = tid & 3;
  const int wv = tid >> 6;
  const int l = tid & 63;
  const int lr = l & 15;
  const int kq = l >> 4;

  const half8* bpa = (const half8*)pn1;
  const half8* bpc = (const half8*)pnW2p;
  half8 b1f[16];
#pragma unroll
  for (int kt = 0; kt < 4; ++kt)
#pragma unroll
    for (int c = 0; c < 2; ++c) {
      b1f[kt * 2 + c] = bpa[(kt * 8 + wv * 2 + c) * 64 + l];
      b1f[(kt + 4) * 2 + c] = bpc[(kt * 8 + wv * 2 + c) * 64 + l];
    }

  {
    const int gr = r0 + le;
    short* row = &sA[le * NS];
    if (gr < NN) {
      float cntf = (float)chist[gr];
      float rinv = 1.0f / (cntf + 1e-8f);
      if (lq == 0) sFac[le] = cntf * rinv;
      const float4* xs = (const float4*)(x + (size_t)gr * HH);
#pragma unroll
      for (int i = 0; i < 4; ++i) {
        float4 a = xs[lq * 8 + i * 2], c = xs[lq * 8 + i * 2 + 1];
        uint4 u = {pkh(a.x, a.y), pkh(a.z, a.w), pkh(c.x, c.y), pkh(c.z, c.w)};
        *(uint4*)(row + lq * 32 + i * 8) = u;
      }
      const float4* hs = (const float4*)(Hagg + (size_t)gr * HH);
#pragma unroll
      for (int i = 0; i < 4; ++i) {
        float4 a = hs[lq * 8 + i * 2], c = hs[lq * 8 + i * 2 + 1];
        uint4 u = {pkh(a.x * rinv, a.y * rinv), pkh(a.z * rinv, a.w * rinv),
                   pkh(c.x * rinv, c.y * rinv), pkh(c.z * rinv, c.w * rinv)};
        *(uint4*)(row + 128 + lq * 32 + i * 8) = u;
      }
    } else {
      if (lq == 0) sFac[le] = 0.f;
      uint4 z = {0, 0, 0, 0};
#pragma unroll
      for (int i = 0; i < 8; ++i) *(uint4*)(row + lq * 64 + i * 8) = z;
    }
  }
  __syncthreads();

  f32x4 acc[4][2];
  const f32x4 zero = {0.f, 0.f, 0.f, 0.f};
#pragma unroll
  for (int m = 0; m < 4; ++m) { acc[m][0] = zero; acc[m][1] = zero; }
  const short* ab = &sA[lr * NS + kq * 8];
#pragma unroll
  for (int kt = 0; kt < 8; ++kt) {
    half8 af[4];
#pragma unroll
    for (int m = 0; m < 4; ++m)
      af[m] = *(const half8*)(ab + m * 16 * NS + kt * 32);
#pragma unroll
    for (int m = 0; m < 4; ++m)
#pragma unroll
      for (int c = 0; c < 2; ++c)
        acc[m][c] = __builtin_amdgcn_mfma_f32_16x16x32_f16(af[m], b1f[kt * 2 + c], acc[m][c], 0, 0, 0);
  }

  const half8* bp2 = (const half8*)pn2;
  half8 b2f_[8];
#pragma unroll
  for (int kt = 0; kt < 4; ++kt)
#pragma unroll
    for (int c = 0; c < 2; ++c)
      b2f_[kt * 2 + c] = bp2[(kt * 8 + wv * 2 + c) * 64 + l];

  __syncthreads();

  // ---- bias (nb1 + f*b2p) + GELU -> sA cols 128..255 (Hm region, consumed) ----
#pragma unroll
  for (int c = 0; c < 2; ++c) {
    const int col = wv * 32 + c * 16 + lr;
    const float b1v = nb1[col];
    const float b2pv = b2p[col];
#pragma unroll
    for (int m = 0; m < 4; ++m)
#pragma unroll
      for (int r = 0; r < 4; ++r) {
        const int row = m * 16 + kq * 4 + r;
        float fac = sFac[row];
        sA[row * NS + 128 + col] = f2hs(gelu_f(acc[m][c][r] + b1v + fac * b2pv));
      }
  }
  __syncthreads();

  f32x4 acc2[4][2];
#pragma unroll
  for (int m = 0; m < 4; ++m) { acc2[m][0] = zero; acc2[m][1] = zero; }
#pragma unroll
  for (int kt = 0; kt < 4; ++kt) {
    half8 af[4];
#pragma unroll
    for (int m = 0; m < 4; ++m)
      af[m] = *(const half8*)(ab + m * 16 * NS + 128 + kt * 32);
#pragma unroll
    for (int m = 0; m < 4; ++m)
#pragma unroll
      for (int c = 0; c < 2; ++c)
        acc2[m][c] = __builtin_amdgcn_mfma_f32_16x16x32_f16(af[m], b2f_[kt * 2 + c], acc2[m][c], 0, 0, 0);
  }

  // ---- + b2 + residual (x f16 from LDS cols 0..127) ----
  float val[4][2][4];
#pragma unroll
  for (int c = 0; c < 2; ++c) {
    const int col = wv * 32 + c * 16 + lr;
    const float b2v = nb2[col];
#pragma unroll
    for (int m = 0; m < 4; ++m)
#pragma unroll
      for (int r = 0; r < 4; ++r) {
        const int lrow = m * 16 + kq * 4 + r;
        float xr = h2f(sA[lrow * NS + col]);
        val[m][c][r] = acc2[m][c][r] + b2v + xr;
      }
  }
#pragma unroll
  for (int m = 0; m < 4; ++m)
#pragma unroll
    for (int r = 0; r < 4; ++r) {
      float s = val[m][0][r] + val[m][1][r];
      float s2 = val[m][0][r] * val[m][0][r] + val[m][1][r] * val[m][1][r];
#pragma unroll
      for (int o = 1; o < 16; o <<= 1) {
        s += __shfl_xor(s, o);
        s2 += __shfl_xor(s2, o);
      }
      if (lr == 0) {
        const int row = m * 16 + kq * 4 + r;
        sP[row * 4 + wv] = s;
        sP2[row * 4 + wv] = s2;
      }
    }
  __syncthreads();

#pragma unroll
  for (int c = 0; c < 2; ++c) {
    const int col = wv * 32 + c * 16 + lr;
    const float gv = g[col];
    const float bv = be[col];
#pragma unroll
    for (int m = 0; m < 4; ++m)
#pragma unroll
      for (int r = 0; r < 4; ++r) {
        const int lrow = m * 16 + kq * 4 + r;
        const int row = r0 + lrow;
        if (row < NN) {
          float4 ps = *(float4*)&sP[lrow * 4];
          float4 qs = *(float4*)&sP2[lrow * 4];
          float s = ps.x + ps.y + ps.z + ps.w;
          float s2 = qs.x + qs.y + qs.z + qs.w;
          float mu = s * 0.0078125f;
          float var = s2 * 0.0078125f - mu * mu;
          float rs = rsqrtf(var + 1e-5f);
          out[(size_t)row * HH + col] = (val[m][c][r] - mu) * rs * gv + bv;
        }
      }
  }
}

extern "C" void kernel_launch(void* const* d_in, const int* in_sizes, int n_in,
                              void* d_out, int out_size, void* d_ws, size_t ws_size,
                              hipStream_t stream) {
  const float* x = (const float*)d_in[0];
  const void* ei = d_in[1];
  const float* ea = (const float*)d_in[2];
  const float* eW1 = (const float*)d_in[3];
  const float* eb1 = (const float*)d_in[4];
  const float* eW2 = (const float*)d_in[5];
  const float* eb2 = (const float*)d_in[6];
  const float* nW1 = (const float*)d_in[7];
  const float* nb1 = (const float*)d_in[8];
  const float* nW2 = (const float*)d_in[9];
  const float* nb2 = (const float*)d_in[10];
  const float* lng = (const float*)d_in[11];
  const float* lnb = (const float*)d_in[12];
  float* out = (float*)d_out;

  char* w = (char*)d_ws;
  size_t off = 0;
  auto alloc = [&](size_t bytes) { void* p = w + off; off = (off + bytes + 255) & ~(size_t)255; return p; };
  float* Hagg = (float*)alloc((size_t)NN * HH * 4);     // zeroed by k_preh
  int* chist = (int*)alloc((size_t)NBINS * 4);          // zeroed by k_setup
  int* cntW = (int*)alloc((size_t)NBINS * 4);           // zeroed by k_setup (contiguous)
  short* pe1 = (short*)alloc((size_t)72 * 512 * 2);
  short* pn1 = (short*)alloc((size_t)64 * 512 * 2);
  short* pn2 = (short*)alloc((size_t)32 * 512 * 2);
  short* pnW2p = (short*)alloc((size_t)32 * 512 * 2);
  float* b2p = (float*)alloc(HH * 4);
  int4* e4 = (int4*)alloc((size_t)EE * 16);
  int* tmpS = (int*)alloc((size_t)NBINS * 4);
  int* bsum = (int*)alloc(256 * 4);
  int* flag = (int*)alloc(256);
  unsigned* Psw = (unsigned*)alloc((size_t)NN * 64 * 4);
  unsigned* Pdw = (unsigned*)alloc((size_t)NN * 64 * 4);

  k_setup<<<95, 256, 0, stream>>>(eW1, nW1, nW2, eW2, eb2, (const long long*)ei,
                                  (long long)NN, pe1, pn1, pn2, pnW2p, b2p, chist, flag);
  k_preh<<<NPRE + (EE + 255) / 256, 256, 0, stream>>>(x, pe1, ei, flag, Psw, Pdw, Hagg, chist);
  k_scan1<<<NBINS / 256, 256, 0, stream>>>(chist, tmpS, bsum);
  k_scan2<<<1, 256, 0, stream>>>(bsum);
  k_scatter<<<(EE + 255) / 256, 256, 0, stream>>>(ei, flag, tmpS, chist, bsum, cntW, e4);
  k_edge<<<EE / 64, 256, 0, stream>>>(Psw, Pdw, ea, pe1, eb1, e4, Hagg);
  k_node<<<(NN + 63) / 64, 256, 0, stream>>>(x, Hagg, chist, pn1, pnW2p, nb1, b2p, pn2, nb2, lng, lnb, out);
}

// Round 10
// 156.368 us; speedup vs baseline: 15.7082x; 1.0931x over previous
//
#include <hip/hip_runtime.h>
#include <hip/hip_fp16.h>
#include <math.h>

#define NN 50000
#define HH 128
#define EE 600000
#define EDD 32
#define NBINS 50176   // 196*256 >= NN
#define NPRE 782      // (NN+63)/64
#define NWG_E (EE / 64)

typedef __attribute__((ext_vector_type(8))) _Float16 half8;
typedef __attribute__((ext_vector_type(4))) float f32x4;

__device__ __forceinline__ unsigned pkh(float a, float b) {
  __half2 h = __floats2half2_rn(a, b);
  return *reinterpret_cast<unsigned*>(&h);
}
__device__ __forceinline__ unsigned hadd2u(unsigned a, unsigned b) {
  __half2 x = *reinterpret_cast<__half2*>(&a);
  __half2 y = *reinterpret_cast<__half2*>(&b);
  __half2 s = __hadd2(x, y);
  return *reinterpret_cast<unsigned*>(&s);
}
__device__ __forceinline__ unsigned hmul2u(unsigned a, unsigned b) {
  __half2 x = *reinterpret_cast<__half2*>(&a);
  __half2 y = *reinterpret_cast<__half2*>(&b);
  __half2 s = __hmul2(x, y);
  return *reinterpret_cast<unsigned*>(&s);
}
__device__ __forceinline__ float lo16f(unsigned u) {
  __half2 h = *reinterpret_cast<__half2*>(&u);
  return __low2float(h);
}
__device__ __forceinline__ float hi16f(unsigned u) {
  __half2 h = *reinterpret_cast<__half2*>(&u);
  return __high2float(h);
}
__device__ __forceinline__ short f2hs(float f) {
  __half h = __float2half_rn(f);
  return *reinterpret_cast<short*>(&h);
}
__device__ __forceinline__ float h2f(short s) {
  __half h = *reinterpret_cast<__half*>(&s);
  return __half2float(h);
}

// tanh-form GELU via native v_exp_f32 / v_rcp_f32 (saturates exactly).
__device__ __forceinline__ float gelu_f(float v) {
  float u = 2.3022082f * v * fmaf(0.044715f, v * v, 1.0f);
  float e = __builtin_amdgcn_exp2f(u);
  float r = __builtin_amdgcn_rcpf(e + 1.0f);
  return fmaf(-v, r, v);
}

// ---------------------------------------------------------------------------
// k_setup (95 blocks x 256):
//   blocks 0..41 : pack eW1/nW1/nW2 f16 B-frag order (4 sub-tiles each)
//   block 42     : detect int64 vs int32 edge_index (flag=1 -> int64)
//   blocks 43..91: zero chist+cntW
//   blocks 92,93 : W2' = eW2 @ nW1b, B-frag order with PAIR-PERMUTED rows
//                  (K-axis permuted to match packed-pair Hm LDS layout)
//   block 94     : b2p = eb2 @ nW1b (f32)
// ---------------------------------------------------------------------------
#define FS 132
__global__ __launch_bounds__(256) void k_setup(
    const float* __restrict__ eW1, const float* __restrict__ nW1,
    const float* __restrict__ nW2, const float* __restrict__ eW2,
    const float* __restrict__ eb2, const long long* __restrict__ ei,
    long long nmax,
    short* __restrict__ pe1, short* __restrict__ pn1, short* __restrict__ pn2,
    short* __restrict__ pnW2p, float* __restrict__ b2p,
    int* __restrict__ zbase, int* __restrict__ flag) {
  __shared__ short sA[64 * 136];
  __shared__ float sR[64 * FS];
  __shared__ int bad;
  const int blk = blockIdx.x;
  const int tid = threadIdx.x;

  if (blk < 42) {                       // ---- weight pack ----
    const int b = blk * 4 + (tid >> 6);
    const int l = tid & 63;
    const float* W;
    short* P;
    int bb;
    if (b < 72)       { W = eW1; P = pe1; bb = b; }
    else if (b < 136) { W = nW1; P = pn1; bb = b - 72; }
    else              { W = nW2; P = pn2; bb = b - 136; }
    const int kt = bb >> 3, ct = bb & 7;
    short v[8];
#pragma unroll
    for (int j = 0; j < 8; ++j)
      v[j] = f2hs(W[(size_t)(kt * 32 + ((l >> 4) * 8 + j)) * HH + ct * 16 + (l & 15)]);
    short* dst = P + ((size_t)bb * 64 + l) * 8;
#pragma unroll
    for (int j = 0; j < 8; ++j) dst[j] = v[j];
    return;
  }
  if (blk == 42) {                      // ---- dtype detect ----
    if (tid == 0) bad = 0;
    __syncthreads();
    for (int i = tid; i < 2048; i += 256) {
      long long v = ei[i];
      if (v < 0 || v >= nmax) bad = 1;
    }
    __syncthreads();
    if (tid == 0) *flag = (bad ? 0 : 1);
    return;
  }
  if (blk < 92) {                       // ---- zero chist+cntW ----
    int idx = (blk - 43) * 2048 + tid * 8;
    int4 z = {0, 0, 0, 0};
    *(int4*)(zbase + idx) = z;
    *(int4*)(zbase + idx + 4) = z;
    return;
  }
  if (blk == 94) {                      // ---- b2p ----
    if (tid < 128) {
      float acc = 0.f;
#pragma unroll 4
      for (int k = 0; k < 128; ++k)
        acc += eb2[k] * nW1[(size_t)(128 + k) * HH + tid];
      b2p[tid] = acc;
    }
    return;
  }
  // ---- W2' GEMM (blocks 92,93) ----
  {
    const int b = blk - 92;
    const int le = tid >> 2, lq = tid & 3;
    const int wv = tid >> 6, l = tid & 63, lr = l & 15, kq = l >> 4;

    half8 bf[8];
#pragma unroll
    for (int kt = 0; kt < 4; ++kt)
#pragma unroll
      for (int c = 0; c < 2; ++c) {
        half8 v;
#pragma unroll
        for (int j = 0; j < 8; ++j)
          v[j] = (_Float16)nW1[(size_t)(128 + kt * 32 + ((l >> 4) * 8 + j)) * HH +
                               (wv * 2 + c) * 16 + (l & 15)];
        bf[kt * 2 + c] = v;
      }
    {
      const float4* xs = (const float4*)(eW2 + (size_t)(64 * b + le) * HH);
#pragma unroll
      for (int i = 0; i < 4; ++i) {
        float4 a = xs[lq * 8 + i * 2], c = xs[lq * 8 + i * 2 + 1];
        uint4 u = {pkh(a.x, a.y), pkh(a.z, a.w), pkh(c.x, c.y), pkh(c.z, c.w)};
        *(uint4*)&sA[le * 136 + lq * 32 + i * 8] = u;
      }
    }
    __syncthreads();

    f32x4 acc[4][2];
    const f32x4 zero = {0.f, 0.f, 0.f, 0.f};
#pragma unroll
    for (int m = 0; m < 4; ++m) { acc[m][0] = zero; acc[m][1] = zero; }
    const short* ab = &sA[lr * 136 + kq * 8];
#pragma unroll
    for (int kt = 0; kt < 4; ++kt) {
      half8 af[4];
#pragma unroll
      for (int m = 0; m < 4; ++m) af[m] = *(const half8*)(ab + m * 16 * 136 + kt * 32);
#pragma unroll
      for (int m = 0; m < 4; ++m)
#pragma unroll
        for (int c = 0; c < 2; ++c)
          acc[m][c] = __builtin_amdgcn_mfma_f32_16x16x32_f16(af[m], bf[kt * 2 + c], acc[m][c], 0, 0, 0);
    }
#pragma unroll
    for (int c = 0; c < 2; ++c)
#pragma unroll
      for (int m = 0; m < 4; ++m)
#pragma unroll
        for (int r = 0; r < 4; ++r)
          sR[(m * 16 + kq * 4 + r) * FS + wv * 32 + c * 16 + lr] = acc[m][c][r];
    __syncthreads();

    // emit pack with pair-permuted K rows:
    //   kpos_local = ktl*32 + (lane>>4)*8 + j; t = kpos>>1; h = kpos&1;
    //   row_local  = (t>>4)*32 + (t&15) + 16h
#pragma unroll
    for (int it = 0; it < 4; ++it) {
      int item = tid + 256 * it;
      int lane = item & 63;
      int pair = item >> 6;      // 0..15
      int ktl = pair >> 3, ct = pair & 7;
      short v[8];
#pragma unroll
      for (int j = 0; j < 8; ++j) {
        int kpos = ktl * 32 + ((lane >> 4) * 8 + j);
        int t2 = kpos >> 1, h2 = kpos & 1;
        int rowl = (t2 >> 4) * 32 + (t2 & 15) + 16 * h2;
        int colp = ct * 16 + (lane & 15);
        v[j] = f2hs(sR[rowl * FS + colp]);
      }
      short* dst = pnW2p + (((size_t)(2 * b + ktl) * 8 + ct) * 64 + lane) * 8;
#pragma unroll
      for (int j = 0; j < 8; ++j) dst[j] = v[j];
    }
  }
}

// ---------------------------------------------------------------------------
// k_preh: blocks 0..NPRE-1: Psw/Pdw = packed-pair f16 of x@W1a/x@W1b + zero
// HaggH2 rows (packed half2, NN*64 u32). blocks NPRE..: dst histogram.
// ---------------------------------------------------------------------------
__global__ __launch_bounds__(256, 4) void k_preh(
    const float* __restrict__ x, const short* __restrict__ pW1,
    const void* __restrict__ eiv, const int* __restrict__ flag,
    unsigned* __restrict__ Psw, unsigned* __restrict__ Pdw,
    unsigned* __restrict__ HaggH2, int* __restrict__ chist) {
  __shared__ short sX[64 * 136];
  const int blk = blockIdx.x;
  const int tid = threadIdx.x;

  if (blk >= NPRE) {                    // ---- histogram ----
    int e = (blk - NPRE) * 256 + tid;
    if (e < EE) {
      int d;
      if (*flag) d = (int)((const long long*)eiv)[EE + e];
      else       d = ((const int*)eiv)[EE + e];
      atomicAdd(&chist[d], 1);
    }
    return;
  }

  const int r0 = blk * 64;
  const int le = tid >> 2, lq = tid & 3;
  const int wv = tid >> 6, l = tid & 63, lr = l & 15, kq = l >> 4;

  // zero this block's HaggH2 rows (64 u32 per node)
  {
    int gr = r0 + le;
    if (gr < NN) {
      uint4 z = {0, 0, 0, 0};
      uint4* hp = (uint4*)(HaggH2 + (size_t)gr * 64);
#pragma unroll
      for (int i = 0; i < 4; ++i) hp[lq * 4 + i] = z;
    }
  }

  const half8* bp = (const half8*)pW1;
  half8 fa[8], fb[8];
#pragma unroll
  for (int kt = 0; kt < 4; ++kt)
#pragma unroll
    for (int c = 0; c < 2; ++c) {
      fa[kt * 2 + c] = bp[(kt * 8 + wv * 2 + c) * 64 + l];
      fb[kt * 2 + c] = bp[((kt + 4) * 8 + wv * 2 + c) * 64 + l];
    }
  {
    int gr = r0 + le;
    if (gr < NN) {
      const float4* xs = (const float4*)(x + (size_t)gr * HH);
#pragma unroll
      for (int i = 0; i < 4; ++i) {
        float4 a = xs[lq * 8 + i * 2], c = xs[lq * 8 + i * 2 + 1];
        uint4 u = {pkh(a.x, a.y), pkh(a.z, a.w), pkh(c.x, c.y), pkh(c.z, c.w)};
        *(uint4*)&sX[le * 136 + lq * 32 + i * 8] = u;
      }
    } else {
      uint4 z = {0, 0, 0, 0};
#pragma unroll
      for (int i = 0; i < 4; ++i) *(uint4*)&sX[le * 136 + lq * 32 + i * 8] = z;
    }
  }
  __syncthreads();

  f32x4 as_[4][2], ad[4][2];
  const f32x4 zero = {0.f, 0.f, 0.f, 0.f};
#pragma unroll
  for (int m = 0; m < 4; ++m) { as_[m][0] = zero; as_[m][1] = zero; ad[m][0] = zero; ad[m][1] = zero; }
  const short* ab = &sX[lr * 136 + kq * 8];
#pragma unroll
  for (int kt = 0; kt < 4; ++kt) {
    half8 af[4];
#pragma unroll
    for (int m = 0; m < 4; ++m) af[m] = *(const half8*)(ab + m * 16 * 136 + kt * 32);
#pragma unroll
    for (int m = 0; m < 4; ++m)
#pragma unroll
      for (int c = 0; c < 2; ++c) {
        as_[m][c] = __builtin_amdgcn_mfma_f32_16x16x32_f16(af[m], fa[kt * 2 + c], as_[m][c], 0, 0, 0);
        ad[m][c] = __builtin_amdgcn_mfma_f32_16x16x32_f16(af[m], fb[kt * 2 + c], ad[m][c], 0, 0, 0);
      }
  }
#pragma unroll
  for (int m = 0; m < 4; ++m)
#pragma unroll
    for (int r = 0; r < 4; ++r) {
      int grow = r0 + m * 16 + kq * 4 + r;
      if (grow < NN) {
        Psw[(size_t)grow * 64 + wv * 16 + lr] = pkh(as_[m][0][r], as_[m][1][r]);
        Pdw[(size_t)grow * 64 + wv * 16 + lr] = pkh(ad[m][0][r], ad[m][1][r]);
      }
    }
}

// ---------------------------------------------------------------------------
// prefix scan: inclusive within block + block sums (exclusive top level is
// recomputed inside k_scatter).
// ---------------------------------------------------------------------------
__global__ void k_scan1(const int* __restrict__ chist, int* __restrict__ tmp,
                        int* __restrict__ bsum) {
  __shared__ int buf[2][256];
  int t = threadIdx.x;
  int i = blockIdx.x * 256 + t;
  buf[0][t] = chist[i];
  __syncthreads();
  int cur = 0;
  for (int o = 1; o < 256; o <<= 1) {
    int v = buf[cur][t];
    if (t >= o) v += buf[cur][t - o];
    buf[cur ^ 1][t] = v;
    __syncthreads();
    cur ^= 1;
  }
  tmp[i] = buf[cur][t];
  if (t == 255) bsum[blockIdx.x] = buf[cur][255];
}

// ---------------------------------------------------------------------------
// k_scatter: per-block re-scan of bsum (folds old k_scan2), then scatter
// edges into dst-sorted u64 records: src | dst<<20 | eid<<40.
// ---------------------------------------------------------------------------
__global__ void k_scatter(const void* __restrict__ eiv, const int* __restrict__ flag,
                          const int* __restrict__ tmp, const int* __restrict__ chist,
                          const int* __restrict__ bsum, int* __restrict__ cntW,
                          unsigned long long* __restrict__ e8) {
  __shared__ int sB[2][256];
  const int t = threadIdx.x;
  int orig = (t < 196) ? bsum[t] : 0;
  sB[0][t] = orig;
  __syncthreads();
  int cur = 0;
  for (int o = 1; o < 256; o <<= 1) {
    int v = sB[cur][t];
    if (t >= o) v += sB[cur][t - o];
    sB[cur ^ 1][t] = v;
    __syncthreads();
    cur ^= 1;
  }
  // cur == 0 after 8 flips; write exclusive into sB[1]
  sB[1][t] = sB[0][t] - orig;
  __syncthreads();

  int e = blockIdx.x * 256 + t;
  if (e >= EE) return;
  int s, d;
  if (*flag) {
    const long long* p = (const long long*)eiv;
    s = (int)p[e];
    d = (int)p[EE + e];
  } else {
    const int* p = (const int*)eiv;
    s = p[e];
    d = p[EE + e];
  }
  int base = tmp[d] - chist[d] + sB[1][d >> 8];
  int pos = base + atomicAdd(&cntW[d], 1);
  e8[pos] = (unsigned long long)s | ((unsigned long long)d << 20) |
            ((unsigned long long)e << 40);
}

// ---------------------------------------------------------------------------
// k_edge: h = gelu(Ps[src]+Pd[dst] + ea@W1c + b1); segment-sum h (packed
// pairs) -> one pk_add_f16 atomic per segment into HaggH2[dst].
// XCD-chunked block swizzle; transposed-h LDS for wide segment reads.
// ---------------------------------------------------------------------------
#define SFP 68
__global__ __launch_bounds__(256, 7) void k_edge(
    const unsigned* __restrict__ Psw, const unsigned* __restrict__ Pdw,
    const float* __restrict__ ea,
    const short* __restrict__ pW1, const float* __restrict__ b1,
    const unsigned long long* __restrict__ e8, unsigned* __restrict__ HaggH2) {
  __shared__ unsigned sFp[64 * SFP];   // P-sum pairs [row][pair], then h [pair][row]
  __shared__ short sEA[64 * 40];       // ea tile f16
  __shared__ int sDst[64];

  // bijective XCD-chunked swizzle: each XCD gets a contiguous dst range
  int orig = blockIdx.x;
  const int q8 = NWG_E >> 3, r8 = NWG_E & 7;
  int xcd = orig & 7, lid = orig >> 3;
  int swz = (xcd < r8) ? xcd * (q8 + 1) + lid
                       : r8 * (q8 + 1) + (xcd - r8) * q8 + lid;

  const int tid = threadIdx.x;
  const int e0 = swz * 64;
  const int le = tid >> 2, lq = tid & 3;
  const int wv = tid >> 6, l = tid & 63, lr = l & 15, kq = l >> 4;

  // W1c (kt=8 of packed eW1) -> registers
  half8 w1c[2];
#pragma unroll
  for (int c = 0; c < 2; ++c)
    w1c[c] = ((const half8*)pW1)[(64 + wv * 2 + c) * 64 + l];

  const unsigned long long er = e8[e0 + le];
  const int gs = (int)(er & 0xFFFFF);
  const int gd = (int)((er >> 20) & 0xFFFFF);
  const int ge = (int)(er >> 40);
  if (lq == 0) sDst[le] = gd;

  // ---- stage: packed P-sum pairs [row][pair] + ea ----
  {
    const uint4* ps = (const uint4*)(Psw + (size_t)gs * 64);
    const uint4* pd = (const uint4*)(Pdw + (size_t)gd * 64);
#pragma unroll
    for (int i = 0; i < 4; ++i) {
      uint4 a = ps[lq * 4 + i];
      uint4 b = pd[lq * 4 + i];
      uint4 s = {hadd2u(a.x, b.x), hadd2u(a.y, b.y), hadd2u(a.z, b.z), hadd2u(a.w, b.w)};
      *(uint4*)&sFp[le * SFP + lq * 16 + i * 4] = s;
    }
    const float4* ep = (const float4*)(ea + (size_t)ge * EDD);
    float4 a = ep[lq * 2], b = ep[lq * 2 + 1];
    uint4 u = {pkh(a.x, a.y), pkh(a.z, a.w), pkh(b.x, b.y), pkh(b.z, b.w)};
    *(uint4*)&sEA[le * 40 + lq * 8] = u;
  }
  __syncthreads();

  // ---- ea @ W1c : single K=32 tile, 8 MFMA ----
  f32x4 acc[4][2];
  const f32x4 zero = {0.f, 0.f, 0.f, 0.f};
#pragma unroll
  for (int m = 0; m < 4; ++m) { acc[m][0] = zero; acc[m][1] = zero; }
  {
#pragma unroll
    for (int m = 0; m < 4; ++m) {
      half8 af = *(const half8*)&sEA[(m * 16 + lr) * 40 + kq * 8];
#pragma unroll
      for (int c = 0; c < 2; ++c)
        acc[m][c] = __builtin_amdgcn_mfma_f32_16x16x32_f16(af, w1c[c], acc[m][c], 0, 0, 0);
    }
  }

  // ---- h = gelu(acc + P + b1) -> regs (packed pairs) ----
  const float b1c0 = b1[wv * 32 + lr];
  const float b1c1 = b1[wv * 32 + 16 + lr];
  unsigned pr[4][4];
#pragma unroll
  for (int m = 0; m < 4; ++m)
#pragma unroll
    for (int r = 0; r < 4; ++r) {
      const int row = m * 16 + kq * 4 + r;
      unsigned up = sFp[row * SFP + wv * 16 + lr];
      float v0 = acc[m][0][r] + lo16f(up) + b1c0;
      float v1 = acc[m][1][r] + hi16f(up) + b1c1;
      pr[m][r] = pkh(gelu_f(v0), gelu_f(v1));
    }
  __syncthreads();   // all reads of sFp done before transposed overwrite

  // ---- transposed write: sFp[pair][row], rows contiguous ----
  {
    unsigned* tp = &sFp[(wv * 16 + lr) * SFP];
#pragma unroll
    for (int m = 0; m < 4; ++m) {
      uint4 u = {pr[m][0], pr[m][1], pr[m][2], pr[m][3]};
      *(uint4*)&tp[m * 16 + kq * 4] = u;
    }
  }
  __syncthreads();

  // ---- segmented sum over sorted dst runs; one pk atomic per segment ----
  {
    const int p = tid & 63;
    const int q = tid >> 6;
    const unsigned* tp2 = &sFp[p * SFP + q * 16];
    const int rend = q * 16 + 15;
    float r0s = 0.f, r1s = 0.f;
#pragma unroll
    for (int i = 0; i < 4; ++i) {
      uint4 u4 = *(const uint4*)&tp2[i * 4];
      unsigned uu[4] = {u4.x, u4.y, u4.z, u4.w};
#pragma unroll
      for (int j = 0; j < 4; ++j) {
        int r = q * 16 + i * 4 + j;
        r0s += lo16f(uu[j]);
        r1s += hi16f(uu[j]);
        int dcur = sDst[r];
        bool last = (r == rend) || (sDst[r + 1] != dcur);
        if (last) {
          unsafeAtomicAdd((__half2*)&HaggH2[(size_t)dcur * 64 + p],
                          __floats2half2_rn(r0s, r1s));
          r0s = 0.f;
          r1s = 0.f;
        }
      }
    }
  }
}

// ---------------------------------------------------------------------------
// k_node: hidden = gelu(x@nW1a + Hm@W2' + nb1 + f*b2p); out = LN(hidden@nW2
// + nb2 + x). Hm staged from packed HaggH2 (pair layout, pk_mul by rinv);
// W2' rows pre-permuted to match. Hidden GELU -> cols 128..255; x f16 in
// cols 0..127 reused for residual.
// ---------------------------------------------------------------------------
#define NS 264
__global__ __launch_bounds__(256, 4) void k_node(
    const float* __restrict__ x,
    const unsigned* __restrict__ HaggH2, const int* __restrict__ chist,
    const short* __restrict__ pn1, const short* __restrict__ pnW2p,
    const float* __restrict__ nb1, const float* __restrict__ b2p,
    const short* __restrict__ pn2, const float* __restrict__ nb2,
    const float* __restrict__ g, const float* __restrict__ be,
    float* __restrict__ out) {
  __shared__ short sA[64 * NS];
  __shared__ float sP[64 * 4];
  __shared__ float sP2[64 * 4];
  __shared__ float sFac[64];

  const int tid = threadIdx.x;
  const int r0 = blockIdx.x * 64;
  const int le = tid >> 2;
  const int lq = tid & 3;
  const int wv = tid >> 6;
  const int l = tid & 63;
  const int lr = l & 15;
  const int kq = l >> 4;

  const half8* bpa = (const half8*)pn1;
  const half8* bpc = (const half8*)pnW2p;
  half8 b1f[16];
#pragma unroll
  for (int kt = 0; kt < 4; ++kt)
#pragma unroll
    for (int c = 0; c < 2; ++c) {
      b1f[kt * 2 + c] = bpa[(kt * 8 + wv * 2 + c) * 64 + l];
      b1f[(kt + 4) * 2 + c] = bpc[(kt * 8 + wv * 2 + c) * 64 + l];
    }

  {
    const int gr = r0 + le;
    short* row = &sA[le * NS];
    if (gr < NN) {
      float cntf = (float)chist[gr];
      float rinv = 1.0f / (cntf + 1e-8f);
      if (lq == 0) sFac[le] = cntf * rinv;
      const float4* xs = (const float4*)(x + (size_t)gr * HH);
#pragma unroll
      for (int i = 0; i < 4; ++i) {
        float4 a = xs[lq * 8 + i * 2], c = xs[lq * 8 + i * 2 + 1];
        uint4 u = {pkh(a.x, a.y), pkh(a.z, a.w), pkh(c.x, c.y), pkh(c.z, c.w)};
        *(uint4*)(row + lq * 32 + i * 8) = u;
      }
      // Hm: packed pairs straight into LDS (pair layout), scaled by rinv
      const unsigned rv2 = pkh(rinv, rinv);
      const uint4* hs = (const uint4*)(HaggH2 + (size_t)gr * 64);
#pragma unroll
      for (int i = 0; i < 4; ++i) {
        uint4 u = hs[lq * 4 + i];
        u.x = hmul2u(u.x, rv2);
        u.y = hmul2u(u.y, rv2);
        u.z = hmul2u(u.z, rv2);
        u.w = hmul2u(u.w, rv2);
        *(uint4*)(row + 128 + lq * 32 + i * 8) = u;
      }
    } else {
      if (lq == 0) sFac[le] = 0.f;
      uint4 z = {0, 0, 0, 0};
#pragma unroll
      for (int i = 0; i < 8; ++i) *(uint4*)(row + lq * 64 + i * 8) = z;
    }
  }
  __syncthreads();

  f32x4 acc[4][2];
  const f32x4 zero = {0.f, 0.f, 0.f, 0.f};
#pragma unroll
  for (int m = 0; m < 4; ++m) { acc[m][0] = zero; acc[m][1] = zero; }
  const short* ab = &sA[lr * NS + kq * 8];
#pragma unroll
  for (int kt = 0; kt < 8; ++kt) {
    half8 af[4];
#pragma unroll
    for (int m = 0; m < 4; ++m)
      af[m] = *(const half8*)(ab + m * 16 * NS + kt * 32);
#pragma unroll
    for (int m = 0; m < 4; ++m)
#pragma unroll
      for (int c = 0; c < 2; ++c)
        acc[m][c] = __builtin_amdgcn_mfma_f32_16x16x32_f16(af[m], b1f[kt * 2 + c], acc[m][c], 0, 0, 0);
  }

  const half8* bp2 = (const half8*)pn2;
  half8 b2f_[8];
#pragma unroll
  for (int kt = 0; kt < 4; ++kt)
#pragma unroll
    for (int c = 0; c < 2; ++c)
      b2f_[kt * 2 + c] = bp2[(kt * 8 + wv * 2 + c) * 64 + l];

  __syncthreads();

  // ---- bias (nb1 + f*b2p) + GELU -> sA cols 128..255 (std col layout) ----
#pragma unroll
  for (int c = 0; c < 2; ++c) {
    const int col = wv * 32 + c * 16 + lr;
    const float b1v = nb1[col];
    const float b2pv = b2p[col];
#pragma unroll
    for (int m = 0; m < 4; ++m)
#pragma unroll
      for (int r = 0; r < 4; ++r) {
        const int row = m * 16 + kq * 4 + r;
        float fac = sFac[row];
        sA[row * NS + 128 + col] = f2hs(gelu_f(acc[m][c][r] + b1v + fac * b2pv));
      }
  }
  __syncthreads();

  f32x4 acc2[4][2];
#pragma unroll
  for (int m = 0; m < 4; ++m) { acc2[m][0] = zero; acc2[m][1] = zero; }
#pragma unroll
  for (int kt = 0; kt < 4; ++kt) {
    half8 af[4];
#pragma unroll
    for (int m = 0; m < 4; ++m)
      af[m] = *(const half8*)(ab + m * 16 * NS + 128 + kt * 32);
#pragma unroll
    for (int m = 0; m < 4; ++m)
#pragma unroll
      for (int c = 0; c < 2; ++c)
        acc2[m][c] = __builtin_amdgcn_mfma_f32_16x16x32_f16(af[m], b2f_[kt * 2 + c], acc2[m][c], 0, 0, 0);
  }

  // ---- + b2 + residual (x f16 from LDS cols 0..127) ----
  float val[4][2][4];
#pragma unroll
  for (int c = 0; c < 2; ++c) {
    const int col = wv * 32 + c * 16 + lr;
    const float b2v = nb2[col];
#pragma unroll
    for (int m = 0; m < 4; ++m)
#pragma unroll
      for (int r = 0; r < 4; ++r) {
        const int lrow = m * 16 + kq * 4 + r;
        float xr = h2f(sA[lrow * NS + col]);
        val[m][c][r] = acc2[m][c][r] + b2v + xr;
      }
  }
#pragma unroll
  for (int m = 0; m < 4; ++m)
#pragma unroll
    for (int r = 0; r < 4; ++r) {
      float s = val[m][0][r] + val[m][1][r];
      float s2 = val[m][0][r] * val[m][0][r] + val[m][1][r] * val[m][1][r];
#pragma unroll
      for (int o = 1; o < 16; o <<= 1) {
        s += __shfl_xor(s, o);
        s2 += __shfl_xor(s2, o);
      }
      if (lr == 0) {
        const int row = m * 16 + kq * 4 + r;
        sP[row * 4 + wv] = s;
        sP2[row * 4 + wv] = s2;
      }
    }
  __syncthreads();

#pragma unroll
  for (int c = 0; c < 2; ++c) {
    const int col = wv * 32 + c * 16 + lr;
    const float gv = g[col];
    const float bv = be[col];
#pragma unroll
    for (int m = 0; m < 4; ++m)
#pragma unroll
      for (int r = 0; r < 4; ++r) {
        const int lrow = m * 16 + kq * 4 + r;
        const int row = r0 + lrow;
        if (row < NN) {
          float4 ps = *(float4*)&sP[lrow * 4];
          float4 qs = *(float4*)&sP2[lrow * 4];
          float s = ps.x + ps.y + ps.z + ps.w;
          float s2 = qs.x + qs.y + qs.z + qs.w;
          float mu = s * 0.0078125f;
          float var = s2 * 0.0078125f - mu * mu;
          float rs = rsqrtf(var + 1e-5f);
          out[(size_t)row * HH + col] = (val[m][c][r] - mu) * rs * gv + bv;
        }
      }
  }
}

extern "C" void kernel_launch(void* const* d_in, const int* in_sizes, int n_in,
                              void* d_out, int out_size, void* d_ws, size_t ws_size,
                              hipStream_t stream) {
  const float* x = (const float*)d_in[0];
  const void* ei = d_in[1];
  const float* ea = (const float*)d_in[2];
  const float* eW1 = (const float*)d_in[3];
  const float* eb1 = (const float*)d_in[4];
  const float* eW2 = (const float*)d_in[5];
  const float* eb2 = (const float*)d_in[6];
  const float* nW1 = (const float*)d_in[7];
  const float* nb1 = (const float*)d_in[8];
  const float* nW2 = (const float*)d_in[9];
  const float* nb2 = (const float*)d_in[10];
  const float* lng = (const float*)d_in[11];
  const float* lnb = (const float*)d_in[12];
  float* out = (float*)d_out;

  char* w = (char*)d_ws;
  size_t off = 0;
  auto alloc = [&](size_t bytes) { void* p = w + off; off = (off + bytes + 255) & ~(size_t)255; return p; };
  unsigned* HaggH2 = (unsigned*)alloc((size_t)NN * 64 * 4);  // packed half2, zeroed by k_preh
  int* chist = (int*)alloc((size_t)NBINS * 4);               // zeroed by k_setup
  int* cntW = (int*)alloc((size_t)NBINS * 4);                // zeroed by k_setup (contiguous)
  short* pe1 = (short*)alloc((size_t)72 * 512 * 2);
  short* pn1 = (short*)alloc((size_t)64 * 512 * 2);
  short* pn2 = (short*)alloc((size_t)32 * 512 * 2);
  short* pnW2p = (short*)alloc((size_t)32 * 512 * 2);
  float* b2p = (float*)alloc(HH * 4);
  unsigned long long* e8 = (unsigned long long*)alloc((size_t)EE * 8);
  int* tmpS = (int*)alloc((size_t)NBINS * 4);
  int* bsum = (int*)alloc(256 * 4);
  int* flag = (int*)alloc(256);
  unsigned* Psw = (unsigned*)alloc((size_t)NN * 64 * 4);
  unsigned* Pdw = (unsigned*)alloc((size_t)NN * 64 * 4);

  k_setup<<<95, 256, 0, stream>>>(eW1, nW1, nW2, eW2, eb2, (const long long*)ei,
                                  (long long)NN, pe1, pn1, pn2, pnW2p, b2p, chist, flag);
  k_preh<<<NPRE + (EE + 255) / 256, 256, 0, stream>>>(x, pe1, ei, flag, Psw, Pdw, HaggH2, chist);
  k_scan1<<<NBINS / 256, 256, 0, stream>>>(chist, tmpS, bsum);
  k_scatter<<<(EE + 255) / 256, 256, 0, stream>>>(ei, flag, tmpS, chist, bsum, cntW, e8);
  k_edge<<<NWG_E, 256, 0, stream>>>(Psw, Pdw, ea, pe1, eb1, e8, HaggH2);
  k_node<<<(NN + 63) / 64, 256, 0, stream>>>(x, HaggH2, chist, pn1, pnW2p, nb1, b2p, pn2, nb2, lng, lnb, out);
}